// Round 8
// baseline (3829.639 us; speedup 1.0000x reference)
//
#include <hip/hip_runtime.h>

typedef unsigned short u16;
typedef unsigned int   u32;
typedef short s8v __attribute__((ext_vector_type(8)));
typedef short s4v __attribute__((ext_vector_type(4)));
typedef float f4v __attribute__((ext_vector_type(4)));
typedef u32   u2v __attribute__((ext_vector_type(2)));

// Problem constants
#define TT 32
#define BB 32
#define LL 128
#define FF 512
#define HH 1024
#define G4 4096
#define SCALE_ 0.08838834764831845f   // 1/sqrt(128)

// ---------- helpers ----------
__device__ __forceinline__ u16 f2bf(float f){
  u32 u = __float_as_uint(f);
  u32 r = u + 0x7fffu + ((u >> 16) & 1u);   // RNE
  return (u16)(r >> 16);
}
__device__ __forceinline__ float bf2f(u16 s){ return __uint_as_float(((u32)s) << 16); }
__device__ __forceinline__ float sigf(float x){ return 1.f / (1.f + __expf(-x)); }

__device__ __forceinline__ void mfma16(f4v& d, s8v a, s8v b){
  asm("v_mfma_f32_16x16x32_bf16 %0, %1, %2, %0" : "+v"(d) : "v"(a), "v"(b));
}

typedef __attribute__((address_space(3))) u32 as3u32;
typedef __attribute__((address_space(1))) u32 as1u32;
__device__ __forceinline__ void glds16(const u16* g, u16* l){
  __builtin_amdgcn_global_load_lds((const as1u32*)g, (as3u32*)l, 16, 0, 0);
}

// ---- producer stores: write-through to LLC (coherent point) ----
__device__ __forceinline__ void stcc_u16(u16* p, u16 v){
  u32 vv = v;
  asm volatile("global_store_short %0, %1, off sc0 sc1" :: "v"(p), "v"(vv) : "memory");
}
__device__ __forceinline__ void stcc_f32(float* p, float v){
  asm volatile("global_store_dword %0, %1, off sc0 sc1" :: "v"(p), "v"(v) : "memory");
}
__device__ __forceinline__ void stcc_2x32(void* p, u2v v){
  asm volatile("global_store_dwordx2 %0, %1, off sc0 sc1" :: "v"(p), "v"(v) : "memory");
}
__device__ __forceinline__ u32 poll_ld(const u32* p){
  u32 v;
  asm volatile("global_load_dword %0, %1, off sc0 sc1\n\ts_waitcnt vmcnt(0)"
               : "=v"(v) : "v"(p) : "memory");
  return v;
}

// grid barrier: vmcnt(0) drains producer sc0sc1 stores (release);
// sc0sc1 poll is the acquire. Consumers use PLAIN cached loads of
// write-once rotated buffers (never stale; replay-invariant values).
__device__ __forceinline__ void gbar(u32* cnt, u32 nblk, u32& epoch){
  asm volatile("s_waitcnt vmcnt(0)" ::: "memory");
  __syncthreads();
  ++epoch;
  if (threadIdx.x == 0){
    atomicAdd(cnt, 1u);
    u32 target = epoch * nblk;
    while (poll_ld(cnt) < target) __builtin_amdgcn_s_sleep(1);
  }
  __syncthreads();
}

// ---------- staging: [32][1024] u16 -> LDS, XOR swizzle (byte ^= (row&15)<<4) ----------
__device__ __forceinline__ void stage_issue(const u16* __restrict__ src, s8v* tmp){
  const int tid = threadIdx.x;
  const int row = tid >> 3, s0 = tid & 7;
  const u16* p = src + row * HH + s0 * 8;
  #pragma unroll
  for (int i = 0; i < 16; i++) tmp[i] = *(const s8v*)(p + i * 64);
}
__device__ __forceinline__ void stage_commit(const s8v* tmp, u16* lds){
  const int tid = threadIdx.x;
  const int row = tid >> 3, s0 = tid & 7;
  char* base = (char*)lds + (row << 11);
  u32 x = (u32)(row & 15) << 4;
  #pragma unroll
  for (int i = 0; i < 16; i++){
    u32 cb = (u32)(s0 + 8 * i) << 4;
    *(s8v*)(base + (cb ^ x)) = tmp[i];
  }
}
__device__ __forceinline__ s8v ldsA(const u16* lds, int row, int cb){
  return *(const s8v*)((const char*)lds + (row << 11) + (cb ^ ((row & 15) << 4)));
}
// phase-C per-wave [32][256] slice (16KB), row stride 512B
__device__ __forceinline__ void stageC_issue(const u16* __restrict__ src, s8v* tmp, int lane){
  const int row = lane >> 1, s0 = lane & 1;
  const u16* p = src + row * G4 + s0 * 8;
  #pragma unroll
  for (int i = 0; i < 16; i++) tmp[i] = *(const s8v*)(p + i * 16);
}
__device__ __forceinline__ void stageC_commit(const s8v* tmp, u16* ldsw, int lane){
  const int row = lane >> 1, s0 = lane & 1;
  char* base = (char*)ldsw + (row << 9);
  u32 x = (u32)(row & 15) << 4;
  #pragma unroll
  for (int i = 0; i < 16; i++){
    u32 cb = (u32)(s0 + 2 * i) << 4;
    *(s8v*)(base + (cb ^ x)) = tmp[i];
  }
}
__device__ __forceinline__ s8v ldsC(const u16* ldsw, int row, int cb){
  return *(const s8v*)((const char*)ldsw + (row << 9) + (cb ^ ((row & 15) << 4)));
}

// ---------- prep kernels ----------
__global__ void k_convert(const float* __restrict__ src, u16* __restrict__ dst, int n){
  int i = blockIdx.x * blockDim.x + threadIdx.x;
  int st = gridDim.x * blockDim.x;
  for (; i < n; i += st) dst[i] = f2bf(src[i]);
}
__global__ void k_split_w1(const float* __restrict__ w1, u16* __restrict__ w1c, u16* __restrict__ w1o){
  int i = blockIdx.x * blockDim.x + threadIdx.x;
  int st = gridDim.x * blockDim.x;
  const int n = G4 * (FF + HH);
  for (; i < n; i += st){
    int j = i / 1536, k = i - j * 1536;
    u16 v = f2bf(w1[i]);
    if (k < HH) w1c[j * HH + k] = v;
    else        w1o[j * FF + (k - HH)] = v;
  }
}
__global__ void k_addb(const float* __restrict__ a, const float* __restrict__ b,
                       float* __restrict__ o, int n){
  int i = blockIdx.x * blockDim.x + threadIdx.x;
  int st = gridDim.x * blockDim.x;
  for (; i < n; i += st) o[i] = a[i] + b[i];
}
__global__ void k_demo_t(const float* __restrict__ d, u16* __restrict__ o){
  const int n = LL * BB * FF;
  int i = blockIdx.x * blockDim.x + threadIdx.x;
  int st = gridDim.x * blockDim.x;
  for (; i < n; i += st){
    int f = i & 511;
    int row = i >> 9;
    int l = row >> 5, b = row & 31;
    o[i] = f2bf(d[(size_t)b * (LL * FF) + l * FF + f]);
  }
}

// ---------- generic GEMM (unchanged) ----------
template<int RELU>
__global__ void __launch_bounds__(256) k_gemm_bt(const u16* __restrict__ A, const u16* __restrict__ B,
        const float* __restrict__ bias, u16* __restrict__ C, int M, int N, int K)
{
  __shared__ u16 As[128 * 64];
  __shared__ u16 Bs[128 * 64];
  const int tid = threadIdx.x;
  const int lane = tid & 63, wave = tid >> 6;
  const int m0 = blockIdx.x * 128, n0 = blockIdx.y * 128;
  const int wm = wave >> 1, wn = wave & 1;
  const int lr = lane & 15, lk = (lane >> 4) * 8;
  f4v acc[4][4];
  #pragma unroll
  for (int i = 0; i < 4; i++)
    #pragma unroll
    for (int j = 0; j < 4; j++) acc[i][j] = f4v{0.f, 0.f, 0.f, 0.f};

  for (int kt = 0; kt < K; kt += 64){
    #pragma unroll
    for (int i = 0; i < 4; i++){
      int c = tid + i * 256;
      int row = c >> 3, cc = (c & 7) * 8;
      glds16(A + (size_t)(m0 + row) * K + kt + cc, &As[c * 8]);
      glds16(B + (size_t)(n0 + row) * K + kt + cc, &Bs[c * 8]);
    }
    __syncthreads();
    #pragma unroll
    for (int ks = 0; ks < 2; ++ks){
      int ko = ks * 32 + lk;
      s8v av[4], bv[4];
      #pragma unroll
      for (int m = 0; m < 4; m++) av[m] = *(const s8v*)&As[(wm * 64 + m * 16 + lr) * 64 + ko];
      #pragma unroll
      for (int n = 0; n < 4; n++) bv[n] = *(const s8v*)&Bs[(wn * 64 + n * 16 + lr) * 64 + ko];
      #pragma unroll
      for (int m = 0; m < 4; m++)
        #pragma unroll
        for (int n = 0; n < 4; n++) mfma16(acc[m][n], av[m], bv[n]);
    }
    __syncthreads();
  }
  const int r0 = (lane >> 4) * 4;
  #pragma unroll
  for (int m = 0; m < 4; m++){
    #pragma unroll
    for (int n = 0; n < 4; n++){
      int col = n0 + wn * 64 + n * 16 + lr;
      float bc = bias[col];
      #pragma unroll
      for (int r = 0; r < 4; r++){
        int row = m0 + wm * 64 + m * 16 + r0 + r;
        float v = acc[m][n][r] + bc;
        if (RELU) v = fmaxf(v, 0.f);
        C[(size_t)row * N + col] = f2bf(v);
      }
    }
  }
}

// ---------- encoder: h-chain lives in denc[l] (write-once per l) ----------
union SMemE { u16 stage[32768]; float gx[4][32][17]; };

__global__ void __launch_bounds__(256, 1) k_encoder(const u16* __restrict__ Whh, const u16* __restrict__ Xih,
      u16* __restrict__ zslot, u16* __restrict__ denc, u32* bar)
{
  __shared__ SMemE sm;
  const int nb = blockIdx.x, tid = threadIdx.x;
  const int lane = tid & 63, g = tid >> 6;
  const int jc = nb * 16;
  const int lr = lane & 15, lk = (lane >> 4) * 8;
  const int eb = tid >> 4, ejj = tid & 15;

  for (int i = tid; i < 512; i += 256){     // zero slot (h(-1) = 0), own cols
    int b = i >> 4, jj = i & 15;
    stcc_u16(&zslot[b * HH + jc + jj], 0);
  }
  float cr0 = 0.f, cr1 = 0.f;
  u32 epoch = 0;
  gbar(bar, 64, epoch);

  const u16* Wb = Whh + (size_t)(g * HH + jc + lr) * HH + lk;
  const int rb = (lane >> 4) * 4;
  for (int l = 0; l < LL; ++l){
    const u16* hb = (l == 0) ? zslot : (denc + (size_t)(l - 1) * (BB * HH));
    s8v ht[16];
    stage_issue(hb, ht);                    // plain cached loads (L2 dedup)
    // Xih: stream-once tensor -> non-temporal (don't evict Whh from L2)
    const u16* xr0 = Xih + ((size_t)(l * BB + eb)) * G4 + jc + ejj;
    const u16* xr1 = xr0 + (size_t)16 * G4;
    float xi0 = bf2f(__builtin_nontemporal_load(xr0));
    float xf0 = bf2f(__builtin_nontemporal_load(xr0 + 1024));
    float xg0 = bf2f(__builtin_nontemporal_load(xr0 + 2048));
    float xo0 = bf2f(__builtin_nontemporal_load(xr0 + 3072));
    float xi1 = bf2f(__builtin_nontemporal_load(xr1));
    float xf1 = bf2f(__builtin_nontemporal_load(xr1 + 1024));
    float xg1 = bf2f(__builtin_nontemporal_load(xr1 + 2048));
    float xo1 = bf2f(__builtin_nontemporal_load(xr1 + 3072));
    stage_commit(ht, sm.stage);
    __syncthreads();
    f4v a0 = {0.f,0.f,0.f,0.f}, a1 = {0.f,0.f,0.f,0.f};
    #pragma unroll 8
    for (int ks = 0; ks < 32; ++ks){
      int cb = (lk + ks * 32) * 2;
      s8v va0 = ldsA(sm.stage, lr,      cb);
      s8v va1 = ldsA(sm.stage, lr + 16, cb);
      s8v vb  = *(const s8v*)(Wb + ks * 32);
      mfma16(a0, va0, vb);
      mfma16(a1, va1, vb);
    }
    __syncthreads();
    #pragma unroll
    for (int r = 0; r < 4; r++){ sm.gx[g][rb + r][lr] = a0[r]; sm.gx[g][16 + rb + r][lr] = a1[r]; }
    __syncthreads();
    u16* ho = denc + (size_t)l * (BB * HH);
    {
      float gi = sm.gx[0][eb][ejj] + xi0;
      float gf = sm.gx[1][eb][ejj] + xf0;
      float gg = sm.gx[2][eb][ejj] + xg0;
      float go = sm.gx[3][eb][ejj] + xo0;
      cr0 = sigf(gf) * cr0 + sigf(gi) * tanhf(gg);
      float h = sigf(go) * tanhf(cr0);
      stcc_u16(&ho[eb * HH + jc + ejj], f2bf(h));
    }
    {
      int b2 = eb + 16;
      float gi = sm.gx[0][b2][ejj] + xi1;
      float gf = sm.gx[1][b2][ejj] + xf1;
      float gg = sm.gx[2][b2][ejj] + xg1;
      float go = sm.gx[3][b2][ejj] + xo1;
      cr1 = sigf(gf) * cr1 + sigf(gi) * tanhf(gg);
      float h = sigf(go) * tanhf(cr1);
      stcc_u16(&ho[b2 * HH + jc + ejj], f2bf(h));
    }
    gbar(bar, 64, epoch);
  }
}

// ---------- decoder: round-5 proven structure; nt loads on streaming tensors ----------
union SMemD {
  u16 stage[32768];
  float gx[4][32][17];
  struct { float ssc[128]; float swt[128]; } a;
};

__global__ void __launch_bounds__(256, 1) k_decoder(
    const u16* __restrict__ aproj, const u16* __restrict__ denc, const u16* __restrict__ obsp,
    const u16* __restrict__ W1c, const u16* __restrict__ W2w, const u16* __restrict__ WihL,
    const u16* __restrict__ WhhL, const float* __restrict__ blstm, const float* __restrict__ b2,
    const float* __restrict__ h0, const float* __restrict__ c0, const int* __restrict__ lens,
    float* __restrict__ hfR, u16* __restrict__ hbR, u16* __restrict__ ctxR,
    u16* __restrict__ mbR, u16* __restrict__ xbR, float* __restrict__ out, u32* bar)
{
  __shared__ SMemD sm;
  const int nb = blockIdx.x, tid = threadIdx.x;
  const int lane = tid & 63, w = tid >> 6;
  const int jc = nb * 16;
  const int lr = lane & 15, lk = (lane >> 4) * 8;
  const int eb = tid >> 4, ejj = tid & 15;
  const int rb = (lane >> 4) * 4;

  float cr0, cr1;
  {
    float hv0 = h0[eb * HH + jc + ejj];
    float hv1 = h0[(eb + 16) * HH + jc + ejj];
    stcc_f32(&hfR[eb * HH + jc + ejj], hv0);
    stcc_f32(&hfR[(eb + 16) * HH + jc + ejj], hv1);
    stcc_u16(&hbR[eb * HH + jc + ejj], f2bf(hv0));
    stcc_u16(&hbR[(eb + 16) * HH + jc + ejj], f2bf(hv1));
    cr0 = c0[eb * HH + jc + ejj];
    cr1 = c0[(eb + 16) * HH + jc + ejj];
  }
  u32 epoch = 0;
  gbar(bar, 64, epoch);

  s8v htmp[16];
  for (int t = 0; t < TT; ++t){
    const u16* ctxS = ctxR + (size_t)t * (BB * HH);
    const u16* mbS  = mbR  + (size_t)t * (BB * G4);
    const u16* xbS  = xbR  + (size_t)t * (BB * HH);
    const u16* hbS  = hbR  + (size_t)t * (BB * HH);
    const float* hfS= hfR  + (size_t)t * (BB * HH);

    // ---- Phase A: scores -> softmax -> ctx (blocks 0..31) ----
    if (nb < BB){
      const int b = nb;
      const int len = lens[b];
      float hr[16];
      const float* hp = hfS + b * HH + lane * 16;
      #pragma unroll
      for (int i = 0; i < 16; i++) hr[i] = hp[i];
      for (int i = 0; i < 32; ++i){
        int l = w * 32 + i;
        const u16* ap = aproj + ((size_t)(l * BB + b)) * HH + lane * 16;
        // aproj: stream-once per t, zero reuse -> non-temporal
        s8v v0 = __builtin_nontemporal_load((const s8v*)ap);
        s8v v1 = __builtin_nontemporal_load((const s8v*)(ap + 8));
        float s = 0.f;
        #pragma unroll
        for (int k = 0; k < 8; k++) s += bf2f((u16)v0[k]) * hr[k];
        #pragma unroll
        for (int k = 0; k < 8; k++) s += bf2f((u16)v1[k]) * hr[8 + k];
        #pragma unroll
        for (int off = 32; off > 0; off >>= 1) s += __shfl_down(s, off);
        if (lane == 0){
          s *= SCALE_;
          if (l >= len && l != 0) s = -__builtin_inff();
          sm.a.ssc[l] = s;
        }
      }
      __syncthreads();
      if (w == 0){
        float x0 = sm.a.ssc[lane], x1 = sm.a.ssc[lane + 64];
        float mx = fmaxf(x0, x1);
        #pragma unroll
        for (int off = 32; off > 0; off >>= 1) mx = fmaxf(mx, __shfl_xor(mx, off));
        float e0 = __expf(x0 - mx), e1 = __expf(x1 - mx);
        float smv = e0 + e1;
        #pragma unroll
        for (int off = 32; off > 0; off >>= 1) smv += __shfl_xor(smv, off);
        float inv = 1.f / smv;
        sm.a.swt[lane] = e0 * inv;
        sm.a.swt[lane + 64] = e1 * inv;
      }
      __syncthreads();
      int hh = tid * 4;
      float a0 = 0, a1 = 0, a2 = 0, a3 = 0;
      #pragma unroll 4
      for (int l = 0; l < LL; ++l){
        float wv = sm.a.swt[l];
        const u16* dp = denc + ((size_t)(l * BB + b)) * HH + hh;
        // denc: stream-once per t, zero reuse -> non-temporal
        s4v dv = __builtin_nontemporal_load((const s4v*)dp);
        a0 += wv * bf2f((u16)dv[0]); a1 += wv * bf2f((u16)dv[1]);
        a2 += wv * bf2f((u16)dv[2]); a3 += wv * bf2f((u16)dv[3]);
      }
      u2v pk;
      pk[0] = ((u32)f2bf(a1) << 16) | f2bf(a0);
      pk[1] = ((u32)f2bf(a3) << 16) | f2bf(a2);
      stcc_2x32((void*)(ctxS + b * HH + hh), pk);
    }
    gbar(bar, 64, epoch);

    // ---- Phase B: m = relu(ctx @ W1c^T + obs_part[t]) ----
    {
      s8v ct[16];
      stage_issue(ctxS, ct);
      const int col0 = nb * 64 + w * 16;
      const int cc = col0 + lr;
      float ov0[4], ov1[4];
      #pragma unroll
      for (int r = 0; r < 4; r++){
        // obsp: read exactly once over the whole launch -> non-temporal
        ov0[r] = bf2f(__builtin_nontemporal_load(&obsp[((size_t)(t * BB + rb + r)) * G4 + cc]));
        ov1[r] = bf2f(__builtin_nontemporal_load(&obsp[((size_t)(t * BB + rb + r + 16)) * G4 + cc]));
      }
      stage_commit(ct, sm.stage);
      __syncthreads();
      f4v a0 = {0.f,0.f,0.f,0.f}, a1 = {0.f,0.f,0.f,0.f};
      const u16* Bp = W1c + (size_t)(col0 + lr) * HH + lk;
      #pragma unroll 8
      for (int ks = 0; ks < 32; ++ks){
        int cb = (lk + ks * 32) * 2;
        s8v va0 = ldsA(sm.stage, lr,      cb);
        s8v va1 = ldsA(sm.stage, lr + 16, cb);
        s8v vb  = *(const s8v*)(Bp + ks * 32);
        mfma16(a0, va0, vb);
        mfma16(a1, va1, vb);
      }
      #pragma unroll
      for (int r = 0; r < 4; r++){
        int b = rb + r;
        stcc_u16((u16*)&mbS[b * G4 + cc], f2bf(fmaxf(a0[r] + ov0[r], 0.f)));
        stcc_u16((u16*)&mbS[(b + 16) * G4 + cc], f2bf(fmaxf(a1[r] + ov1[r], 0.f)));
      }
    }
    gbar(bar, 64, epoch);

    // ---- Phase C: x = relu(m @ W2^T + b2); waves K-split; 4 sequential chunks ----
    {
      f4v a0 = {0.f,0.f,0.f,0.f}, a1 = {0.f,0.f,0.f,0.f};
      u16* ldsw = sm.stage + w * 8192;       // per-wave 16KB slice
      const u16* Bp = W2w + (size_t)(jc + lr) * G4 + w * HH + lk;
      for (int c = 0; c < 4; ++c){
        s8v ct[16];
        stageC_issue(mbS + w * HH + c * 256, ct, lane);
        stageC_commit(ct, ldsw, lane);
        __syncthreads();
        #pragma unroll
        for (int ks = 0; ks < 8; ++ks){
          int cb = (lk + ks * 32) * 2;
          s8v va0 = ldsC(ldsw, lr,      cb);
          s8v va1 = ldsC(ldsw, lr + 16, cb);
          s8v vb  = *(const s8v*)(Bp + c * 256 + ks * 32);
          mfma16(a0, va0, vb);
          mfma16(a1, va1, vb);
        }
        __syncthreads();
      }
      #pragma unroll
      for (int r = 0; r < 4; r++){ sm.gx[w][rb + r][lr] = a0[r]; sm.gx[w][16 + rb + r][lr] = a1[r]; }
      __syncthreads();
      {
        float v0 = sm.gx[0][eb][ejj] + sm.gx[1][eb][ejj] + sm.gx[2][eb][ejj] + sm.gx[3][eb][ejj] + b2[jc + ejj];
        stcc_u16((u16*)&xbS[eb * HH + jc + ejj], f2bf(fmaxf(v0, 0.f)));
        int b2e = eb + 16;
        float v1 = sm.gx[0][b2e][ejj] + sm.gx[1][b2e][ejj] + sm.gx[2][b2e][ejj] + sm.gx[3][b2e][ejj] + b2[jc + ejj];
        stcc_u16((u16*)&xbS[b2e * HH + jc + ejj], f2bf(fmaxf(v1, 0.f)));
      }
      // prefetch h(t) tile for phase D (slot t written in D(t-1), plain cached)
      stage_issue(hbS, htmp);
    }
    gbar(bar, 64, epoch);

    // ---- Phase D: gates = x@WihL^T + h@WhhL^T + b; LSTM cell ----
    {
      s8v xt[16];
      stage_issue(xbS, xt);
      stage_commit(xt, sm.stage);
      __syncthreads();
      f4v a0 = {0.f,0.f,0.f,0.f}, a1 = {0.f,0.f,0.f,0.f};
      const u16* Bx = WihL + (size_t)(w * HH + jc + lr) * HH + lk;
      #pragma unroll 8
      for (int ks = 0; ks < 32; ++ks){
        int cb = (lk + ks * 32) * 2;
        s8v va0 = ldsA(sm.stage, lr,      cb);
        s8v va1 = ldsA(sm.stage, lr + 16, cb);
        s8v vb  = *(const s8v*)(Bx + ks * 32);
        mfma16(a0, va0, vb);
        mfma16(a1, va1, vb);
      }
      __syncthreads();
      stage_commit(htmp, sm.stage);
      __syncthreads();
      const u16* Bh = WhhL + (size_t)(w * HH + jc + lr) * HH + lk;
      #pragma unroll 8
      for (int ks = 0; ks < 32; ++ks){
        int cb = (lk + ks * 32) * 2;
        s8v va0 = ldsA(sm.stage, lr,      cb);
        s8v va1 = ldsA(sm.stage, lr + 16, cb);
        s8v vb  = *(const s8v*)(Bh + ks * 32);
        mfma16(a0, va0, vb);
        mfma16(a1, va1, vb);
      }
      __syncthreads();
      #pragma unroll
      for (int r = 0; r < 4; r++){ sm.gx[w][rb + r][lr] = a0[r]; sm.gx[w][16 + rb + r][lr] = a1[r]; }
      __syncthreads();
      u16* ho = hbR + (size_t)(t + 1) * (BB * HH);
      float* hfo = hfR + (size_t)(t + 1) * (BB * HH);
      {
        int col = jc + ejj;
        float gi = sm.gx[0][eb][ejj] + blstm[col];
        float gf = sm.gx[1][eb][ejj] + blstm[1024 + col];
        float gg = sm.gx[2][eb][ejj] + blstm[2048 + col];
        float go = sm.gx[3][eb][ejj] + blstm[3072 + col];
        cr0 = sigf(gf) * cr0 + sigf(gi) * tanhf(gg);
        float h = sigf(go) * tanhf(cr0);
        stcc_f32(&out[(size_t)t * (BB * HH) + eb * HH + col], h);
        stcc_f32(&hfo[eb * HH + col], h);
        stcc_u16(&ho[eb * HH + col], f2bf(h));
        if (t == TT - 1){ stcc_f32(&out[1048576 + eb * HH + col], h); stcc_f32(&out[1081344 + eb * HH + col], cr0); }
        int b2e = eb + 16;
        float gi2 = sm.gx[0][b2e][ejj] + blstm[col];
        float gf2 = sm.gx[1][b2e][ejj] + blstm[1024 + col];
        float gg2 = sm.gx[2][b2e][ejj] + blstm[2048 + col];
        float go2 = sm.gx[3][b2e][ejj] + blstm[3072 + col];
        cr1 = sigf(gf2) * cr1 + sigf(gi2) * tanhf(gg2);
        float h2 = sigf(go2) * tanhf(cr1);
        stcc_f32(&out[(size_t)t * (BB * HH) + b2e * HH + col], h2);
        stcc_f32(&hfo[b2e * HH + col], h2);
        stcc_u16(&ho[b2e * HH + col], f2bf(h2));
        if (t == TT - 1){ stcc_f32(&out[1048576 + b2e * HH + col], h2); stcc_f32(&out[1081344 + b2e * HH + col], cr1); }
      }
    }
    gbar(bar, 64, epoch);
  }
}

// ---------- workspace layout (bytes) ----------
static constexpr size_t oWihE = 0;
static constexpr size_t oWhhE = oWihE + 4194304;
static constexpr size_t oAttnW= oWhhE + 8388608;
static constexpr size_t oW1C  = oAttnW+ 2097152;
static constexpr size_t oW1O  = oW1C  + 8388608;
static constexpr size_t oW2   = oW1O  + 4194304;
static constexpr size_t oWihL = oW2   + 8388608;
static constexpr size_t oWhhL = oWihL + 8388608;
static constexpr size_t oBEnc = oWhhL + 8388608;
static constexpr size_t oBL   = oBEnc + 16384;
static constexpr size_t oDemoT= oBL   + 16384;
static constexpr size_t oObsB = oDemoT+ 4194304;
static constexpr size_t oXih  = oObsB + 1048576;
static constexpr size_t oObsP = oXih  + 33554432;
static constexpr size_t oDEnc = oObsP + 8388608;
static constexpr size_t oAPrj = oDEnc + 8388608;
static constexpr size_t oZE   = oAPrj + 8388608;
static constexpr size_t oHFR  = oZE   + 65536;           // 33 x 128KB
static constexpr size_t oHBR  = oHFR  + 4325376;         // 33 x 64KB
static constexpr size_t oCtxR = oHBR  + 2162688;         // 32 x 64KB
static constexpr size_t oMBR  = oCtxR + 2097152;         // 32 x 256KB
static constexpr size_t oXBR  = oMBR  + 8388608;         // 32 x 64KB
static constexpr size_t oBar  = oXBR  + 2097152;

extern "C" void kernel_launch(void* const* d_in, const int* in_sizes, int n_in,
                              void* d_out, int out_size, void* d_ws, size_t ws_size,
                              hipStream_t stream)
{
  const float* demo = (const float*)d_in[0];
  const int*   lens = (const int*)  d_in[1];
  const float* obs  = (const float*)d_in[2];
  const float* h0   = (const float*)d_in[3];
  const float* c0   = (const float*)d_in[4];
  const float* eWih = (const float*)d_in[5];
  const float* eWhh = (const float*)d_in[6];
  const float* eBih = (const float*)d_in[7];
  const float* eBhh = (const float*)d_in[8];
  const float* aW   = (const float*)d_in[9];
  const float* aB   = (const float*)d_in[10];
  const float* W1   = (const float*)d_in[11];
  const float* B1   = (const float*)d_in[12];
  const float* W2   = (const float*)d_in[13];
  const float* B2   = (const float*)d_in[14];
  const float* lWih = (const float*)d_in[15];
  const float* lWhh = (const float*)d_in[16];
  const float* lBih = (const float*)d_in[17];
  const float* lBhh = (const float*)d_in[18];

  char* ws = (char*)d_ws;
  u16*  WihE = (u16*)(ws + oWihE);
  u16*  WhhE = (u16*)(ws + oWhhE);
  u16*  AttnW= (u16*)(ws + oAttnW);
  u16*  W1C  = (u16*)(ws + oW1C);
  u16*  W1O  = (u16*)(ws + oW1O);
  u16*  W2w  = (u16*)(ws + oW2);
  u16*  WihL = (u16*)(ws + oWihL);
  u16*  WhhL = (u16*)(ws + oWhhL);
  float* BEnc= (float*)(ws + oBEnc);
  float* BL  = (float*)(ws + oBL);
  u16*  DemoT= (u16*)(ws + oDemoT);
  u16*  ObsB = (u16*)(ws + oObsB);
  u16*  Xih  = (u16*)(ws + oXih);
  u16*  ObsP = (u16*)(ws + oObsP);
  u16*  DEnc = (u16*)(ws + oDEnc);
  u16*  APrj = (u16*)(ws + oAPrj);
  u16*  ZE   = (u16*)(ws + oZE);
  float* HFR = (float*)(ws + oHFR);
  u16*  HBR  = (u16*)(ws + oHBR);
  u16*  CtxR = (u16*)(ws + oCtxR);
  u16*  MBR  = (u16*)(ws + oMBR);
  u16*  XBR  = (u16*)(ws + oXBR);
  u32*  Bar  = (u32*)(ws + oBar);

  k_convert<<<1024, 256, 0, stream>>>(eWih, WihE, G4 * FF);
  k_convert<<<1024, 256, 0, stream>>>(eWhh, WhhE, G4 * HH);
  k_convert<<<512,  256, 0, stream>>>(aW,   AttnW, HH * HH);
  k_split_w1<<<1024, 256, 0, stream>>>(W1, W1C, W1O);
  k_convert<<<1024, 256, 0, stream>>>(W2,   W2w,  HH * G4);
  k_convert<<<1024, 256, 0, stream>>>(lWih, WihL, G4 * HH);
  k_convert<<<1024, 256, 0, stream>>>(lWhh, WhhL, G4 * HH);
  k_addb<<<16, 256, 0, stream>>>(eBih, eBhh, BEnc, G4);
  k_addb<<<16, 256, 0, stream>>>(lBih, lBhh, BL, G4);
  k_demo_t<<<1024, 256, 0, stream>>>(demo, DemoT);
  k_convert<<<512, 256, 0, stream>>>(obs, ObsB, TT * BB * FF);
  hipMemsetAsync(Bar, 0, 256, stream);

  {
    dim3 g(LL * BB / 128, G4 / 128);
    k_gemm_bt<0><<<g, 256, 0, stream>>>(DemoT, WihE, BEnc, Xih, LL * BB, G4, FF);
  }
  {
    dim3 g(TT * BB / 128, G4 / 128);
    k_gemm_bt<0><<<g, 256, 0, stream>>>(ObsB, W1O, B1, ObsP, TT * BB, G4, FF);
  }

  k_encoder<<<64, 256, 0, stream>>>(WhhE, Xih, ZE, DEnc, Bar);

  {
    dim3 g(LL * BB / 128, HH / 128);
    k_gemm_bt<0><<<g, 256, 0, stream>>>(DEnc, AttnW, aB, APrj, LL * BB, HH, HH);
  }

  k_decoder<<<64, 256, 0, stream>>>(APrj, DEnc, ObsP, W1C, W2w, WihL, WhhL,
                                    BL, B2, h0, c0, lens,
                                    HFR, HBR, CtxR, MBR, XBR, (float*)d_out, Bar + 16);
}

// Round 9
// 2740.760 us; speedup vs baseline: 1.3973x; 1.3973x over previous
//
#include <hip/hip_runtime.h>

typedef unsigned short u16;
typedef unsigned int   u32;
typedef short s8v __attribute__((ext_vector_type(8)));
typedef short s4v __attribute__((ext_vector_type(4)));
typedef float f4v __attribute__((ext_vector_type(4)));

// Problem constants
#define TT 32
#define BB 32
#define LL 128
#define FF 512
#define HH 1024
#define G4 4096
#define SCALE_ 0.08838834764831845f   // 1/sqrt(128)

// ---------- helpers ----------
__device__ __forceinline__ u16 f2bf(float f){
  u32 u = __float_as_uint(f);
  u32 r = u + 0x7fffu + ((u >> 16) & 1u);   // RNE
  return (u16)(r >> 16);
}
__device__ __forceinline__ float bf2f(u16 s){ return __uint_as_float(((u32)s) << 16); }
__device__ __forceinline__ float sigf(float x){ return 1.f / (1.f + __expf(-x)); }

__device__ __forceinline__ void mfma16(f4v& d, s8v a, s8v b){
  asm("v_mfma_f32_16x16x32_bf16 %0, %1, %2, %0" : "+v"(d) : "v"(a), "v"(b));
}

typedef __attribute__((address_space(3))) u32 as3u32;
typedef __attribute__((address_space(1))) u32 as1u32;
__device__ __forceinline__ void glds16(const u16* g, u16* l){
  __builtin_amdgcn_global_load_lds((const as1u32*)g, (as3u32*)l, 16, 0, 0);
}

// ---- producer stores: write-through to LLC (coherent point) ----
__device__ __forceinline__ void stcc_u16(u16* p, u16 v){
  u32 vv = v;
  asm volatile("global_store_short %0, %1, off sc0 sc1" :: "v"(p), "v"(vv) : "memory");
}
__device__ __forceinline__ void stcc_u32(void* p, u32 v){
  asm volatile("global_store_dword %0, %1, off sc0 sc1" :: "v"(p), "v"(v) : "memory");
}
__device__ __forceinline__ void stcc_f32(float* p, float v){
  asm volatile("global_store_dword %0, %1, off sc0 sc1" :: "v"(p), "v"(v) : "memory");
}
__device__ __forceinline__ u32 poll_ld(const u32* p){
  u32 v;
  asm volatile("global_load_dword %0, %1, off sc0 sc1\n\ts_waitcnt vmcnt(0)"
               : "=v"(v) : "v"(p) : "memory");
  return v;
}

// grid barrier: vmcnt(0) drains producer sc0sc1 stores (release);
// sc0sc1 poll is the acquire. Consumers use PLAIN cached loads of
// write-once rotated buffers (never stale; replay-invariant values).
__device__ __forceinline__ void gbar(u32* cnt, u32 nblk, u32& epoch){
  asm volatile("s_waitcnt vmcnt(0)" ::: "memory");
  __syncthreads();
  ++epoch;
  if (threadIdx.x == 0){
    atomicAdd(cnt, 1u);
    u32 target = epoch * nblk;
    while (poll_ld(cnt) < target) __builtin_amdgcn_s_sleep(1);
  }
  __syncthreads();
}

// ---------- 512-thread staging: [32][1024] u16 -> LDS, XOR swizzle ----------
// thread (row = tid>>4, s0 = tid&15) loads 8 x s8v: cols s0*8 + i*128
__device__ __forceinline__ void stage512_issueS(const u16* __restrict__ src, s8v* tmp, int rstride){
  const int tid = threadIdx.x;
  const int row = tid >> 4, s0 = tid & 15;
  const u16* p = src + (size_t)row * rstride + s0 * 8;
  #pragma unroll
  for (int i = 0; i < 8; i++) tmp[i] = *(const s8v*)(p + i * 128);
}
__device__ __forceinline__ void stage512_commit(const s8v* tmp, u16* lds){
  const int tid = threadIdx.x;
  const int row = tid >> 4, s0 = tid & 15;
  char* base = (char*)lds + (row << 11);
  u32 x = (u32)(row & 15) << 4;
  #pragma unroll
  for (int i = 0; i < 8; i++){
    u32 cb = (u32)(s0 + 16 * i) << 4;
    *(s8v*)(base + (cb ^ x)) = tmp[i];
  }
}
__device__ __forceinline__ s8v ldsA(const u16* lds, int row, int cb){
  return *(const s8v*)((const char*)lds + (row << 11) + (cb ^ ((row & 15) << 4)));
}

// ---------- prep kernels ----------
__global__ void k_convert(const float* __restrict__ src, u16* __restrict__ dst, int n){
  int i = blockIdx.x * blockDim.x + threadIdx.x;
  int st = gridDim.x * blockDim.x;
  for (; i < n; i += st) dst[i] = f2bf(src[i]);
}
__global__ void k_split_w1(const float* __restrict__ w1, u16* __restrict__ w1c, u16* __restrict__ w1o){
  int i = blockIdx.x * blockDim.x + threadIdx.x;
  int st = gridDim.x * blockDim.x;
  const int n = G4 * (FF + HH);
  for (; i < n; i += st){
    int j = i / 1536, k = i - j * 1536;
    u16 v = f2bf(w1[i]);
    if (k < HH) w1c[j * HH + k] = v;
    else        w1o[j * FF + (k - HH)] = v;
  }
}
__global__ void k_addb(const float* __restrict__ a, const float* __restrict__ b,
                       float* __restrict__ o, int n){
  int i = blockIdx.x * blockDim.x + threadIdx.x;
  int st = gridDim.x * blockDim.x;
  for (; i < n; i += st) o[i] = a[i] + b[i];
}
__global__ void k_demo_t(const float* __restrict__ d, u16* __restrict__ o){
  const int n = LL * BB * FF;
  int i = blockIdx.x * blockDim.x + threadIdx.x;
  int st = gridDim.x * blockDim.x;
  for (; i < n; i += st){
    int f = i & 511;
    int row = i >> 9;
    int l = row >> 5, b = row & 31;
    o[i] = f2bf(d[(size_t)b * (LL * FF) + l * FF + f]);
  }
}

// ---------- generic GEMM (unchanged, proven) ----------
template<int RELU>
__global__ void __launch_bounds__(256) k_gemm_bt(const u16* __restrict__ A, const u16* __restrict__ B,
        const float* __restrict__ bias, u16* __restrict__ C, int M, int N, int K)
{
  __shared__ u16 As[128 * 64];
  __shared__ u16 Bs[128 * 64];
  const int tid = threadIdx.x;
  const int lane = tid & 63, wave = tid >> 6;
  const int m0 = blockIdx.x * 128, n0 = blockIdx.y * 128;
  const int wm = wave >> 1, wn = wave & 1;
  const int lr = lane & 15, lk = (lane >> 4) * 8;
  f4v acc[4][4];
  #pragma unroll
  for (int i = 0; i < 4; i++)
    #pragma unroll
    for (int j = 0; j < 4; j++) acc[i][j] = f4v{0.f, 0.f, 0.f, 0.f};

  for (int kt = 0; kt < K; kt += 64){
    #pragma unroll
    for (int i = 0; i < 4; i++){
      int c = tid + i * 256;
      int row = c >> 3, cc = (c & 7) * 8;
      glds16(A + (size_t)(m0 + row) * K + kt + cc, &As[c * 8]);
      glds16(B + (size_t)(n0 + row) * K + kt + cc, &Bs[c * 8]);
    }
    __syncthreads();
    #pragma unroll
    for (int ks = 0; ks < 2; ++ks){
      int ko = ks * 32 + lk;
      s8v av[4], bv[4];
      #pragma unroll
      for (int m = 0; m < 4; m++) av[m] = *(const s8v*)&As[(wm * 64 + m * 16 + lr) * 64 + ko];
      #pragma unroll
      for (int n = 0; n < 4; n++) bv[n] = *(const s8v*)&Bs[(wn * 64 + n * 16 + lr) * 64 + ko];
      #pragma unroll
      for (int m = 0; m < 4; m++)
        #pragma unroll
        for (int n = 0; n < 4; n++) mfma16(acc[m][n], av[m], bv[n]);
    }
    __syncthreads();
  }
  const int r0 = (lane >> 4) * 4;
  #pragma unroll
  for (int m = 0; m < 4; m++){
    #pragma unroll
    for (int n = 0; n < 4; n++){
      int col = n0 + wn * 64 + n * 16 + lr;
      float bc = bias[col];
      #pragma unroll
      for (int r = 0; r < 4; r++){
        int row = m0 + wm * 64 + m * 16 + r0 + r;
        float v = acc[m][n][r] + bc;
        if (RELU) v = fmaxf(v, 0.f);
        C[(size_t)row * N + col] = f2bf(v);
      }
    }
  }
}

// ---------- encoder: 512 threads, 8 waves (gate = w>>1, K-half = w&1) ----------
union SMemE { u16 stage[32768]; float gx[8][32][17]; };

__global__ void __launch_bounds__(512, 1) k_encoder(const u16* __restrict__ Whh, const u16* __restrict__ Xih,
      u16* __restrict__ zslot, u16* __restrict__ denc, u32* bar)
{
  __shared__ SMemE sm;
  const int nb = blockIdx.x, tid = threadIdx.x;
  const int lane = tid & 63, w = tid >> 6;
  const int jc = nb * 16;
  const int lr = lane & 15, lk = (lane >> 4) * 8;
  const int eb = tid >> 4, ejj = tid & 15;   // elementwise: batch, col (1 elem/thread)
  const int rb = (lane >> 4) * 4;

  stcc_u16(&zslot[eb * HH + jc + ejj], 0);
  float cr = 0.f;
  u32 epoch = 0;
  gbar(bar, 64, epoch);

  const int kh = (w & 1) * 512;
  const u16* Wb = Whh + (size_t)((w >> 1) * HH + jc + lr) * HH + kh + lk;
  for (int l = 0; l < LL; ++l){
    const u16* hb = (l == 0) ? zslot : (denc + (size_t)(l - 1) * (BB * HH));
    s8v ht[8];
    stage512_issueS(hb, ht, HH);
    // hoist Xih gate loads (plain cached)
    const u16* xr = Xih + ((size_t)(l * BB + eb)) * G4 + jc + ejj;
    float xi = bf2f(xr[0]), xf = bf2f(xr[1024]), xg = bf2f(xr[2048]), xo = bf2f(xr[3072]);
    stage512_commit(ht, sm.stage);
    __syncthreads();
    f4v a0 = {0.f,0.f,0.f,0.f}, a1 = {0.f,0.f,0.f,0.f};
    #pragma unroll 8
    for (int ks = 0; ks < 16; ++ks){
      int cb = (kh + lk + ks * 32) * 2;
      s8v va0 = ldsA(sm.stage, lr,      cb);
      s8v va1 = ldsA(sm.stage, lr + 16, cb);
      s8v vb  = *(const s8v*)(Wb + ks * 32);
      mfma16(a0, va0, vb);
      mfma16(a1, va1, vb);
    }
    __syncthreads();              // stage dead -> gx overlay
    #pragma unroll
    for (int r = 0; r < 4; r++){ sm.gx[w][rb + r][lr] = a0[r]; sm.gx[w][16 + rb + r][lr] = a1[r]; }
    __syncthreads();
    {
      float gi = sm.gx[0][eb][ejj] + sm.gx[1][eb][ejj] + xi;
      float gf = sm.gx[2][eb][ejj] + sm.gx[3][eb][ejj] + xf;
      float gg = sm.gx[4][eb][ejj] + sm.gx[5][eb][ejj] + xg;
      float go = sm.gx[6][eb][ejj] + sm.gx[7][eb][ejj] + xo;
      cr = sigf(gf) * cr + sigf(gi) * tanhf(gg);
      float h = sigf(go) * tanhf(cr);
      stcc_u16(&denc[(size_t)l * (BB * HH) + eb * HH + jc + ejj], f2bf(h));
    }
    gbar(bar, 64, epoch);
  }
}

// ---------- decoder: 512 threads, 8 waves; round-5 phases with K-pair splits ----------
union SMemD {
  u16 stage[32768];
  float gx[8][32][17];
  struct { float ssc[128]; float swt[128]; } a;
};

__global__ void __launch_bounds__(512, 1) k_decoder(
    const u16* __restrict__ aproj, const u16* __restrict__ denc, const u16* __restrict__ obsp,
    const u16* __restrict__ W1c, const u16* __restrict__ W2w, const u16* __restrict__ WihL,
    const u16* __restrict__ WhhL, const float* __restrict__ blstm, const float* __restrict__ b2,
    const float* __restrict__ h0, const float* __restrict__ c0, const int* __restrict__ lens,
    float* __restrict__ hfR, u16* __restrict__ hbR, u16* __restrict__ ctxR,
    u16* __restrict__ mbR, u16* __restrict__ xbR, float* __restrict__ out, u32* bar)
{
  __shared__ SMemD sm;
  const int nb = blockIdx.x, tid = threadIdx.x;
  const int lane = tid & 63, w = tid >> 6;
  const int jc = nb * 16;
  const int lr = lane & 15, lk = (lane >> 4) * 8;
  const int eb = tid >> 4, ejj = tid & 15;   // elementwise map (1 elem/thread)
  const int rb = (lane >> 4) * 4;

  float cr;
  {
    float hv = h0[eb * HH + jc + ejj];
    stcc_f32(&hfR[eb * HH + jc + ejj], hv);
    stcc_u16(&hbR[eb * HH + jc + ejj], f2bf(hv));
    cr = c0[eb * HH + jc + ejj];
  }
  u32 epoch = 0;
  gbar(bar, 64, epoch);

  for (int t = 0; t < TT; ++t){
    const u16* ctxS = ctxR + (size_t)t * (BB * HH);
    const u16* mbS  = mbR  + (size_t)t * (BB * G4);
    const u16* xbS  = xbR  + (size_t)t * (BB * HH);
    const u16* hbS  = hbR  + (size_t)t * (BB * HH);
    const float* hfS= hfR  + (size_t)t * (BB * HH);

    // ---- Phase A: scores -> softmax -> ctx (blocks 0..31) ----
    if (nb < BB){
      const int b = nb;
      const int len = lens[b];
      float hr[16];
      const float* hp = hfS + b * HH + lane * 16;
      #pragma unroll
      for (int i = 0; i < 16; i++) hr[i] = hp[i];
      for (int i = 0; i < 16; ++i){
        int l = w * 16 + i;
        const u16* ap = aproj + ((size_t)(l * BB + b)) * HH + lane * 16;
        s8v v0 = *(const s8v*)ap;
        s8v v1 = *(const s8v*)(ap + 8);
        float s = 0.f;
        #pragma unroll
        for (int k = 0; k < 8; k++) s += bf2f((u16)v0[k]) * hr[k];
        #pragma unroll
        for (int k = 0; k < 8; k++) s += bf2f((u16)v1[k]) * hr[8 + k];
        #pragma unroll
        for (int off = 32; off > 0; off >>= 1) s += __shfl_down(s, off);
        if (lane == 0){
          s *= SCALE_;
          if (l >= len && l != 0) s = -__builtin_inff();
          sm.a.ssc[l] = s;
        }
      }
      __syncthreads();
      if (w == 0){
        float x0 = sm.a.ssc[lane], x1 = sm.a.ssc[lane + 64];
        float mx = fmaxf(x0, x1);
        #pragma unroll
        for (int off = 32; off > 0; off >>= 1) mx = fmaxf(mx, __shfl_xor(mx, off));
        float e0 = __expf(x0 - mx), e1 = __expf(x1 - mx);
        float smv = e0 + e1;
        #pragma unroll
        for (int off = 32; off > 0; off >>= 1) smv += __shfl_xor(smv, off);
        float inv = 1.f / smv;
        sm.a.swt[lane] = e0 * inv;
        sm.a.swt[lane + 64] = e1 * inv;
      }
      __syncthreads();
      int hh = tid * 2;
      float a0 = 0, a1 = 0;
      #pragma unroll 4
      for (int l = 0; l < LL; ++l){
        float wv = sm.a.swt[l];
        u32 dv = *(const u32*)(denc + ((size_t)(l * BB + b)) * HH + hh);
        a0 += wv * bf2f((u16)(dv & 0xffff));
        a1 += wv * bf2f((u16)(dv >> 16));
      }
      u32 pk = ((u32)f2bf(a1) << 16) | f2bf(a0);
      stcc_u32((void*)(ctxS + b * HH + hh), pk);
    }
    gbar(bar, 64, epoch);

    // ---- Phase B: m = relu(ctx @ W1c^T + obsp[t]); 8 waves = 4 col-groups x 2 K-halves ----
    {
      s8v ct[8];
      stage512_issueS(ctxS, ct, HH);
      stage512_commit(ct, sm.stage);
      __syncthreads();
      const int col0 = nb * 64 + (w >> 1) * 16;
      const int kh = (w & 1) * 512;
      f4v a0 = {0.f,0.f,0.f,0.f}, a1 = {0.f,0.f,0.f,0.f};
      const u16* Bp = W1c + (size_t)(col0 + lr) * HH + kh + lk;
      #pragma unroll 8
      for (int ks = 0; ks < 16; ++ks){
        int cb = (kh + lk + ks * 32) * 2;
        s8v va0 = ldsA(sm.stage, lr,      cb);
        s8v va1 = ldsA(sm.stage, lr + 16, cb);
        s8v vb  = *(const s8v*)(Bp + ks * 32);
        mfma16(a0, va0, vb);
        mfma16(a1, va1, vb);
      }
      __syncthreads();            // stage dead -> gx overlay
      #pragma unroll
      for (int r = 0; r < 4; r++){ sm.gx[w][rb + r][lr] = a0[r]; sm.gx[w][16 + rb + r][lr] = a1[r]; }
      __syncthreads();
      #pragma unroll
      for (int cg = 0; cg < 4; ++cg){
        int col = nb * 64 + cg * 16 + ejj;
        float v = sm.gx[2 * cg][eb][ejj] + sm.gx[2 * cg + 1][eb][ejj]
                + bf2f(obsp[((size_t)(t * BB + eb)) * G4 + col]);
        stcc_u16((u16*)&mbS[eb * G4 + col], f2bf(fmaxf(v, 0.f)));
      }
    }
    gbar(bar, 64, epoch);

    // ---- Phase C: x = relu(m @ W2^T + b2); 4 staged K-quarters, 8 waves x 128-K slices ----
    {
      f4v a0 = {0.f,0.f,0.f,0.f}, a1 = {0.f,0.f,0.f,0.f};
      for (int q = 0; q < 4; ++q){
        s8v ct[8];
        stage512_issueS(mbS + q * 1024, ct, G4);
        stage512_commit(ct, sm.stage);
        __syncthreads();
        const u16* Bp = W2w + (size_t)(jc + lr) * G4 + q * 1024 + w * 128 + lk;
        #pragma unroll
        for (int ks = 0; ks < 4; ++ks){
          int cb = (w * 128 + lk + ks * 32) * 2;
          s8v va0 = ldsA(sm.stage, lr,      cb);
          s8v va1 = ldsA(sm.stage, lr + 16, cb);
          s8v vb  = *(const s8v*)(Bp + ks * 32);
          mfma16(a0, va0, vb);
          mfma16(a1, va1, vb);
        }
        __syncthreads();
      }
      #pragma unroll
      for (int r = 0; r < 4; r++){ sm.gx[w][rb + r][lr] = a0[r]; sm.gx[w][16 + rb + r][lr] = a1[r]; }
      __syncthreads();
      {
        float v = b2[jc + ejj];
        #pragma unroll
        for (int g = 0; g < 8; ++g) v += sm.gx[g][eb][ejj];
        stcc_u16((u16*)&xbS[eb * HH + jc + ejj], f2bf(fmaxf(v, 0.f)));
      }
    }
    gbar(bar, 64, epoch);

    // ---- Phase D: gates = x@WihL^T + h@WhhL^T; 8 waves = 4 gates x 2 K-halves ----
    {
      s8v xt[8], ht[8];
      stage512_issueS(xbS, xt, HH);
      stage512_issueS(hbS, ht, HH);
      stage512_commit(xt, sm.stage);
      __syncthreads();
      const int kh = (w & 1) * 512;
      f4v a0 = {0.f,0.f,0.f,0.f}, a1 = {0.f,0.f,0.f,0.f};
      const u16* Bx = WihL + (size_t)((w >> 1) * HH + jc + lr) * HH + kh + lk;
      #pragma unroll 8
      for (int ks = 0; ks < 16; ++ks){
        int cb = (kh + lk + ks * 32) * 2;
        s8v va0 = ldsA(sm.stage, lr,      cb);
        s8v va1 = ldsA(sm.stage, lr + 16, cb);
        s8v vb  = *(const s8v*)(Bx + ks * 32);
        mfma16(a0, va0, vb);
        mfma16(a1, va1, vb);
      }
      __syncthreads();
      stage512_commit(ht, sm.stage);
      __syncthreads();
      const u16* Bh = WhhL + (size_t)((w >> 1) * HH + jc + lr) * HH + kh + lk;
      #pragma unroll 8
      for (int ks = 0; ks < 16; ++ks){
        int cb = (kh + lk + ks * 32) * 2;
        s8v va0 = ldsA(sm.stage, lr,      cb);
        s8v va1 = ldsA(sm.stage, lr + 16, cb);
        s8v vb  = *(const s8v*)(Bh + ks * 32);
        mfma16(a0, va0, vb);
        mfma16(a1, va1, vb);
      }
      __syncthreads();
      #pragma unroll
      for (int r = 0; r < 4; r++){ sm.gx[w][rb + r][lr] = a0[r]; sm.gx[w][16 + rb + r][lr] = a1[r]; }
      __syncthreads();
      {
        int col = jc + ejj;
        float gi = sm.gx[0][eb][ejj] + sm.gx[1][eb][ejj] + blstm[col];
        float gf = sm.gx[2][eb][ejj] + sm.gx[3][eb][ejj] + blstm[1024 + col];
        float gg = sm.gx[4][eb][ejj] + sm.gx[5][eb][ejj] + blstm[2048 + col];
        float go = sm.gx[6][eb][ejj] + sm.gx[7][eb][ejj] + blstm[3072 + col];
        cr = sigf(gf) * cr + sigf(gi) * tanhf(gg);
        float h = sigf(go) * tanhf(cr);
        stcc_f32(&out[(size_t)t * (BB * HH) + eb * HH + col], h);
        stcc_f32(&hfR[(size_t)(t + 1) * (BB * HH) + eb * HH + col], h);
        stcc_u16(&hbR[(size_t)(t + 1) * (BB * HH) + eb * HH + col], f2bf(h));
        if (t == TT - 1){
          stcc_f32(&out[1048576 + eb * HH + col], h);
          stcc_f32(&out[1081344 + eb * HH + col], cr);
        }
      }
    }
    gbar(bar, 64, epoch);
  }
}

// ---------- workspace layout (round-5 proven, no aliases) ----------
static constexpr size_t oWihE = 0;
static constexpr size_t oWhhE = oWihE + 4194304;
static constexpr size_t oAttnW= oWhhE + 8388608;
static constexpr size_t oW1C  = oAttnW+ 2097152;
static constexpr size_t oW1O  = oW1C  + 8388608;
static constexpr size_t oW2   = oW1O  + 4194304;
static constexpr size_t oWihL = oW2   + 8388608;
static constexpr size_t oWhhL = oWihL + 8388608;
static constexpr size_t oBEnc = oWhhL + 8388608;
static constexpr size_t oBL   = oBEnc + 16384;
static constexpr size_t oDemoT= oBL   + 16384;
static constexpr size_t oObsB = oDemoT+ 4194304;
static constexpr size_t oXih  = oObsB + 1048576;
static constexpr size_t oObsP = oXih  + 33554432;
static constexpr size_t oDEnc = oObsP + 8388608;
static constexpr size_t oAPrj = oDEnc + 8388608;
static constexpr size_t oZE   = oAPrj + 8388608;
static constexpr size_t oHFR  = oZE   + 65536;
static constexpr size_t oHBR  = oHFR  + 4325376;
static constexpr size_t oCtxR = oHBR  + 2162688;
static constexpr size_t oMBR  = oCtxR + 2097152;
static constexpr size_t oXBR  = oMBR  + 8388608;
static constexpr size_t oBar  = oXBR  + 2097152;

extern "C" void kernel_launch(void* const* d_in, const int* in_sizes, int n_in,
                              void* d_out, int out_size, void* d_ws, size_t ws_size,
                              hipStream_t stream)
{
  const float* demo = (const float*)d_in[0];
  const int*   lens = (const int*)  d_in[1];
  const float* obs  = (const float*)d_in[2];
  const float* h0   = (const float*)d_in[3];
  const float* c0   = (const float*)d_in[4];
  const float* eWih = (const float*)d_in[5];
  const float* eWhh = (const float*)d_in[6];
  const float* eBih = (const float*)d_in[7];
  const float* eBhh = (const float*)d_in[8];
  const float* aW   = (const float*)d_in[9];
  const float* aB   = (const float*)d_in[10];
  const float* W1   = (const float*)d_in[11];
  const float* B1   = (const float*)d_in[12];
  const float* W2   = (const float*)d_in[13];
  const float* B2   = (const float*)d_in[14];
  const float* lWih = (const float*)d_in[15];
  const float* lWhh = (const float*)d_in[16];
  const float* lBih = (const float*)d_in[17];
  const float* lBhh = (const float*)d_in[18];

  char* ws = (char*)d_ws;
  u16*  WihE = (u16*)(ws + oWihE);
  u16*  WhhE = (u16*)(ws + oWhhE);
  u16*  AttnW= (u16*)(ws + oAttnW);
  u16*  W1C  = (u16*)(ws + oW1C);
  u16*  W1O  = (u16*)(ws + oW1O);
  u16*  W2w  = (u16*)(ws + oW2);
  u16*  WihL = (u16*)(ws + oWihL);
  u16*  WhhL = (u16*)(ws + oWhhL);
  float* BEnc= (float*)(ws + oBEnc);
  float* BL  = (float*)(ws + oBL);
  u16*  DemoT= (u16*)(ws + oDemoT);
  u16*  ObsB = (u16*)(ws + oObsB);
  u16*  Xih  = (u16*)(ws + oXih);
  u16*  ObsP = (u16*)(ws + oObsP);
  u16*  DEnc = (u16*)(ws + oDEnc);
  u16*  APrj = (u16*)(ws + oAPrj);
  u16*  ZE   = (u16*)(ws + oZE);
  float* HFR = (float*)(ws + oHFR);
  u16*  HBR  = (u16*)(ws + oHBR);
  u16*  CtxR = (u16*)(ws + oCtxR);
  u16*  MBR  = (u16*)(ws + oMBR);
  u16*  XBR  = (u16*)(ws + oXBR);
  u32*  Bar  = (u32*)(ws + oBar);

  k_convert<<<1024, 256, 0, stream>>>(eWih, WihE, G4 * FF);
  k_convert<<<1024, 256, 0, stream>>>(eWhh, WhhE, G4 * HH);
  k_convert<<<512,  256, 0, stream>>>(aW,   AttnW, HH * HH);
  k_split_w1<<<1024, 256, 0, stream>>>(W1, W1C, W1O);
  k_convert<<<1024, 256, 0, stream>>>(W2,   W2w,  HH * G4);
  k_convert<<<1024, 256, 0, stream>>>(lWih, WihL, G4 * HH);
  k_convert<<<1024, 256, 0, stream>>>(lWhh, WhhL, G4 * HH);
  k_addb<<<16, 256, 0, stream>>>(eBih, eBhh, BEnc, G4);
  k_addb<<<16, 256, 0, stream>>>(lBih, lBhh, BL, G4);
  k_demo_t<<<1024, 256, 0, stream>>>(demo, DemoT);
  k_convert<<<512, 256, 0, stream>>>(obs, ObsB, TT * BB * FF);
  hipMemsetAsync(Bar, 0, 256, stream);

  {
    dim3 g(LL * BB / 128, G4 / 128);
    k_gemm_bt<0><<<g, 256, 0, stream>>>(DemoT, WihE, BEnc, Xih, LL * BB, G4, FF);
  }
  {
    dim3 g(TT * BB / 128, G4 / 128);
    k_gemm_bt<0><<<g, 256, 0, stream>>>(ObsB, W1O, B1, ObsP, TT * BB, G4, FF);
  }

  k_encoder<<<64, 512, 0, stream>>>(WhhE, Xih, ZE, DEnc, Bar);

  {
    dim3 g(LL * BB / 128, HH / 128);
    k_gemm_bt<0><<<g, 256, 0, stream>>>(DEnc, AttnW, aB, APrj, LL * BB, HH, HH);
  }

  k_decoder<<<64, 512, 0, stream>>>(APrj, DEnc, ObsP, W1C, W2w, WihL, WhhL,
                                    BL, B2, h0, c0, lens,
                                    HFR, HBR, CtxR, MBR, XBR, (float*)d_out, Bar + 16);
}

// Round 10
// 2699.685 us; speedup vs baseline: 1.4186x; 1.0152x over previous
//
#include <hip/hip_runtime.h>

typedef unsigned short u16;
typedef unsigned int   u32;
typedef short s8v __attribute__((ext_vector_type(8)));
typedef short s4v __attribute__((ext_vector_type(4)));
typedef float f4v __attribute__((ext_vector_type(4)));

// Problem constants
#define TT 32
#define BB 32
#define LL 128
#define FF 512
#define HH 1024
#define G4 4096
#define SCALE_ 0.08838834764831845f   // 1/sqrt(128)

// ---------- helpers ----------
__device__ __forceinline__ u16 f2bf(float f){
  u32 u = __float_as_uint(f);
  u32 r = u + 0x7fffu + ((u >> 16) & 1u);   // RNE
  return (u16)(r >> 16);
}
__device__ __forceinline__ float bf2f(u16 s){ return __uint_as_float(((u32)s) << 16); }
__device__ __forceinline__ float sigf(float x){ return 1.f / (1.f + __expf(-x)); }

__device__ __forceinline__ void mfma16(f4v& d, s8v a, s8v b){
  asm("v_mfma_f32_16x16x32_bf16 %0, %1, %2, %0" : "+v"(d) : "v"(a), "v"(b));
}

typedef __attribute__((address_space(3))) u32 as3u32;
typedef __attribute__((address_space(1))) u32 as1u32;
__device__ __forceinline__ void glds16(const u16* g, u16* l){
  __builtin_amdgcn_global_load_lds((const as1u32*)g, (as3u32*)l, 16, 0, 0);
}

// ---- producer stores: write-through to LLC (coherent point) ----
__device__ __forceinline__ void stcc_u16(u16* p, u16 v){
  u32 vv = v;
  asm volatile("global_store_short %0, %1, off sc0 sc1" :: "v"(p), "v"(vv) : "memory");
}
__device__ __forceinline__ void stcc_u32(void* p, u32 v){
  asm volatile("global_store_dword %0, %1, off sc0 sc1" :: "v"(p), "v"(v) : "memory");
}
__device__ __forceinline__ void stcc_f32(float* p, float v){
  asm volatile("global_store_dword %0, %1, off sc0 sc1" :: "v"(p), "v"(v) : "memory");
}
__device__ __forceinline__ u32 poll_ld(const u32* p){
  u32 v;
  asm volatile("global_load_dword %0, %1, off sc0 sc1\n\ts_waitcnt vmcnt(0)"
               : "=v"(v) : "v"(p) : "memory");
  return v;
}

// grid barrier: vmcnt(0) drains producer sc0sc1 stores (release);
// sc0sc1 poll is the acquire. Consumers use PLAIN cached loads of
// write-once rotated buffers (never stale; replay-invariant values).
__device__ __forceinline__ void gbar(u32* cnt, u32 nblk, u32& epoch){
  asm volatile("s_waitcnt vmcnt(0)" ::: "memory");
  __syncthreads();
  ++epoch;
  if (threadIdx.x == 0){
    atomicAdd(cnt, 1u);
    u32 target = epoch * nblk;
    while (poll_ld(cnt) < target) __builtin_amdgcn_s_sleep(1);
  }
  __syncthreads();
}

// ---------- 512-thread staging: [32][1024] u16 -> LDS, XOR swizzle ----------
__device__ __forceinline__ void stage512_issueS(const u16* __restrict__ src, s8v* tmp, int rstride){
  const int tid = threadIdx.x;
  const int row = tid >> 4, s0 = tid & 15;
  const u16* p = src + (size_t)row * rstride + s0 * 8;
  #pragma unroll
  for (int i = 0; i < 8; i++) tmp[i] = *(const s8v*)(p + i * 128);
}
__device__ __forceinline__ void stage512_commit(const s8v* tmp, u16* lds){
  const int tid = threadIdx.x;
  const int row = tid >> 4, s0 = tid & 15;
  char* base = (char*)lds + (row << 11);
  u32 x = (u32)(row & 15) << 4;
  #pragma unroll
  for (int i = 0; i < 8; i++){
    u32 cb = (u32)(s0 + 16 * i) << 4;
    *(s8v*)(base + (cb ^ x)) = tmp[i];
  }
}
__device__ __forceinline__ s8v ldsA(const u16* lds, int row, int cb){
  return *(const s8v*)((const char*)lds + (row << 11) + (cb ^ ((row & 15) << 4)));
}

// ---------- prep kernels ----------
__global__ void k_convert(const float* __restrict__ src, u16* __restrict__ dst, int n){
  int i = blockIdx.x * blockDim.x + threadIdx.x;
  int st = gridDim.x * blockDim.x;
  for (; i < n; i += st) dst[i] = f2bf(src[i]);
}
__global__ void k_split_w1(const float* __restrict__ w1, u16* __restrict__ w1c, u16* __restrict__ w1o){
  int i = blockIdx.x * blockDim.x + threadIdx.x;
  int st = gridDim.x * blockDim.x;
  const int n = G4 * (FF + HH);
  for (; i < n; i += st){
    int j = i / 1536, k = i - j * 1536;
    u16 v = f2bf(w1[i]);
    if (k < HH) w1c[j * HH + k] = v;
    else        w1o[j * FF + (k - HH)] = v;
  }
}
__global__ void k_addb(const float* __restrict__ a, const float* __restrict__ b,
                       float* __restrict__ o, int n){
  int i = blockIdx.x * blockDim.x + threadIdx.x;
  int st = gridDim.x * blockDim.x;
  for (; i < n; i += st) o[i] = a[i] + b[i];
}
__global__ void k_demo_t(const float* __restrict__ d, u16* __restrict__ o){
  const int n = LL * BB * FF;
  int i = blockIdx.x * blockDim.x + threadIdx.x;
  int st = gridDim.x * blockDim.x;
  for (; i < n; i += st){
    int f = i & 511;
    int row = i >> 9;
    int l = row >> 5, b = row & 31;
    o[i] = f2bf(d[(size_t)b * (LL * FF) + l * FF + f]);
  }
}

// ---------- generic GEMM (unchanged, proven) ----------
template<int RELU>
__global__ void __launch_bounds__(256) k_gemm_bt(const u16* __restrict__ A, const u16* __restrict__ B,
        const float* __restrict__ bias, u16* __restrict__ C, int M, int N, int K)
{
  __shared__ u16 As[128 * 64];
  __shared__ u16 Bs[128 * 64];
  const int tid = threadIdx.x;
  const int lane = tid & 63, wave = tid >> 6;
  const int m0 = blockIdx.x * 128, n0 = blockIdx.y * 128;
  const int wm = wave >> 1, wn = wave & 1;
  const int lr = lane & 15, lk = (lane >> 4) * 8;
  f4v acc[4][4];
  #pragma unroll
  for (int i = 0; i < 4; i++)
    #pragma unroll
    for (int j = 0; j < 4; j++) acc[i][j] = f4v{0.f, 0.f, 0.f, 0.f};

  for (int kt = 0; kt < K; kt += 64){
    #pragma unroll
    for (int i = 0; i < 4; i++){
      int c = tid + i * 256;
      int row = c >> 3, cc = (c & 7) * 8;
      glds16(A + (size_t)(m0 + row) * K + kt + cc, &As[c * 8]);
      glds16(B + (size_t)(n0 + row) * K + kt + cc, &Bs[c * 8]);
    }
    __syncthreads();
    #pragma unroll
    for (int ks = 0; ks < 2; ++ks){
      int ko = ks * 32 + lk;
      s8v av[4], bv[4];
      #pragma unroll
      for (int m = 0; m < 4; m++) av[m] = *(const s8v*)&As[(wm * 64 + m * 16 + lr) * 64 + ko];
      #pragma unroll
      for (int n = 0; n < 4; n++) bv[n] = *(const s8v*)&Bs[(wn * 64 + n * 16 + lr) * 64 + ko];
      #pragma unroll
      for (int m = 0; m < 4; m++)
        #pragma unroll
        for (int n = 0; n < 4; n++) mfma16(acc[m][n], av[m], bv[n]);
    }
    __syncthreads();
  }
  const int r0 = (lane >> 4) * 4;
  #pragma unroll
  for (int m = 0; m < 4; m++){
    #pragma unroll
    for (int n = 0; n < 4; n++){
      int col = n0 + wn * 64 + n * 16 + lr;
      float bc = bias[col];
      #pragma unroll
      for (int r = 0; r < 4; r++){
        int row = m0 + wm * 64 + m * 16 + r0 + r;
        float v = acc[m][n][r] + bc;
        if (RELU) v = fmaxf(v, 0.f);
        C[(size_t)row * N + col] = f2bf(v);
      }
    }
  }
}

// ---------- encoder: 512 threads, 8 waves (proven round-9, unchanged) ----------
union SMemE { u16 stage[32768]; float gx[8][32][17]; };

__global__ void __launch_bounds__(512, 1) k_encoder(const u16* __restrict__ Whh, const u16* __restrict__ Xih,
      u16* __restrict__ zslot, u16* __restrict__ denc, u32* bar)
{
  __shared__ SMemE sm;
  const int nb = blockIdx.x, tid = threadIdx.x;
  const int lane = tid & 63, w = tid >> 6;
  const int jc = nb * 16;
  const int lr = lane & 15, lk = (lane >> 4) * 8;
  const int eb = tid >> 4, ejj = tid & 15;
  const int rb = (lane >> 4) * 4;

  stcc_u16(&zslot[eb * HH + jc + ejj], 0);
  float cr = 0.f;
  u32 epoch = 0;
  gbar(bar, 64, epoch);

  const int kh = (w & 1) * 512;
  const u16* Wb = Whh + (size_t)((w >> 1) * HH + jc + lr) * HH + kh + lk;
  for (int l = 0; l < LL; ++l){
    const u16* hb = (l == 0) ? zslot : (denc + (size_t)(l - 1) * (BB * HH));
    s8v ht[8];
    stage512_issueS(hb, ht, HH);
    const u16* xr = Xih + ((size_t)(l * BB + eb)) * G4 + jc + ejj;
    float xi = bf2f(xr[0]), xf = bf2f(xr[1024]), xg = bf2f(xr[2048]), xo = bf2f(xr[3072]);
    stage512_commit(ht, sm.stage);
    __syncthreads();
    f4v a0 = {0.f,0.f,0.f,0.f}, a1 = {0.f,0.f,0.f,0.f};
    #pragma unroll 8
    for (int ks = 0; ks < 16; ++ks){
      int cb = (kh + lk + ks * 32) * 2;
      s8v va0 = ldsA(sm.stage, lr,      cb);
      s8v va1 = ldsA(sm.stage, lr + 16, cb);
      s8v vb  = *(const s8v*)(Wb + ks * 32);
      mfma16(a0, va0, vb);
      mfma16(a1, va1, vb);
    }
    __syncthreads();
    #pragma unroll
    for (int r = 0; r < 4; r++){ sm.gx[w][rb + r][lr] = a0[r]; sm.gx[w][16 + rb + r][lr] = a1[r]; }
    __syncthreads();
    {
      float gi = sm.gx[0][eb][ejj] + sm.gx[1][eb][ejj] + xi;
      float gf = sm.gx[2][eb][ejj] + sm.gx[3][eb][ejj] + xf;
      float gg = sm.gx[4][eb][ejj] + sm.gx[5][eb][ejj] + xg;
      float go = sm.gx[6][eb][ejj] + sm.gx[7][eb][ejj] + xo;
      cr = sigf(gf) * cr + sigf(gi) * tanhf(gg);
      float h = sigf(go) * tanhf(cr);
      stcc_u16(&denc[(size_t)l * (BB * HH) + eb * HH + jc + ejj], f2bf(h));
    }
    gbar(bar, 64, epoch);
  }
}

// ---------- decoder: 512 threads, 8 waves; phase A split across all 64 blocks ----------
union SMemD {
  u16 stage[32768];
  float gx[8][32][17];
  struct { float swt[128]; } a;
};

__global__ void __launch_bounds__(512, 1) k_decoder(
    const u16* __restrict__ aproj, const u16* __restrict__ denc, const u16* __restrict__ obsp,
    const u16* __restrict__ W1c, const u16* __restrict__ W2w, const u16* __restrict__ WihL,
    const u16* __restrict__ WhhL, const float* __restrict__ blstm, const float* __restrict__ b2,
    const float* __restrict__ h0, const float* __restrict__ c0, const int* __restrict__ lens,
    float* __restrict__ hfR, u16* __restrict__ hbR, u16* __restrict__ ctxR,
    u16* __restrict__ mbR, u16* __restrict__ xbR, float* __restrict__ scX,
    float* __restrict__ out, u32* bar)
{
  __shared__ SMemD sm;
  const int nb = blockIdx.x, tid = threadIdx.x;
  const int lane = tid & 63, w = tid >> 6;
  const int jc = nb * 16;
  const int lr = lane & 15, lk = (lane >> 4) * 8;
  const int eb = tid >> 4, ejj = tid & 15;
  const int rb = (lane >> 4) * 4;
  const int ab = nb & 31, ah = nb >> 5;      // phase-A: batch, l/ctx-half

  float cr;
  {
    float hv = h0[eb * HH + jc + ejj];
    stcc_f32(&hfR[eb * HH + jc + ejj], hv);
    stcc_u16(&hbR[eb * HH + jc + ejj], f2bf(hv));
    cr = c0[eb * HH + jc + ejj];
  }
  u32 epoch = 0;
  gbar(bar, 64, epoch);

  for (int t = 0; t < TT; ++t){
    const u16* ctxS = ctxR + (size_t)t * (BB * HH);
    const u16* mbS  = mbR  + (size_t)t * (BB * G4);
    const u16* xbS  = xbR  + (size_t)t * (BB * HH);
    const u16* hbS  = hbR  + (size_t)t * (BB * HH);
    const float* hfS= hfR  + (size_t)t * (BB * HH);
    float* scT = scX + (size_t)t * (BB * 128) + ab * 128;

    // ---- Phase A1: scores for batch ab, l-half ah (all 64 blocks active) ----
    {
      const int len = lens[ab];
      float hr[16];
      const float* hp = hfS + ab * HH + lane * 16;
      #pragma unroll
      for (int i = 0; i < 16; i++) hr[i] = hp[i];
      for (int i = 0; i < 8; ++i){
        int l = ah * 64 + w * 8 + i;
        const u16* ap = aproj + ((size_t)(l * BB + ab)) * HH + lane * 16;
        s8v v0 = *(const s8v*)ap;
        s8v v1 = *(const s8v*)(ap + 8);
        float s = 0.f;
        #pragma unroll
        for (int k = 0; k < 8; k++) s += bf2f((u16)v0[k]) * hr[k];
        #pragma unroll
        for (int k = 0; k < 8; k++) s += bf2f((u16)v1[k]) * hr[8 + k];
        #pragma unroll
        for (int off = 32; off > 0; off >>= 1) s += __shfl_down(s, off);
        if (lane == 0){
          s *= SCALE_;
          if (l >= len && l != 0) s = -__builtin_inff();
          stcc_f32(&scT[l], s);
        }
      }
    }
    gbar(bar, 64, epoch);

    // ---- Phase A2: softmax (replicated in pair) + ctx half ----
    {
      if (w == 0){
        float x0 = scT[lane], x1 = scT[lane + 64];   // plain: virgin rotated slot
        float mx = fmaxf(x0, x1);
        #pragma unroll
        for (int off = 32; off > 0; off >>= 1) mx = fmaxf(mx, __shfl_xor(mx, off));
        float e0 = __expf(x0 - mx), e1 = __expf(x1 - mx);
        float smv = e0 + e1;
        #pragma unroll
        for (int off = 32; off > 0; off >>= 1) smv += __shfl_xor(smv, off);
        float inv = 1.f / smv;
        sm.a.swt[lane] = e0 * inv;
        sm.a.swt[lane + 64] = e1 * inv;
      }
      __syncthreads();
      int col = ah * 512 + tid;
      const u16* dp = denc + (size_t)ab * HH + col;
      float acc = 0.f;
      #pragma unroll 4
      for (int l = 0; l < LL; ++l)
        acc += sm.a.swt[l] * bf2f(dp[(size_t)l * (BB * HH)]);
      stcc_u16((u16*)&ctxS[ab * HH + col], f2bf(acc));
    }
    gbar(bar, 64, epoch);

    // ---- Phase B: m = relu(ctx @ W1c^T + obsp[t]); 8 waves = 4 col-groups x 2 K-halves ----
    {
      s8v ct[8];
      stage512_issueS(ctxS, ct, HH);
      stage512_commit(ct, sm.stage);
      __syncthreads();
      const int col0 = nb * 64 + (w >> 1) * 16;
      const int kh = (w & 1) * 512;
      f4v a0 = {0.f,0.f,0.f,0.f}, a1 = {0.f,0.f,0.f,0.f};
      const u16* Bp = W1c + (size_t)(col0 + lr) * HH + kh + lk;
      #pragma unroll 8
      for (int ks = 0; ks < 16; ++ks){
        int cb = (kh + lk + ks * 32) * 2;
        s8v va0 = ldsA(sm.stage, lr,      cb);
        s8v va1 = ldsA(sm.stage, lr + 16, cb);
        s8v vb  = *(const s8v*)(Bp + ks * 32);
        mfma16(a0, va0, vb);
        mfma16(a1, va1, vb);
      }
      __syncthreads();            // stage dead -> gx overlay
      #pragma unroll
      for (int r = 0; r < 4; r++){ sm.gx[w][rb + r][lr] = a0[r]; sm.gx[w][16 + rb + r][lr] = a1[r]; }
      __syncthreads();
      #pragma unroll
      for (int cg = 0; cg < 4; ++cg){
        int col = nb * 64 + cg * 16 + ejj;
        float v = sm.gx[2 * cg][eb][ejj] + sm.gx[2 * cg + 1][eb][ejj]
                + bf2f(obsp[((size_t)(t * BB + eb)) * G4 + col]);
        stcc_u16((u16*)&mbS[eb * G4 + col], f2bf(fmaxf(v, 0.f)));
      }
    }
    gbar(bar, 64, epoch);

    // ---- Phase C: x = relu(m @ W2^T + b2); 4 staged K-quarters, 8 waves x 128-K slices ----
    {
      f4v a0 = {0.f,0.f,0.f,0.f}, a1 = {0.f,0.f,0.f,0.f};
      for (int q = 0; q < 4; ++q){
        s8v ct[8];
        stage512_issueS(mbS + q * 1024, ct, G4);
        stage512_commit(ct, sm.stage);
        __syncthreads();
        const u16* Bp = W2w + (size_t)(jc + lr) * G4 + q * 1024 + w * 128 + lk;
        #pragma unroll
        for (int ks = 0; ks < 4; ++ks){
          int cb = (w * 128 + lk + ks * 32) * 2;
          s8v va0 = ldsA(sm.stage, lr,      cb);
          s8v va1 = ldsA(sm.stage, lr + 16, cb);
          s8v vb  = *(const s8v*)(Bp + ks * 32);
          mfma16(a0, va0, vb);
          mfma16(a1, va1, vb);
        }
        __syncthreads();
      }
      #pragma unroll
      for (int r = 0; r < 4; r++){ sm.gx[w][rb + r][lr] = a0[r]; sm.gx[w][16 + rb + r][lr] = a1[r]; }
      __syncthreads();
      {
        float v = b2[jc + ejj];
        #pragma unroll
        for (int g = 0; g < 8; ++g) v += sm.gx[g][eb][ejj];
        stcc_u16((u16*)&xbS[eb * HH + jc + ejj], f2bf(fmaxf(v, 0.f)));
      }
    }
    gbar(bar, 64, epoch);

    // ---- Phase D: gates = x@WihL^T + h@WhhL^T; 8 waves = 4 gates x 2 K-halves ----
    {
      s8v xt[8], ht[8];
      stage512_issueS(xbS, xt, HH);
      stage512_issueS(hbS, ht, HH);
      stage512_commit(xt, sm.stage);
      __syncthreads();
      const int kh = (w & 1) * 512;
      f4v a0 = {0.f,0.f,0.f,0.f}, a1 = {0.f,0.f,0.f,0.f};
      const u16* Bx = WihL + (size_t)((w >> 1) * HH + jc + lr) * HH + kh + lk;
      #pragma unroll 8
      for (int ks = 0; ks < 16; ++ks){
        int cb = (kh + lk + ks * 32) * 2;
        s8v va0 = ldsA(sm.stage, lr,      cb);
        s8v va1 = ldsA(sm.stage, lr + 16, cb);
        s8v vb  = *(const s8v*)(Bx + ks * 32);
        mfma16(a0, va0, vb);
        mfma16(a1, va1, vb);
      }
      __syncthreads();
      stage512_commit(ht, sm.stage);
      __syncthreads();
      const u16* Bh = WhhL + (size_t)((w >> 1) * HH + jc + lr) * HH + kh + lk;
      #pragma unroll 8
      for (int ks = 0; ks < 16; ++ks){
        int cb = (kh + lk + ks * 32) * 2;
        s8v va0 = ldsA(sm.stage, lr,      cb);
        s8v va1 = ldsA(sm.stage, lr + 16, cb);
        s8v vb  = *(const s8v*)(Bh + ks * 32);
        mfma16(a0, va0, vb);
        mfma16(a1, va1, vb);
      }
      __syncthreads();
      #pragma unroll
      for (int r = 0; r < 4; r++){ sm.gx[w][rb + r][lr] = a0[r]; sm.gx[w][16 + rb + r][lr] = a1[r]; }
      __syncthreads();
      {
        int col = jc + ejj;
        float gi = sm.gx[0][eb][ejj] + sm.gx[1][eb][ejj] + blstm[col];
        float gf = sm.gx[2][eb][ejj] + sm.gx[3][eb][ejj] + blstm[1024 + col];
        float gg = sm.gx[4][eb][ejj] + sm.gx[5][eb][ejj] + blstm[2048 + col];
        float go = sm.gx[6][eb][ejj] + sm.gx[7][eb][ejj] + blstm[3072 + col];
        cr = sigf(gf) * cr + sigf(gi) * tanhf(gg);
        float h = sigf(go) * tanhf(cr);
        stcc_f32(&out[(size_t)t * (BB * HH) + eb * HH + col], h);
        stcc_f32(&hfR[(size_t)(t + 1) * (BB * HH) + eb * HH + col], h);
        stcc_u16(&hbR[(size_t)(t + 1) * (BB * HH) + eb * HH + col], f2bf(h));
        if (t == TT - 1){
          stcc_f32(&out[1048576 + eb * HH + col], h);
          stcc_f32(&out[1081344 + eb * HH + col], cr);
        }
      }
    }
    gbar(bar, 64, epoch);
  }
}

// ---------- workspace layout (round-5 proven, no aliases; + scX) ----------
static constexpr size_t oWihE = 0;
static constexpr size_t oWhhE = oWihE + 4194304;
static constexpr size_t oAttnW= oWhhE + 8388608;
static constexpr size_t oW1C  = oAttnW+ 2097152;
static constexpr size_t oW1O  = oW1C  + 8388608;
static constexpr size_t oW2   = oW1O  + 4194304;
static constexpr size_t oWihL = oW2   + 8388608;
static constexpr size_t oWhhL = oWihL + 8388608;
static constexpr size_t oBEnc = oWhhL + 8388608;
static constexpr size_t oBL   = oBEnc + 16384;
static constexpr size_t oDemoT= oBL   + 16384;
static constexpr size_t oObsB = oDemoT+ 4194304;
static constexpr size_t oXih  = oObsB + 1048576;
static constexpr size_t oObsP = oXih  + 33554432;
static constexpr size_t oDEnc = oObsP + 8388608;
static constexpr size_t oAPrj = oDEnc + 8388608;
static constexpr size_t oZE   = oAPrj + 8388608;
static constexpr size_t oHFR  = oZE   + 65536;
static constexpr size_t oHBR  = oHFR  + 4325376;
static constexpr size_t oCtxR = oHBR  + 2162688;
static constexpr size_t oMBR  = oCtxR + 2097152;
static constexpr size_t oXBR  = oMBR  + 8388608;
static constexpr size_t oScX  = oXBR  + 2097152;         // 32 x 32 x 128 x 4B = 512KB (fresh, no alias)
static constexpr size_t oBar  = oScX  + 524288;

extern "C" void kernel_launch(void* const* d_in, const int* in_sizes, int n_in,
                              void* d_out, int out_size, void* d_ws, size_t ws_size,
                              hipStream_t stream)
{
  const float* demo = (const float*)d_in[0];
  const int*   lens = (const int*)  d_in[1];
  const float* obs  = (const float*)d_in[2];
  const float* h0   = (const float*)d_in[3];
  const float* c0   = (const float*)d_in[4];
  const float* eWih = (const float*)d_in[5];
  const float* eWhh = (const float*)d_in[6];
  const float* eBih = (const float*)d_in[7];
  const float* eBhh = (const float*)d_in[8];
  const float* aW   = (const float*)d_in[9];
  const float* aB   = (const float*)d_in[10];
  const float* W1   = (const float*)d_in[11];
  const float* B1   = (const float*)d_in[12];
  const float* W2   = (const float*)d_in[13];
  const float* B2   = (const float*)d_in[14];
  const float* lWih = (const float*)d_in[15];
  const float* lWhh = (const float*)d_in[16];
  const float* lBih = (const float*)d_in[17];
  const float* lBhh = (const float*)d_in[18];

  char* ws = (char*)d_ws;
  u16*  WihE = (u16*)(ws + oWihE);
  u16*  WhhE = (u16*)(ws + oWhhE);
  u16*  AttnW= (u16*)(ws + oAttnW);
  u16*  W1C  = (u16*)(ws + oW1C);
  u16*  W1O  = (u16*)(ws + oW1O);
  u16*  W2w  = (u16*)(ws + oW2);
  u16*  WihL = (u16*)(ws + oWihL);
  u16*  WhhL = (u16*)(ws + oWhhL);
  float* BEnc= (float*)(ws + oBEnc);
  float* BL  = (float*)(ws + oBL);
  u16*  DemoT= (u16*)(ws + oDemoT);
  u16*  ObsB = (u16*)(ws + oObsB);
  u16*  Xih  = (u16*)(ws + oXih);
  u16*  ObsP = (u16*)(ws + oObsP);
  u16*  DEnc = (u16*)(ws + oDEnc);
  u16*  APrj = (u16*)(ws + oAPrj);
  u16*  ZE   = (u16*)(ws + oZE);
  float* HFR = (float*)(ws + oHFR);
  u16*  HBR  = (u16*)(ws + oHBR);
  u16*  CtxR = (u16*)(ws + oCtxR);
  u16*  MBR  = (u16*)(ws + oMBR);
  u16*  XBR  = (u16*)(ws + oXBR);
  float* ScX = (float*)(ws + oScX);
  u32*  Bar  = (u32*)(ws + oBar);

  k_convert<<<1024, 256, 0, stream>>>(eWih, WihE, G4 * FF);
  k_convert<<<1024, 256, 0, stream>>>(eWhh, WhhE, G4 * HH);
  k_convert<<<512,  256, 0, stream>>>(aW,   AttnW, HH * HH);
  k_split_w1<<<1024, 256, 0, stream>>>(W1, W1C, W1O);
  k_convert<<<1024, 256, 0, stream>>>(W2,   W2w,  HH * G4);
  k_convert<<<1024, 256, 0, stream>>>(lWih, WihL, G4 * HH);
  k_convert<<<1024, 256, 0, stream>>>(lWhh, WhhL, G4 * HH);
  k_addb<<<16, 256, 0, stream>>>(eBih, eBhh, BEnc, G4);
  k_addb<<<16, 256, 0, stream>>>(lBih, lBhh, BL, G4);
  k_demo_t<<<1024, 256, 0, stream>>>(demo, DemoT);
  k_convert<<<512, 256, 0, stream>>>(obs, ObsB, TT * BB * FF);
  hipMemsetAsync(Bar, 0, 256, stream);

  {
    dim3 g(LL * BB / 128, G4 / 128);
    k_gemm_bt<0><<<g, 256, 0, stream>>>(DemoT, WihE, BEnc, Xih, LL * BB, G4, FF);
  }
  {
    dim3 g(TT * BB / 128, G4 / 128);
    k_gemm_bt<0><<<g, 256, 0, stream>>>(ObsB, W1O, B1, ObsP, TT * BB, G4, FF);
  }

  k_encoder<<<64, 512, 0, stream>>>(WhhE, Xih, ZE, DEnc, Bar);

  {
    dim3 g(LL * BB / 128, HH / 128);
    k_gemm_bt<0><<<g, 256, 0, stream>>>(DEnc, AttnW, aB, APrj, LL * BB, HH, HH);
  }

  k_decoder<<<64, 512, 0, stream>>>(APrj, DEnc, ObsP, W1C, W2w, WihL, WhhL,
                                    BL, B2, h0, c0, lens,
                                    HFR, HBR, CtxR, MBR, XBR, ScX,
                                    (float*)d_out, Bar + 16);
}

// Round 11
// 2675.978 us; speedup vs baseline: 1.4311x; 1.0089x over previous
//
#include <hip/hip_runtime.h>

typedef unsigned short u16;
typedef unsigned int   u32;
typedef short s8v __attribute__((ext_vector_type(8)));
typedef float f4v __attribute__((ext_vector_type(4)));

// Problem constants
#define TT 32
#define BB 32
#define LL 128
#define FF 512
#define HH 1024
#define G4 4096
#define SCALE_ 0.08838834764831845f   // 1/sqrt(128)

// ---------- helpers ----------
__device__ __forceinline__ u16 f2bf(float f){
  u32 u = __float_as_uint(f);
  u32 r = u + 0x7fffu + ((u >> 16) & 1u);   // RNE
  return (u16)(r >> 16);
}
__device__ __forceinline__ float bf2f(u16 s){ return __uint_as_float(((u32)s) << 16); }
__device__ __forceinline__ float sigf(float x){ return 1.f / (1.f + __expf(-x)); }

__device__ __forceinline__ void mfma16(f4v& d, s8v a, s8v b){
  asm("v_mfma_f32_16x16x32_bf16 %0, %1, %2, %0" : "+v"(d) : "v"(a), "v"(b));
}

typedef __attribute__((address_space(3))) u32 as3u32;
typedef __attribute__((address_space(1))) u32 as1u32;
__device__ __forceinline__ void glds16(const u16* g, u16* l){
  __builtin_amdgcn_global_load_lds((const as1u32*)g, (as3u32*)l, 16, 0, 0);
}

// ---- producer stores: write-through to LLC (coherent point) ----
__device__ __forceinline__ void stcc_u16(u16* p, u16 v){
  u32 vv = v;
  asm volatile("global_store_short %0, %1, off sc0 sc1" :: "v"(p), "v"(vv) : "memory");
}
__device__ __forceinline__ void stcc_f32(float* p, float v){
  asm volatile("global_store_dword %0, %1, off sc0 sc1" :: "v"(p), "v"(v) : "memory");
}
__device__ __forceinline__ u32 poll_ld(const u32* p){
  u32 v;
  asm volatile("global_load_dword %0, %1, off sc0 sc1\n\ts_waitcnt vmcnt(0)"
               : "=v"(v) : "v"(p) : "memory");
  return v;
}

// grid barrier: vmcnt(0) drains producer sc0sc1 stores (release);
// sc0sc1 poll is the acquire. Consumers use PLAIN cached loads of
// write-once rotated buffers (never stale; replay-invariant values).
__device__ __forceinline__ void gbar(u32* cnt, u32 nblk, u32& epoch){
  asm volatile("s_waitcnt vmcnt(0)" ::: "memory");
  __syncthreads();
  ++epoch;
  if (threadIdx.x == 0){
    atomicAdd(cnt, 1u);
    u32 target = epoch * nblk;
    while (poll_ld(cnt) < target) __builtin_amdgcn_s_sleep(1);
  }
  __syncthreads();
}

// ---------- 1024-thread staging: [32][1024] u16 -> LDS, XOR swizzle ----------
// thread (row = tid>>5, s0 = tid&31) loads 4 x s8v: cols s0*8 + i*256
__device__ __forceinline__ void stg_issue(const u16* __restrict__ src, s8v* tmp, int rstride){
  const int tid = threadIdx.x;
  const int row = tid >> 5, s0 = tid & 31;
  const u16* p = src + (size_t)row * rstride + s0 * 8;
  #pragma unroll
  for (int i = 0; i < 4; i++) tmp[i] = *(const s8v*)(p + i * 256);
}
__device__ __forceinline__ void stg_commit(const s8v* tmp, u16* lds){
  const int tid = threadIdx.x;
  const int row = tid >> 5, s0 = tid & 31;
  char* base = (char*)lds + (row << 11);
  u32 x = (u32)(row & 15) << 4;
  #pragma unroll
  for (int i = 0; i < 4; i++){
    u32 cb = (u32)(s0 + 32 * i) << 4;
    *(s8v*)(base + (cb ^ x)) = tmp[i];
  }
}
__device__ __forceinline__ s8v ldsA(const u16* lds, int row, int cb){
  return *(const s8v*)((const char*)lds + (row << 11) + (cb ^ ((row & 15) << 4)));
}

// ---------- prep kernels ----------
__global__ void k_convert(const float* __restrict__ src, u16* __restrict__ dst, int n){
  int i = blockIdx.x * blockDim.x + threadIdx.x;
  int st = gridDim.x * blockDim.x;
  for (; i < n; i += st) dst[i] = f2bf(src[i]);
}
__global__ void k_split_w1(const float* __restrict__ w1, u16* __restrict__ w1c, u16* __restrict__ w1o){
  int i = blockIdx.x * blockDim.x + threadIdx.x;
  int st = gridDim.x * blockDim.x;
  const int n = G4 * (FF + HH);
  for (; i < n; i += st){
    int j = i / 1536, k = i - j * 1536;
    u16 v = f2bf(w1[i]);
    if (k < HH) w1c[j * HH + k] = v;
    else        w1o[j * FF + (k - HH)] = v;
  }
}
__global__ void k_addb(const float* __restrict__ a, const float* __restrict__ b,
                       float* __restrict__ o, int n){
  int i = blockIdx.x * blockDim.x + threadIdx.x;
  int st = gridDim.x * blockDim.x;
  for (; i < n; i += st) o[i] = a[i] + b[i];
}
__global__ void k_demo_t(const float* __restrict__ d, u16* __restrict__ o){
  const int n = LL * BB * FF;
  int i = blockIdx.x * blockDim.x + threadIdx.x;
  int st = gridDim.x * blockDim.x;
  for (; i < n; i += st){
    int f = i & 511;
    int row = i >> 9;
    int l = row >> 5, b = row & 31;
    o[i] = f2bf(d[(size_t)b * (LL * FF) + l * FF + f]);
  }
}

// ---------- generic GEMM (unchanged, proven) ----------
template<int RELU>
__global__ void __launch_bounds__(256) k_gemm_bt(const u16* __restrict__ A, const u16* __restrict__ B,
        const float* __restrict__ bias, u16* __restrict__ C, int M, int N, int K)
{
  __shared__ u16 As[128 * 64];
  __shared__ u16 Bs[128 * 64];
  const int tid = threadIdx.x;
  const int lane = tid & 63, wave = tid >> 6;
  const int m0 = blockIdx.x * 128, n0 = blockIdx.y * 128;
  const int wm = wave >> 1, wn = wave & 1;
  const int lr = lane & 15, lk = (lane >> 4) * 8;
  f4v acc[4][4];
  #pragma unroll
  for (int i = 0; i < 4; i++)
    #pragma unroll
    for (int j = 0; j < 4; j++) acc[i][j] = f4v{0.f, 0.f, 0.f, 0.f};

  for (int kt = 0; kt < K; kt += 64){
    #pragma unroll
    for (int i = 0; i < 4; i++){
      int c = tid + i * 256;
      int row = c >> 3, cc = (c & 7) * 8;
      glds16(A + (size_t)(m0 + row) * K + kt + cc, &As[c * 8]);
      glds16(B + (size_t)(n0 + row) * K + kt + cc, &Bs[c * 8]);
    }
    __syncthreads();
    #pragma unroll
    for (int ks = 0; ks < 2; ++ks){
      int ko = ks * 32 + lk;
      s8v av[4], bv[4];
      #pragma unroll
      for (int m = 0; m < 4; m++) av[m] = *(const s8v*)&As[(wm * 64 + m * 16 + lr) * 64 + ko];
      #pragma unroll
      for (int n = 0; n < 4; n++) bv[n] = *(const s8v*)&Bs[(wn * 64 + n * 16 + lr) * 64 + ko];
      #pragma unroll
      for (int m = 0; m < 4; m++)
        #pragma unroll
        for (int n = 0; n < 4; n++) mfma16(acc[m][n], av[m], bv[n]);
    }
    __syncthreads();
  }
  const int r0 = (lane >> 4) * 4;
  #pragma unroll
  for (int m = 0; m < 4; m++){
    #pragma unroll
    for (int n = 0; n < 4; n++){
      int col = n0 + wn * 64 + n * 16 + lr;
      float bc = bias[col];
      #pragma unroll
      for (int r = 0; r < 4; r++){
        int row = m0 + wm * 64 + m * 16 + r0 + r;
        float v = acc[m][n][r] + bc;
        if (RELU) v = fmaxf(v, 0.f);
        C[(size_t)row * N + col] = f2bf(v);
      }
    }
  }
}

// ---------- encoder: 1024 threads, 16 waves = 4 gates x 4 K-quarters ----------
union SMemE { u16 stage[32768]; float gx[16][32][17]; };

__global__ void __launch_bounds__(1024, 4) k_encoder(const u16* __restrict__ Whh, const u16* __restrict__ Xih,
      u16* __restrict__ zslot, u16* __restrict__ denc, u32* bar)
{
  __shared__ SMemE sm;
  const int nb = blockIdx.x, tid = threadIdx.x;
  const int lane = tid & 63, w = tid >> 6;
  const int jc = nb * 16;
  const int lr = lane & 15, lk = (lane >> 4) * 8;
  const int eb = tid >> 4, ejj = tid & 15;   // elementwise map (tid<512)
  const int rb = (lane >> 4) * 4;

  if (tid < 512) stcc_u16(&zslot[eb * HH + jc + ejj], 0);
  float cr = 0.f;
  u32 epoch = 0;
  gbar(bar, 64, epoch);

  const int kh = (w & 3) * 256;
  const u16* Wb = Whh + (size_t)((w >> 2) * HH + jc + lr) * HH + kh + lk;
  for (int l = 0; l < LL; ++l){
    const u16* hb = (l == 0) ? zslot : (denc + (size_t)(l - 1) * (BB * HH));
    s8v ht[4];
    stg_issue(hb, ht, HH);
    float xi = 0, xf = 0, xg = 0, xo = 0;
    if (tid < 512){
      const u16* xr = Xih + ((size_t)(l * BB + eb)) * G4 + jc + ejj;
      xi = bf2f(xr[0]); xf = bf2f(xr[1024]); xg = bf2f(xr[2048]); xo = bf2f(xr[3072]);
    }
    stg_commit(ht, sm.stage);
    __syncthreads();
    f4v a0 = {0.f,0.f,0.f,0.f}, a1 = {0.f,0.f,0.f,0.f};
    #pragma unroll
    for (int ks = 0; ks < 8; ++ks){
      int cb = (kh + lk + ks * 32) * 2;
      s8v va0 = ldsA(sm.stage, lr,      cb);
      s8v va1 = ldsA(sm.stage, lr + 16, cb);
      s8v vb  = *(const s8v*)(Wb + ks * 32);
      mfma16(a0, va0, vb);
      mfma16(a1, va1, vb);
    }
    __syncthreads();              // stage dead -> gx overlay
    #pragma unroll
    for (int r = 0; r < 4; r++){ sm.gx[w][rb + r][lr] = a0[r]; sm.gx[w][16 + rb + r][lr] = a1[r]; }
    __syncthreads();
    if (tid < 512){
      float gi = sm.gx[0][eb][ejj] + sm.gx[1][eb][ejj] + sm.gx[2][eb][ejj] + sm.gx[3][eb][ejj] + xi;
      float gf = sm.gx[4][eb][ejj] + sm.gx[5][eb][ejj] + sm.gx[6][eb][ejj] + sm.gx[7][eb][ejj] + xf;
      float gg = sm.gx[8][eb][ejj] + sm.gx[9][eb][ejj] + sm.gx[10][eb][ejj] + sm.gx[11][eb][ejj] + xg;
      float go = sm.gx[12][eb][ejj] + sm.gx[13][eb][ejj] + sm.gx[14][eb][ejj] + sm.gx[15][eb][ejj] + xo;
      cr = sigf(gf) * cr + sigf(gi) * tanhf(gg);
      float h = sigf(go) * tanhf(cr);
      stcc_u16(&denc[(size_t)l * (BB * HH) + eb * HH + jc + ejj], f2bf(h));
    }
    gbar(bar, 64, epoch);
  }
}

// ---------- decoder: 1024 threads, 16 waves; A split across 64 blocks ----------
union SMemD {
  u16 stage[32768];
  float gx[16][32][17];
  struct { float swt[128]; } a;
};

__global__ void __launch_bounds__(1024, 4) k_decoder(
    const u16* __restrict__ aproj, const u16* __restrict__ denc, const u16* __restrict__ obsp,
    const u16* __restrict__ W1c, const u16* __restrict__ W2w, const u16* __restrict__ WihL,
    const u16* __restrict__ WhhL, const float* __restrict__ blstm, const float* __restrict__ b2,
    const float* __restrict__ h0, const float* __restrict__ c0, const int* __restrict__ lens,
    float* __restrict__ hfR, u16* __restrict__ hbR, u16* __restrict__ ctxR,
    u16* __restrict__ mbR, u16* __restrict__ xbR, float* __restrict__ scX,
    float* __restrict__ out, u32* bar)
{
  __shared__ SMemD sm;
  const int nb = blockIdx.x, tid = threadIdx.x;
  const int lane = tid & 63, w = tid >> 6;
  const int jc = nb * 16;
  const int lr = lane & 15, lk = (lane >> 4) * 8;
  const int eb = tid >> 4, ejj = tid & 15;   // elementwise map (tid<512)
  const int rb = (lane >> 4) * 4;
  const int ab = nb & 31, ah = nb >> 5;      // phase-A: batch, l/ctx-half

  float cr = 0.f;
  if (tid < 512){
    float hv = h0[eb * HH + jc + ejj];
    stcc_f32(&hfR[eb * HH + jc + ejj], hv);
    stcc_u16(&hbR[eb * HH + jc + ejj], f2bf(hv));
    cr = c0[eb * HH + jc + ejj];
  }
  u32 epoch = 0;
  gbar(bar, 64, epoch);

  for (int t = 0; t < TT; ++t){
    const u16* ctxS = ctxR + (size_t)t * (BB * HH);
    const u16* mbS  = mbR  + (size_t)t * (BB * G4);
    const u16* xbS  = xbR  + (size_t)t * (BB * HH);
    const u16* hbS  = hbR  + (size_t)t * (BB * HH);
    const float* hfS= hfR  + (size_t)t * (BB * HH);
    float* scT = scX + (size_t)t * (BB * 128) + ab * 128;

    // ---- Phase A1: scores for batch ab, l-half ah (16 waves x 4 l) ----
    {
      const int len = lens[ab];
      float hr[16];
      const float* hp = hfS + ab * HH + lane * 16;
      #pragma unroll
      for (int i = 0; i < 16; i++) hr[i] = hp[i];
      #pragma unroll
      for (int i = 0; i < 4; ++i){
        int l = ah * 64 + w * 4 + i;
        const u16* ap = aproj + ((size_t)(l * BB + ab)) * HH + lane * 16;
        s8v v0 = *(const s8v*)ap;
        s8v v1 = *(const s8v*)(ap + 8);
        float s = 0.f;
        #pragma unroll
        for (int k = 0; k < 8; k++) s += bf2f((u16)v0[k]) * hr[k];
        #pragma unroll
        for (int k = 0; k < 8; k++) s += bf2f((u16)v1[k]) * hr[8 + k];
        #pragma unroll
        for (int off = 32; off > 0; off >>= 1) s += __shfl_down(s, off);
        if (lane == 0){
          s *= SCALE_;
          if (l >= len && l != 0) s = -__builtin_inff();
          stcc_f32(&scT[l], s);
        }
      }
    }
    gbar(bar, 64, epoch);

    // ---- Phase A2: softmax (replicated in pair) + ctx half ----
    {
      if (w == 0){
        float x0 = scT[lane], x1 = scT[lane + 64];   // plain: virgin rotated slot
        float mx = fmaxf(x0, x1);
        #pragma unroll
        for (int off = 32; off > 0; off >>= 1) mx = fmaxf(mx, __shfl_xor(mx, off));
        float e0 = __expf(x0 - mx), e1 = __expf(x1 - mx);
        float smv = e0 + e1;
        #pragma unroll
        for (int off = 32; off > 0; off >>= 1) smv += __shfl_xor(smv, off);
        float inv = 1.f / smv;
        sm.a.swt[lane] = e0 * inv;
        sm.a.swt[lane + 64] = e1 * inv;
      }
      __syncthreads();
      if (tid < 512){
        int col = ah * 512 + tid;
        const u16* dp = denc + (size_t)ab * HH + col;
        float acc = 0.f;
        #pragma unroll 4
        for (int l = 0; l < LL; ++l)
          acc += sm.a.swt[l] * bf2f(dp[(size_t)l * (BB * HH)]);
        stcc_u16((u16*)&ctxS[ab * HH + col], f2bf(acc));
      }
    }
    gbar(bar, 64, epoch);

    // ---- Phase B: m = relu(ctx @ W1c^T + obsp[t]); 16 waves = 4 col-groups x 4 K-quarters ----
    {
      s8v ct[4];
      stg_issue(ctxS, ct, HH);
      stg_commit(ct, sm.stage);
      __syncthreads();
      const int col0 = nb * 64 + (w >> 2) * 16;
      const int kh = (w & 3) * 256;
      f4v a0 = {0.f,0.f,0.f,0.f}, a1 = {0.f,0.f,0.f,0.f};
      const u16* Bp = W1c + (size_t)(col0 + lr) * HH + kh + lk;
      #pragma unroll
      for (int ks = 0; ks < 8; ++ks){
        int cb = (kh + lk + ks * 32) * 2;
        s8v va0 = ldsA(sm.stage, lr,      cb);
        s8v va1 = ldsA(sm.stage, lr + 16, cb);
        s8v vb  = *(const s8v*)(Bp + ks * 32);
        mfma16(a0, va0, vb);
        mfma16(a1, va1, vb);
      }
      __syncthreads();            // stage dead -> gx overlay
      #pragma unroll
      for (int r = 0; r < 4; r++){ sm.gx[w][rb + r][lr] = a0[r]; sm.gx[w][16 + rb + r][lr] = a1[r]; }
      __syncthreads();
      if (tid < 512){
        #pragma unroll
        for (int cg = 0; cg < 4; ++cg){
          int col = nb * 64 + cg * 16 + ejj;
          float v = sm.gx[4 * cg][eb][ejj] + sm.gx[4 * cg + 1][eb][ejj]
                  + sm.gx[4 * cg + 2][eb][ejj] + sm.gx[4 * cg + 3][eb][ejj]
                  + bf2f(obsp[((size_t)(t * BB + eb)) * G4 + col]);
          stcc_u16((u16*)&mbS[eb * G4 + col], f2bf(fmaxf(v, 0.f)));
        }
      }
    }
    gbar(bar, 64, epoch);

    // ---- Phase C: x = relu(m @ W2^T + b2); 4 staged K-quarters, 16 waves x 64-K slices ----
    {
      f4v a0 = {0.f,0.f,0.f,0.f}, a1 = {0.f,0.f,0.f,0.f};
      for (int q = 0; q < 4; ++q){
        s8v ct[4];
        stg_issue(mbS + q * 1024, ct, G4);
        stg_commit(ct, sm.stage);
        __syncthreads();
        const u16* Bp = W2w + (size_t)(jc + lr) * G4 + q * 1024 + w * 64 + lk;
        #pragma unroll
        for (int ks = 0; ks < 2; ++ks){
          int cb = (w * 64 + lk + ks * 32) * 2;
          s8v va0 = ldsA(sm.stage, lr,      cb);
          s8v va1 = ldsA(sm.stage, lr + 16, cb);
          s8v vb  = *(const s8v*)(Bp + ks * 32);
          mfma16(a0, va0, vb);
          mfma16(a1, va1, vb);
        }
        __syncthreads();
      }
      #pragma unroll
      for (int r = 0; r < 4; r++){ sm.gx[w][rb + r][lr] = a0[r]; sm.gx[w][16 + rb + r][lr] = a1[r]; }
      __syncthreads();
      if (tid < 512){
        float v = b2[jc + ejj];
        #pragma unroll
        for (int g = 0; g < 16; ++g) v += sm.gx[g][eb][ejj];
        stcc_u16((u16*)&xbS[eb * HH + jc + ejj], f2bf(fmaxf(v, 0.f)));
      }
    }
    gbar(bar, 64, epoch);

    // ---- Phase D: gates = x@WihL^T + h@WhhL^T; 16 waves = 4 gates x 4 K-quarters ----
    {
      s8v xt[4], ht[4];
      stg_issue(xbS, xt, HH);
      stg_issue(hbS, ht, HH);
      stg_commit(xt, sm.stage);
      __syncthreads();
      const int kh = (w & 3) * 256;
      f4v a0 = {0.f,0.f,0.f,0.f}, a1 = {0.f,0.f,0.f,0.f};
      const u16* Bx = WihL + (size_t)((w >> 2) * HH + jc + lr) * HH + kh + lk;
      #pragma unroll
      for (int ks = 0; ks < 8; ++ks){
        int cb = (kh + lk + ks * 32) * 2;
        s8v va0 = ldsA(sm.stage, lr,      cb);
        s8v va1 = ldsA(sm.stage, lr + 16, cb);
        s8v vb  = *(const s8v*)(Bx + ks * 32);
        mfma16(a0, va0, vb);
        mfma16(a1, va1, vb);
      }
      __syncthreads();
      stg_commit(ht, sm.stage);
      __syncthreads();
      const u16* Bh = WhhL + (size_t)((w >> 2) * HH + jc + lr) * HH + kh + lk;
      #pragma unroll
      for (int ks = 0; ks < 8; ++ks){
        int cb = (kh + lk + ks * 32) * 2;
        s8v va0 = ldsA(sm.stage, lr,      cb);
        s8v va1 = ldsA(sm.stage, lr + 16, cb);
        s8v vb  = *(const s8v*)(Bh + ks * 32);
        mfma16(a0, va0, vb);
        mfma16(a1, va1, vb);
      }
      __syncthreads();
      #pragma unroll
      for (int r = 0; r < 4; r++){ sm.gx[w][rb + r][lr] = a0[r]; sm.gx[w][16 + rb + r][lr] = a1[r]; }
      __syncthreads();
      if (tid < 512){
        int col = jc + ejj;
        float gi = sm.gx[0][eb][ejj] + sm.gx[1][eb][ejj] + sm.gx[2][eb][ejj] + sm.gx[3][eb][ejj] + blstm[col];
        float gf = sm.gx[4][eb][ejj] + sm.gx[5][eb][ejj] + sm.gx[6][eb][ejj] + sm.gx[7][eb][ejj] + blstm[1024 + col];
        float gg = sm.gx[8][eb][ejj] + sm.gx[9][eb][ejj] + sm.gx[10][eb][ejj] + sm.gx[11][eb][ejj] + blstm[2048 + col];
        float go = sm.gx[12][eb][ejj] + sm.gx[13][eb][ejj] + sm.gx[14][eb][ejj] + sm.gx[15][eb][ejj] + blstm[3072 + col];
        cr = sigf(gf) * cr + sigf(gi) * tanhf(gg);
        float h = sigf(go) * tanhf(cr);
        stcc_f32(&out[(size_t)t * (BB * HH) + eb * HH + col], h);
        stcc_f32(&hfR[(size_t)(t + 1) * (BB * HH) + eb * HH + col], h);
        stcc_u16(&hbR[(size_t)(t + 1) * (BB * HH) + eb * HH + col], f2bf(h));
        if (t == TT - 1){
          stcc_f32(&out[1048576 + eb * HH + col], h);
          stcc_f32(&out[1081344 + eb * HH + col], cr);
        }
      }
    }
    gbar(bar, 64, epoch);
  }
}

// ---------- workspace layout (proven, no aliases) ----------
static constexpr size_t oWihE = 0;
static constexpr size_t oWhhE = oWihE + 4194304;
static constexpr size_t oAttnW= oWhhE + 8388608;
static constexpr size_t oW1C  = oAttnW+ 2097152;
static constexpr size_t oW1O  = oW1C  + 8388608;
static constexpr size_t oW2   = oW1O  + 4194304;
static constexpr size_t oWihL = oW2   + 8388608;
static constexpr size_t oWhhL = oWihL + 8388608;
static constexpr size_t oBEnc = oWhhL + 8388608;
static constexpr size_t oBL   = oBEnc + 16384;
static constexpr size_t oDemoT= oBL   + 16384;
static constexpr size_t oObsB = oDemoT+ 4194304;
static constexpr size_t oXih  = oObsB + 1048576;
static constexpr size_t oObsP = oXih  + 33554432;
static constexpr size_t oDEnc = oObsP + 8388608;
static constexpr size_t oAPrj = oDEnc + 8388608;
static constexpr size_t oZE   = oAPrj + 8388608;
static constexpr size_t oHFR  = oZE   + 65536;
static constexpr size_t oHBR  = oHFR  + 4325376;
static constexpr size_t oCtxR = oHBR  + 2162688;
static constexpr size_t oMBR  = oCtxR + 2097152;
static constexpr size_t oXBR  = oMBR  + 8388608;
static constexpr size_t oScX  = oXBR  + 2097152;
static constexpr size_t oBar  = oScX  + 524288;

extern "C" void kernel_launch(void* const* d_in, const int* in_sizes, int n_in,
                              void* d_out, int out_size, void* d_ws, size_t ws_size,
                              hipStream_t stream)
{
  const float* demo = (const float*)d_in[0];
  const int*   lens = (const int*)  d_in[1];
  const float* obs  = (const float*)d_in[2];
  const float* h0   = (const float*)d_in[3];
  const float* c0   = (const float*)d_in[4];
  const float* eWih = (const float*)d_in[5];
  const float* eWhh = (const float*)d_in[6];
  const float* eBih = (const float*)d_in[7];
  const float* eBhh = (const float*)d_in[8];
  const float* aW   = (const float*)d_in[9];
  const float* aB   = (const float*)d_in[10];
  const float* W1   = (const float*)d_in[11];
  const float* B1   = (const float*)d_in[12];
  const float* W2   = (const float*)d_in[13];
  const float* B2   = (const float*)d_in[14];
  const float* lWih = (const float*)d_in[15];
  const float* lWhh = (const float*)d_in[16];
  const float* lBih = (const float*)d_in[17];
  const float* lBhh = (const float*)d_in[18];

  char* ws = (char*)d_ws;
  u16*  WihE = (u16*)(ws + oWihE);
  u16*  WhhE = (u16*)(ws + oWhhE);
  u16*  AttnW= (u16*)(ws + oAttnW);
  u16*  W1C  = (u16*)(ws + oW1C);
  u16*  W1O  = (u16*)(ws + oW1O);
  u16*  W2w  = (u16*)(ws + oW2);
  u16*  WihL = (u16*)(ws + oWihL);
  u16*  WhhL = (u16*)(ws + oWhhL);
  float* BEnc= (float*)(ws + oBEnc);
  float* BL  = (float*)(ws + oBL);
  u16*  DemoT= (u16*)(ws + oDemoT);
  u16*  ObsB = (u16*)(ws + oObsB);
  u16*  Xih  = (u16*)(ws + oXih);
  u16*  ObsP = (u16*)(ws + oObsP);
  u16*  DEnc = (u16*)(ws + oDEnc);
  u16*  APrj = (u16*)(ws + oAPrj);
  u16*  ZE   = (u16*)(ws + oZE);
  float* HFR = (float*)(ws + oHFR);
  u16*  HBR  = (u16*)(ws + oHBR);
  u16*  CtxR = (u16*)(ws + oCtxR);
  u16*  MBR  = (u16*)(ws + oMBR);
  u16*  XBR  = (u16*)(ws + oXBR);
  float* ScX = (float*)(ws + oScX);
  u32*  Bar  = (u32*)(ws + oBar);

  k_convert<<<1024, 256, 0, stream>>>(eWih, WihE, G4 * FF);
  k_convert<<<1024, 256, 0, stream>>>(eWhh, WhhE, G4 * HH);
  k_convert<<<512,  256, 0, stream>>>(aW,   AttnW, HH * HH);
  k_split_w1<<<1024, 256, 0, stream>>>(W1, W1C, W1O);
  k_convert<<<1024, 256, 0, stream>>>(W2,   W2w,  HH * G4);
  k_convert<<<1024, 256, 0, stream>>>(lWih, WihL, G4 * HH);
  k_convert<<<1024, 256, 0, stream>>>(lWhh, WhhL, G4 * HH);
  k_addb<<<16, 256, 0, stream>>>(eBih, eBhh, BEnc, G4);
  k_addb<<<16, 256, 0, stream>>>(lBih, lBhh, BL, G4);
  k_demo_t<<<1024, 256, 0, stream>>>(demo, DemoT);
  k_convert<<<512, 256, 0, stream>>>(obs, ObsB, TT * BB * FF);
  hipMemsetAsync(Bar, 0, 256, stream);

  {
    dim3 g(LL * BB / 128, G4 / 128);
    k_gemm_bt<0><<<g, 256, 0, stream>>>(DemoT, WihE, BEnc, Xih, LL * BB, G4, FF);
  }
  {
    dim3 g(TT * BB / 128, G4 / 128);
    k_gemm_bt<0><<<g, 256, 0, stream>>>(ObsB, W1O, B1, ObsP, TT * BB, G4, FF);
  }

  k_encoder<<<64, 1024, 0, stream>>>(WhhE, Xih, ZE, DEnc, Bar);

  {
    dim3 g(LL * BB / 128, HH / 128);
    k_gemm_bt<0><<<g, 256, 0, stream>>>(DEnc, AttnW, aB, APrj, LL * BB, HH, HH);
  }

  k_decoder<<<64, 1024, 0, stream>>>(APrj, DEnc, ObsP, W1C, W2w, WihL, WhhL,
                                     BL, B2, h0, c0, lens,
                                     HFR, HBR, CtxR, MBR, XBR, ScX,
                                     (float*)d_out, Bar + 16);
}

// Round 13
// 2662.756 us; speedup vs baseline: 1.4382x; 1.0050x over previous
//
#include <hip/hip_runtime.h>

typedef unsigned short u16;
typedef unsigned int   u32;
typedef short s8v __attribute__((ext_vector_type(8)));
typedef float f4v __attribute__((ext_vector_type(4)));

// Problem constants
#define TT 32
#define BB 32
#define LL 128
#define FF 512
#define HH 1024
#define G4 4096
#define SCALE_ 0.08838834764831845f   // 1/sqrt(128)

// ---------- helpers ----------
__device__ __forceinline__ u16 f2bf(float f){
  u32 u = __float_as_uint(f);
  u32 r = u + 0x7fffu + ((u >> 16) & 1u);   // RNE
  return (u16)(r >> 16);
}
__device__ __forceinline__ float bf2f(u16 s){ return __uint_as_float(((u32)s) << 16); }
__device__ __forceinline__ float sigf(float x){ return 1.f / (1.f + __expf(-x)); }

__device__ __forceinline__ void mfma16(f4v& d, s8v a, s8v b){
  asm("v_mfma_f32_16x16x32_bf16 %0, %1, %2, %0" : "+v"(d) : "v"(a), "v"(b));
}

typedef __attribute__((address_space(3))) u32 as3u32;
typedef __attribute__((address_space(1))) u32 as1u32;
__device__ __forceinline__ void glds16(const u16* g, u16* l){
  __builtin_amdgcn_global_load_lds((const as1u32*)g, (as3u32*)l, 16, 0, 0);
}

// ---- producer stores: write-through to LLC (coherent point) ----
__device__ __forceinline__ void stcc_u16(u16* p, u16 v){
  u32 vv = v;
  asm volatile("global_store_short %0, %1, off sc0 sc1" :: "v"(p), "v"(vv) : "memory");
}
__device__ __forceinline__ void stcc_f32(float* p, float v){
  asm volatile("global_store_dword %0, %1, off sc0 sc1" :: "v"(p), "v"(v) : "memory");
}
__device__ __forceinline__ u32 poll_ld(const u32* p){
  u32 v;
  asm volatile("global_load_dword %0, %1, off sc0 sc1\n\ts_waitcnt vmcnt(0)"
               : "=v"(v) : "v"(p) : "memory");
  return v;
}

// grid barrier: vmcnt(0) drains producer sc0sc1 stores (release);
// sc0sc1 poll is the acquire. DISCIPLINE (hard-learned, rounds 6/7/12):
// every cross-block buffer must be (a) rotated per step, (b) written exactly
// once before its first read, (c) never aliased onto memory touched earlier
// in the launch. Then plain cached reads can never observe stale lines.
__device__ __forceinline__ void gbar(u32* cnt, u32 nblk, u32& epoch){
  asm volatile("s_waitcnt vmcnt(0)" ::: "memory");
  __syncthreads();
  ++epoch;
  if (threadIdx.x == 0){
    atomicAdd(cnt, 1u);
    u32 target = epoch * nblk;
    while (poll_ld(cnt) < target) __builtin_amdgcn_s_sleep(1);
  }
  __syncthreads();
}

// ---------- 1024-thread staging (encoder): [32][1024] u16 -> LDS, XOR swizzle ----------
__device__ __forceinline__ void stg_issue(const u16* __restrict__ src, s8v* tmp, int rstride){
  const int tid = threadIdx.x;
  const int row = tid >> 5, s0 = tid & 31;
  const u16* p = src + (size_t)row * rstride + s0 * 8;
  #pragma unroll
  for (int i = 0; i < 4; i++) tmp[i] = *(const s8v*)(p + i * 256);
}
__device__ __forceinline__ void stg_commit(const s8v* tmp, u16* lds){
  const int tid = threadIdx.x;
  const int row = tid >> 5, s0 = tid & 31;
  char* base = (char*)lds + (row << 11);
  u32 x = (u32)(row & 15) << 4;
  #pragma unroll
  for (int i = 0; i < 4; i++){
    u32 cb = (u32)(s0 + 32 * i) << 4;
    *(s8v*)(base + (cb ^ x)) = tmp[i];
  }
}
// ---------- 512-thread staging, 32 rows: [32][1024] ----------
__device__ __forceinline__ void st5_issue(const u16* __restrict__ src, s8v* tmp, int rstride){
  const int tid = threadIdx.x;
  const int row = tid >> 4, s0 = tid & 15;
  const u16* p = src + (size_t)row * rstride + s0 * 8;
  #pragma unroll
  for (int i = 0; i < 8; i++) tmp[i] = *(const s8v*)(p + i * 128);
}
__device__ __forceinline__ void st5_commit(const s8v* tmp, u16* lds){
  const int tid = threadIdx.x;
  const int row = tid >> 4, s0 = tid & 15;
  char* base = (char*)lds + (row << 11);
  u32 x = (u32)(row & 15) << 4;
  #pragma unroll
  for (int i = 0; i < 8; i++){
    u32 cb = (u32)(s0 + 16 * i) << 4;
    *(s8v*)(base + (cb ^ x)) = tmp[i];
  }
}
// ---------- 512-thread staging, 16 rows: [16][1024] ----------
__device__ __forceinline__ void st16_issue(const u16* __restrict__ src, s8v* tmp, int rstride){
  const int tid = threadIdx.x;
  const int row = tid >> 5, s0 = tid & 31;   // row 0..15
  const u16* p = src + (size_t)row * rstride + s0 * 8;
  #pragma unroll
  for (int i = 0; i < 4; i++) tmp[i] = *(const s8v*)(p + i * 256);
}
__device__ __forceinline__ void st16_commit(const s8v* tmp, u16* lds){
  const int tid = threadIdx.x;
  const int row = tid >> 5, s0 = tid & 31;
  char* base = (char*)lds + (row << 11);
  u32 x = (u32)(row & 15) << 4;
  #pragma unroll
  for (int i = 0; i < 4; i++){
    u32 cb = (u32)(s0 + 32 * i) << 4;
    *(s8v*)(base + (cb ^ x)) = tmp[i];
  }
}
__device__ __forceinline__ s8v ldsA(const u16* lds, int row, int cb){
  return *(const s8v*)((const char*)lds + (row << 11) + (cb ^ ((row & 15) << 4)));
}

// ---------- prep kernels ----------
__global__ void k_convert(const float* __restrict__ src, u16* __restrict__ dst, int n){
  int i = blockIdx.x * blockDim.x + threadIdx.x;
  int st = gridDim.x * blockDim.x;
  for (; i < n; i += st) dst[i] = f2bf(src[i]);
}
__global__ void k_split_w1(const float* __restrict__ w1, u16* __restrict__ w1c, u16* __restrict__ w1o){
  int i = blockIdx.x * blockDim.x + threadIdx.x;
  int st = gridDim.x * blockDim.x;
  const int n = G4 * (FF + HH);
  for (; i < n; i += st){
    int j = i / 1536, k = i - j * 1536;
    u16 v = f2bf(w1[i]);
    if (k < HH) w1c[j * HH + k] = v;
    else        w1o[j * FF + (k - HH)] = v;
  }
}
__global__ void k_addb(const float* __restrict__ a, const float* __restrict__ b,
                       float* __restrict__ o, int n){
  int i = blockIdx.x * blockDim.x + threadIdx.x;
  int st = gridDim.x * blockDim.x;
  for (; i < n; i += st) o[i] = a[i] + b[i];
}
__global__ void k_demo_t(const float* __restrict__ d, u16* __restrict__ o){
  const int n = LL * BB * FF;
  int i = blockIdx.x * blockDim.x + threadIdx.x;
  int st = gridDim.x * blockDim.x;
  for (; i < n; i += st){
    int f = i & 511;
    int row = i >> 9;
    int l = row >> 5, b = row & 31;
    o[i] = f2bf(d[(size_t)b * (LL * FF) + l * FF + f]);
  }
}

// ---------- generic GEMM (unchanged, proven) ----------
template<int RELU>
__global__ void __launch_bounds__(256) k_gemm_bt(const u16* __restrict__ A, const u16* __restrict__ B,
        const float* __restrict__ bias, u16* __restrict__ C, int M, int N, int K)
{
  __shared__ u16 As[128 * 64];
  __shared__ u16 Bs[128 * 64];
  const int tid = threadIdx.x;
  const int lane = tid & 63, wave = tid >> 6;
  const int m0 = blockIdx.x * 128, n0 = blockIdx.y * 128;
  const int wm = wave >> 1, wn = wave & 1;
  const int lr = lane & 15, lk = (lane >> 4) * 8;
  f4v acc[4][4];
  #pragma unroll
  for (int i = 0; i < 4; i++)
    #pragma unroll
    for (int j = 0; j < 4; j++) acc[i][j] = f4v{0.f, 0.f, 0.f, 0.f};

  for (int kt = 0; kt < K; kt += 64){
    #pragma unroll
    for (int i = 0; i < 4; i++){
      int c = tid + i * 256;
      int row = c >> 3, cc = (c & 7) * 8;
      glds16(A + (size_t)(m0 + row) * K + kt + cc, &As[c * 8]);
      glds16(B + (size_t)(n0 + row) * K + kt + cc, &Bs[c * 8]);
    }
    __syncthreads();
    #pragma unroll
    for (int ks = 0; ks < 2; ++ks){
      int ko = ks * 32 + lk;
      s8v av[4], bv[4];
      #pragma unroll
      for (int m = 0; m < 4; m++) av[m] = *(const s8v*)&As[(wm * 64 + m * 16 + lr) * 64 + ko];
      #pragma unroll
      for (int n = 0; n < 4; n++) bv[n] = *(const s8v*)&Bs[(wn * 64 + n * 16 + lr) * 64 + ko];
      #pragma unroll
      for (int m = 0; m < 4; m++)
        #pragma unroll
        for (int n = 0; n < 4; n++) mfma16(acc[m][n], av[m], bv[n]);
    }
    __syncthreads();
  }
  const int r0 = (lane >> 4) * 4;
  #pragma unroll
  for (int m = 0; m < 4; m++){
    #pragma unroll
    for (int n = 0; n < 4; n++){
      int col = n0 + wn * 64 + n * 16 + lr;
      float bc = bias[col];
      #pragma unroll
      for (int r = 0; r < 4; r++){
        int row = m0 + wm * 64 + m * 16 + r0 + r;
        float v = acc[m][n][r] + bc;
        if (RELU) v = fmaxf(v, 0.f);
        C[(size_t)row * N + col] = f2bf(v);
      }
    }
  }
}

// ---------- encoder: round-11 verbatim (passed) ----------
union SMemE { u16 stage[32768]; float gx[16][32][17]; };

__global__ void __launch_bounds__(1024, 4) k_encoder(const u16* __restrict__ Whh, const u16* __restrict__ Xih,
      u16* __restrict__ zslot, u16* __restrict__ denc, u32* bar)
{
  __shared__ SMemE sm;
  const int nb = blockIdx.x, tid = threadIdx.x;
  const int lane = tid & 63, w = tid >> 6;
  const int jc = nb * 16;
  const int lr = lane & 15, lk = (lane >> 4) * 8;
  const int eb = tid >> 4, ejj = tid & 15;
  const int rb = (lane >> 4) * 4;

  if (tid < 512) stcc_u16(&zslot[eb * HH + jc + ejj], 0);
  float cr = 0.f;
  u32 epoch = 0;
  gbar(bar, 64, epoch);

  const int kh = (w & 3) * 256;
  const u16* Wb = Whh + (size_t)((w >> 2) * HH + jc + lr) * HH + kh + lk;
  for (int l = 0; l < LL; ++l){
    const u16* hb = (l == 0) ? zslot : (denc + (size_t)(l - 1) * (BB * HH));
    s8v ht[4];
    stg_issue(hb, ht, HH);
    float xi = 0, xf = 0, xg = 0, xo = 0;
    if (tid < 512){
      const u16* xr = Xih + ((size_t)(l * BB + eb)) * G4 + jc + ejj;
      xi = bf2f(xr[0]); xf = bf2f(xr[1024]); xg = bf2f(xr[2048]); xo = bf2f(xr[3072]);
    }
    stg_commit(ht, sm.stage);
    __syncthreads();
    f4v a0 = {0.f,0.f,0.f,0.f}, a1 = {0.f,0.f,0.f,0.f};
    #pragma unroll
    for (int ks = 0; ks < 8; ++ks){
      int cb = (kh + lk + ks * 32) * 2;
      s8v va0 = ldsA(sm.stage, lr,      cb);
      s8v va1 = ldsA(sm.stage, lr + 16, cb);
      s8v vb  = *(const s8v*)(Wb + ks * 32);
      mfma16(a0, va0, vb);
      mfma16(a1, va1, vb);
    }
    __syncthreads();
    #pragma unroll
    for (int r = 0; r < 4; r++){ sm.gx[w][rb + r][lr] = a0[r]; sm.gx[w][16 + rb + r][lr] = a1[r]; }
    __syncthreads();
    if (tid < 512){
      float gi = sm.gx[0][eb][ejj] + sm.gx[1][eb][ejj] + sm.gx[2][eb][ejj] + sm.gx[3][eb][ejj] + xi;
      float gf = sm.gx[4][eb][ejj] + sm.gx[5][eb][ejj] + sm.gx[6][eb][ejj] + sm.gx[7][eb][ejj] + xf;
      float gg = sm.gx[8][eb][ejj] + sm.gx[9][eb][ejj] + sm.gx[10][eb][ejj] + sm.gx[11][eb][ejj] + xg;
      float go = sm.gx[12][eb][ejj] + sm.gx[13][eb][ejj] + sm.gx[14][eb][ejj] + sm.gx[15][eb][ejj] + xo;
      cr = sigf(gf) * cr + sigf(gi) * tanhf(gg);
      float h = sigf(go) * tanhf(cr);
      stcc_u16(&denc[(size_t)l * (BB * HH) + eb * HH + jc + ejj], f2bf(h));
    }
    gbar(bar, 64, epoch);
  }
}

// ---------- decoder: 128 blocks x 512 threads; NO partial buffers ----------
union SMemD {
  u16 stage[32768];
  float gx[8][32][17];
  struct { float swt[128]; } a;
  char pad[98304];                 // 96KB LDS -> 1 block/CU -> 128 CUs busy
};

__global__ void __launch_bounds__(512, 1) k_decoder(
    const u16* __restrict__ aproj, const u16* __restrict__ denc, const u16* __restrict__ obsp,
    const u16* __restrict__ W1c, const u16* __restrict__ W2w, const u16* __restrict__ WihL,
    const u16* __restrict__ WhhL, const float* __restrict__ blstm, const float* __restrict__ b2,
    const float* __restrict__ h0, const float* __restrict__ c0, const int* __restrict__ lens,
    float* __restrict__ hfR, u16* __restrict__ hbR, u16* __restrict__ ctxR,
    u16* __restrict__ mbR, u16* __restrict__ xbR, float* __restrict__ scX,
    float* __restrict__ out, u32* bar)
{
  __shared__ SMemD sm;
  const int nb = blockIdx.x, tid = threadIdx.x;
  const int lane = tid & 63, w = tid >> 6;         // 8 waves
  const int lr = lane & 15, lk = (lane >> 4) * 8;
  const int rb = (lane >> 4) * 4;
  const int eb = tid >> 4, ejj = tid & 15;         // 32-batch elementwise map (B)
  const int ab = nb & 31, aq = nb >> 5;            // A: batch, l/ctx quarter
  const int pb = nb >> 1, bh = nb & 1;             // C/D: 16-col group, batch half
  const int jc = pb * 16;

  float cr = 0.f;
  if (tid < 256){
    int b = bh * 16 + (tid >> 4), col = jc + (tid & 15);
    float hv = h0[b * HH + col];
    stcc_f32(&hfR[b * HH + col], hv);
    stcc_u16(&hbR[b * HH + col], f2bf(hv));
    cr = c0[b * HH + col];
  }
  u32 epoch = 0;
  gbar(bar, 128, epoch);

  for (int t = 0; t < TT; ++t){
    const u16* ctxS = ctxR + (size_t)t * (BB * HH);
    const u16* mbS  = mbR  + (size_t)t * (BB * G4);
    const u16* xbS  = xbR  + (size_t)t * (BB * HH);
    const u16* hbS  = hbR  + (size_t)t * (BB * HH);
    const float* hfS= hfR  + (size_t)t * (BB * HH);
    float* scT = scX + (size_t)t * (BB * 128) + ab * 128;

    // ---- A1: scores for batch ab, l-quarter aq (8 waves x 4 l) ----
    {
      const int len = lens[ab];
      float hr[16];
      const float* hp = hfS + ab * HH + lane * 16;
      #pragma unroll
      for (int i = 0; i < 16; i++) hr[i] = hp[i];
      #pragma unroll
      for (int i = 0; i < 4; ++i){
        int l = aq * 32 + w * 4 + i;
        const u16* ap = aproj + ((size_t)(l * BB + ab)) * HH + lane * 16;
        s8v v0 = *(const s8v*)ap;
        s8v v1 = *(const s8v*)(ap + 8);
        float s = 0.f;
        #pragma unroll
        for (int k = 0; k < 8; k++) s += bf2f((u16)v0[k]) * hr[k];
        #pragma unroll
        for (int k = 0; k < 8; k++) s += bf2f((u16)v1[k]) * hr[8 + k];
        #pragma unroll
        for (int off = 32; off > 0; off >>= 1) s += __shfl_down(s, off);
        if (lane == 0){
          s *= SCALE_;
          if (l >= len && l != 0) s = -__builtin_inff();
          stcc_f32(&scT[l], s);
        }
      }
    }
    gbar(bar, 128, epoch);

    // ---- A2: softmax (replicated in quad) + ctx quarter ----
    {
      if (w == 0){
        float x0 = scT[lane], x1 = scT[lane + 64];   // plain: virgin rotated slot
        float mx = fmaxf(x0, x1);
        #pragma unroll
        for (int off = 32; off > 0; off >>= 1) mx = fmaxf(mx, __shfl_xor(mx, off));
        float e0 = __expf(x0 - mx), e1 = __expf(x1 - mx);
        float smv = e0 + e1;
        #pragma unroll
        for (int off = 32; off > 0; off >>= 1) smv += __shfl_xor(smv, off);
        float inv = 1.f / smv;
        sm.a.swt[lane] = e0 * inv;
        sm.a.swt[lane + 64] = e1 * inv;
      }
      __syncthreads();
      if (tid < 256){
        int col = aq * 256 + tid;
        const u16* dp = denc + (size_t)ab * HH + col;
        float acc = 0.f;
        #pragma unroll 4
        for (int l = 0; l < LL; ++l)
          acc += sm.a.swt[l] * bf2f(dp[(size_t)l * (BB * HH)]);
        stcc_u16((u16*)&ctxS[ab * HH + col], f2bf(acc));
      }
    }
    gbar(bar, 128, epoch);

    // ---- B: m[:, nb*32 .. +31] = relu(ctx @ W1c^T + obsp[t]); 8 waves = 2 cg x 4 kq ----
    {
      s8v ct[8];
      st5_issue(ctxS, ct, HH);
      st5_commit(ct, sm.stage);
      __syncthreads();
      const int col0 = nb * 32 + (w >> 2) * 16;
      const int kh = (w & 3) * 256;
      f4v a0 = {0.f,0.f,0.f,0.f}, a1 = {0.f,0.f,0.f,0.f};
      const u16* Bp = W1c + (size_t)(col0 + lr) * HH + kh + lk;
      #pragma unroll
      for (int ks = 0; ks < 8; ++ks){
        int cb = (kh + lk + ks * 32) * 2;
        s8v va0 = ldsA(sm.stage, lr,      cb);
        s8v va1 = ldsA(sm.stage, lr + 16, cb);
        s8v vb  = *(const s8v*)(Bp + ks * 32);
        mfma16(a0, va0, vb);
        mfma16(a1, va1, vb);
      }
      __syncthreads();            // stage dead -> gx overlay
      #pragma unroll
      for (int r = 0; r < 4; r++){ sm.gx[w][rb + r][lr] = a0[r]; sm.gx[w][16 + rb + r][lr] = a1[r]; }
      __syncthreads();
      #pragma unroll
      for (int cg = 0; cg < 2; ++cg){
        int col = nb * 32 + cg * 16 + ejj;
        float v = sm.gx[4 * cg][eb][ejj] + sm.gx[4 * cg + 1][eb][ejj]
                + sm.gx[4 * cg + 2][eb][ejj] + sm.gx[4 * cg + 3][eb][ejj]
                + bf2f(obsp[((size_t)(t * BB + eb)) * G4 + col]);
        stcc_u16((u16*)&mbS[eb * G4 + col], f2bf(fmaxf(v, 0.f)));
      }
    }
    gbar(bar, 128, epoch);

    // ---- C: x[bh*16..+15, jc..+15] = relu(m @ W2^T + b2); FULL K per block ----
    {
      f4v a0 = {0.f,0.f,0.f,0.f};
      for (int q = 0; q < 4; ++q){
        s8v ct[4];
        st16_issue(mbS + (size_t)(bh * 16) * G4 + q * 1024, ct, G4);
        st16_commit(ct, sm.stage);
        __syncthreads();
        const u16* Bp = W2w + (size_t)(jc + lr) * G4 + q * 1024 + w * 128 + lk;
        #pragma unroll
        for (int ks = 0; ks < 4; ++ks){
          int cb = (w * 128 + lk + ks * 32) * 2;
          s8v va0 = ldsA(sm.stage, lr, cb);
          s8v vb  = *(const s8v*)(Bp + ks * 32);
          mfma16(a0, va0, vb);
        }
        __syncthreads();
      }
      #pragma unroll
      for (int r = 0; r < 4; r++) sm.gx[w][rb + r][lr] = a0[r];
      __syncthreads();
      if (tid < 256){
        int bb = tid >> 4, cc = tid & 15;
        float v = b2[jc + cc];
        #pragma unroll
        for (int g = 0; g < 8; ++g) v += sm.gx[g][bb][cc];
        stcc_u16((u16*)&xbS[(bh * 16 + bb) * HH + jc + cc], f2bf(fmaxf(v, 0.f)));
      }
    }
    gbar(bar, 128, epoch);

    // ---- D: gates[bh-half, jc..+15] = x@WihL^T + h@WhhL^T; 8 waves = 4 gates x 2 K-halves ----
    {
      s8v xt[4], ht[4];
      st16_issue(xbS + (size_t)(bh * 16) * HH, xt, HH);
      st16_issue(hbS + (size_t)(bh * 16) * HH, ht, HH);
      st16_commit(xt, sm.stage);              // x: LDS rows 0..15 (bytes 0..32767)
      st16_commit(ht, sm.stage + 16384);      // h: bytes 32768..65535
      __syncthreads();
      const int gate = w >> 1, kh = (w & 1) * 512;
      f4v a0 = {0.f,0.f,0.f,0.f};
      const u16* Bx = WihL + (size_t)(gate * HH + jc + lr) * HH + kh + lk;
      #pragma unroll
      for (int ks = 0; ks < 16; ++ks){
        int cb = (kh + lk + ks * 32) * 2;
        mfma16(a0, ldsA(sm.stage, lr, cb), *(const s8v*)(Bx + ks * 32));
      }
      const u16* Bh = WhhL + (size_t)(gate * HH + jc + lr) * HH + kh + lk;
      #pragma unroll
      for (int ks = 0; ks < 16; ++ks){
        int cb = (kh + lk + ks * 32) * 2;
        mfma16(a0, ldsA(sm.stage + 16384, lr, cb), *(const s8v*)(Bh + ks * 32));
      }
      __syncthreads();
      #pragma unroll
      for (int r = 0; r < 4; r++) sm.gx[w][rb + r][lr] = a0[r];
      __syncthreads();
      if (tid < 256){
        int bb = tid >> 4, cc = tid & 15;
        int b = bh * 16 + bb, col = jc + cc;
        float gi = sm.gx[0][bb][cc] + sm.gx[1][bb][cc] + blstm[col];
        float gf = sm.gx[2][bb][cc] + sm.gx[3][bb][cc] + blstm[1024 + col];
        float gg = sm.gx[4][bb][cc] + sm.gx[5][bb][cc] + blstm[2048 + col];
        float go = sm.gx[6][bb][cc] + sm.gx[7][bb][cc] + blstm[3072 + col];
        cr = sigf(gf) * cr + sigf(gi) * tanhf(gg);
        float h = sigf(go) * tanhf(cr);
        stcc_f32(&out[(size_t)t * (BB * HH) + b * HH + col], h);
        stcc_f32(&hfR[(size_t)(t + 1) * (BB * HH) + b * HH + col], h);
        stcc_u16(&hbR[(size_t)(t + 1) * (BB * HH) + b * HH + col], f2bf(h));
        if (t == TT - 1){
          stcc_f32(&out[1048576 + b * HH + col], h);
          stcc_f32(&out[1081344 + b * HH + col], cr);
        }
      }
    }
    gbar(bar, 128, epoch);
  }
}

// ---------- workspace layout (round-11 proven, no aliases) ----------
static constexpr size_t oWihE = 0;
static constexpr size_t oWhhE = oWihE + 4194304;
static constexpr size_t oAttnW= oWhhE + 8388608;
static constexpr size_t oW1C  = oAttnW+ 2097152;
static constexpr size_t oW1O  = oW1C  + 8388608;
static constexpr size_t oW2   = oW1O  + 4194304;
static constexpr size_t oWihL = oW2   + 8388608;
static constexpr size_t oWhhL = oWihL + 8388608;
static constexpr size_t oBEnc = oWhhL + 8388608;
static constexpr size_t oBL   = oBEnc + 16384;
static constexpr size_t oDemoT= oBL   + 16384;
static constexpr size_t oObsB = oDemoT+ 4194304;
static constexpr size_t oXih  = oObsB + 1048576;
static constexpr size_t oObsP = oXih  + 33554432;
static constexpr size_t oDEnc = oObsP + 8388608;
static constexpr size_t oAPrj = oDEnc + 8388608;
static constexpr size_t oZE   = oAPrj + 8388608;
static constexpr size_t oHFR  = oZE   + 65536;
static constexpr size_t oHBR  = oHFR  + 4325376;
static constexpr size_t oCtxR = oHBR  + 2162688;
static constexpr size_t oMBR  = oCtxR + 2097152;
static constexpr size_t oXBR  = oMBR  + 8388608;
static constexpr size_t oScX  = oXBR  + 2097152;
static constexpr size_t oBar  = oScX  + 524288;

extern "C" void kernel_launch(void* const* d_in, const int* in_sizes, int n_in,
                              void* d_out, int out_size, void* d_ws, size_t ws_size,
                              hipStream_t stream)
{
  const float* demo = (const float*)d_in[0];
  const int*   lens = (const int*)  d_in[1];
  const float* obs  = (const float*)d_in[2];
  const float* h0   = (const float*)d_in[3];
  const float* c0   = (const float*)d_in[4];
  const float* eWih = (const float*)d_in[5];
  const float* eWhh = (const float*)d_in[6];
  const float* eBih = (const float*)d_in[7];
  const float* eBhh = (const float*)d_in[8];
  const float* aW   = (const float*)d_in[9];
  const float* aB   = (const float*)d_in[10];
  const float* W1   = (const float*)d_in[11];
  const float* B1   = (const float*)d_in[12];
  const float* W2   = (const float*)d_in[13];
  const float* B2   = (const float*)d_in[14];
  const float* lWih = (const float*)d_in[15];
  const float* lWhh = (const float*)d_in[16];
  const float* lBih = (const float*)d_in[17];
  const float* lBhh = (const float*)d_in[18];

  char* ws = (char*)d_ws;
  u16*  WihE = (u16*)(ws + oWihE);
  u16*  WhhE = (u16*)(ws + oWhhE);
  u16*  AttnW= (u16*)(ws + oAttnW);
  u16*  W1C  = (u16*)(ws + oW1C);
  u16*  W1O  = (u16*)(ws + oW1O);
  u16*  W2w  = (u16*)(ws + oW2);
  u16*  WihL = (u16*)(ws + oWihL);
  u16*  WhhL = (u16*)(ws + oWhhL);
  float* BEnc= (float*)(ws + oBEnc);
  float* BL  = (float*)(ws + oBL);
  u16*  DemoT= (u16*)(ws + oDemoT);
  u16*  ObsB = (u16*)(ws + oObsB);
  u16*  Xih  = (u16*)(ws + oXih);
  u16*  ObsP = (u16*)(ws + oObsP);
  u16*  DEnc = (u16*)(ws + oDEnc);
  u16*  APrj = (u16*)(ws + oAPrj);
  u16*  ZE   = (u16*)(ws + oZE);
  float* HFR = (float*)(ws + oHFR);
  u16*  HBR  = (u16*)(ws + oHBR);
  u16*  CtxR = (u16*)(ws + oCtxR);
  u16*  MBR  = (u16*)(ws + oMBR);
  u16*  XBR  = (u16*)(ws + oXBR);
  float* ScX = (float*)(ws + oScX);
  u32*  Bar  = (u32*)(ws + oBar);

  k_convert<<<1024, 256, 0, stream>>>(eWih, WihE, G4 * FF);
  k_convert<<<1024, 256, 0, stream>>>(eWhh, WhhE, G4 * HH);
  k_convert<<<512,  256, 0, stream>>>(aW,   AttnW, HH * HH);
  k_split_w1<<<1024, 256, 0, stream>>>(W1, W1C, W1O);
  k_convert<<<1024, 256, 0, stream>>>(W2,   W2w,  HH * G4);
  k_convert<<<1024, 256, 0, stream>>>(lWih, WihL, G4 * HH);
  k_convert<<<1024, 256, 0, stream>>>(lWhh, WhhL, G4 * HH);
  k_addb<<<16, 256, 0, stream>>>(eBih, eBhh, BEnc, G4);
  k_addb<<<16, 256, 0, stream>>>(lBih, lBhh, BL, G4);
  k_demo_t<<<1024, 256, 0, stream>>>(demo, DemoT);
  k_convert<<<512, 256, 0, stream>>>(obs, ObsB, TT * BB * FF);
  hipMemsetAsync(Bar, 0, 256, stream);

  {
    dim3 g(LL * BB / 128, G4 / 128);
    k_gemm_bt<0><<<g, 256, 0, stream>>>(DemoT, WihE, BEnc, Xih, LL * BB, G4, FF);
  }
  {
    dim3 g(TT * BB / 128, G4 / 128);
    k_gemm_bt<0><<<g, 256, 0, stream>>>(ObsB, W1O, B1, ObsP, TT * BB, G4, FF);
  }

  k_encoder<<<64, 1024, 0, stream>>>(WhhE, Xih, ZE, DEnc, Bar);

  {
    dim3 g(LL * BB / 128, HH / 128);
    k_gemm_bt<0><<<g, 256, 0, stream>>>(DEnc, AttnW, aB, APrj, LL * BB, HH, HH);
  }

  k_decoder<<<128, 512, 0, stream>>>(APrj, DEnc, ObsP, W1C, W2w, WihL, WhhL,
                                     BL, B2, h0, c0, lens,
                                     HFR, HBR, CtxR, MBR, XBR, ScX,
                                     (float*)d_out, Bar + 16);
}

// Round 14
// 2550.552 us; speedup vs baseline: 1.5015x; 1.0440x over previous
//
#include <hip/hip_runtime.h>

typedef unsigned short u16;
typedef unsigned int   u32;
typedef short s8v __attribute__((ext_vector_type(8)));
typedef float f4v __attribute__((ext_vector_type(4)));

// Problem constants
#define TT 32
#define BB 32
#define LL 128
#define FF 512
#define HH 1024
#define G4 4096
#define SCALE_ 0.08838834764831845f   // 1/sqrt(128)

// ---------- helpers ----------
__device__ __forceinline__ u16 f2bf(float f){
  u32 u = __float_as_uint(f);
  u32 r = u + 0x7fffu + ((u >> 16) & 1u);   // RNE
  return (u16)(r >> 16);
}
__device__ __forceinline__ float bf2f(u16 s){ return __uint_as_float(((u32)s) << 16); }
__device__ __forceinline__ float sigf(float x){ return 1.f / (1.f + __expf(-x)); }

__device__ __forceinline__ void mfma16(f4v& d, s8v a, s8v b){
  asm("v_mfma_f32_16x16x32_bf16 %0, %1, %2, %0" : "+v"(d) : "v"(a), "v"(b));
}

typedef __attribute__((address_space(3))) u32 as3u32;
typedef __attribute__((address_space(1))) u32 as1u32;
__device__ __forceinline__ void glds16(const u16* g, u16* l){
  __builtin_amdgcn_global_load_lds((const as1u32*)g, (as3u32*)l, 16, 0, 0);
}

// ---- producer stores: write-through to LLC (coherent point) ----
__device__ __forceinline__ void stcc_u16(u16* p, u16 v){
  u32 vv = v;
  asm volatile("global_store_short %0, %1, off sc0 sc1" :: "v"(p), "v"(vv) : "memory");
}
__device__ __forceinline__ void stcc_f32(float* p, float v){
  asm volatile("global_store_dword %0, %1, off sc0 sc1" :: "v"(p), "v"(v) : "memory");
}
__device__ __forceinline__ u32 poll_ld(const u32* p){
  u32 v;
  asm volatile("global_load_dword %0, %1, off sc0 sc1\n\ts_waitcnt vmcnt(0)"
               : "=v"(v) : "v"(p) : "memory");
  return v;
}

// grid barrier: vmcnt(0) drains producer sc0sc1 stores (release);
// sc0sc1 poll is the acquire. DISCIPLINE (hard-learned, rounds 6/7/12):
// every cross-block buffer must be (a) rotated per step, (b) written exactly
// once before its first read, (c) never aliased onto memory touched earlier
// in the launch. Then plain cached reads can never observe stale lines.
__device__ __forceinline__ void gbar(u32* cnt, u32 nblk, u32& epoch){
  asm volatile("s_waitcnt vmcnt(0)" ::: "memory");
  __syncthreads();
  ++epoch;
  if (threadIdx.x == 0){
    atomicAdd(cnt, 1u);
    u32 target = epoch * nblk;
    while (poll_ld(cnt) < target) __builtin_amdgcn_s_sleep(1);
  }
  __syncthreads();
}

// ---------- 1024-thread staging (encoder): [32][1024] u16 -> LDS, XOR swizzle ----------
__device__ __forceinline__ void stg_issue(const u16* __restrict__ src, s8v* tmp, int rstride){
  const int tid = threadIdx.x;
  const int row = tid >> 5, s0 = tid & 31;
  const u16* p = src + (size_t)row * rstride + s0 * 8;
  #pragma unroll
  for (int i = 0; i < 4; i++) tmp[i] = *(const s8v*)(p + i * 256);
}
__device__ __forceinline__ void stg_commit(const s8v* tmp, u16* lds){
  const int tid = threadIdx.x;
  const int row = tid >> 5, s0 = tid & 31;
  char* base = (char*)lds + (row << 11);
  u32 x = (u32)(row & 15) << 4;
  #pragma unroll
  for (int i = 0; i < 4; i++){
    u32 cb = (u32)(s0 + 32 * i) << 4;
    *(s8v*)(base + (cb ^ x)) = tmp[i];
  }
}
// ---------- 512-thread staging, 32 rows: [32][1024] ----------
__device__ __forceinline__ void st5_issue(const u16* __restrict__ src, s8v* tmp, int rstride){
  const int tid = threadIdx.x;
  const int row = tid >> 4, s0 = tid & 15;
  const u16* p = src + (size_t)row * rstride + s0 * 8;
  #pragma unroll
  for (int i = 0; i < 8; i++) tmp[i] = *(const s8v*)(p + i * 128);
}
__device__ __forceinline__ void st5_commit(const s8v* tmp, u16* lds){
  const int tid = threadIdx.x;
  const int row = tid >> 4, s0 = tid & 15;
  char* base = (char*)lds + (row << 11);
  u32 x = (u32)(row & 15) << 4;
  #pragma unroll
  for (int i = 0; i < 8; i++){
    u32 cb = (u32)(s0 + 16 * i) << 4;
    *(s8v*)(base + (cb ^ x)) = tmp[i];
  }
}
// ---------- 512-thread staging, 16 rows: [16][1024] ----------
__device__ __forceinline__ void st16_issue(const u16* __restrict__ src, s8v* tmp, int rstride){
  const int tid = threadIdx.x;
  const int row = tid >> 5, s0 = tid & 31;   // row 0..15
  const u16* p = src + (size_t)row * rstride + s0 * 8;
  #pragma unroll
  for (int i = 0; i < 4; i++) tmp[i] = *(const s8v*)(p + i * 256);
}
__device__ __forceinline__ void st16_commit(const s8v* tmp, u16* lds){
  const int tid = threadIdx.x;
  const int row = tid >> 5, s0 = tid & 31;
  char* base = (char*)lds + (row << 11);
  u32 x = (u32)(row & 15) << 4;
  #pragma unroll
  for (int i = 0; i < 4; i++){
    u32 cb = (u32)(s0 + 32 * i) << 4;
    *(s8v*)(base + (cb ^ x)) = tmp[i];
  }
}
__device__ __forceinline__ s8v ldsA(const u16* lds, int row, int cb){
  return *(const s8v*)((const char*)lds + (row << 11) + (cb ^ ((row & 15) << 4)));
}

// ---------- prep kernels ----------
__global__ void k_convert(const float* __restrict__ src, u16* __restrict__ dst, int n){
  int i = blockIdx.x * blockDim.x + threadIdx.x;
  int st = gridDim.x * blockDim.x;
  for (; i < n; i += st) dst[i] = f2bf(src[i]);
}
__global__ void k_split_w1(const float* __restrict__ w1, u16* __restrict__ w1c, u16* __restrict__ w1o){
  int i = blockIdx.x * blockDim.x + threadIdx.x;
  int st = gridDim.x * blockDim.x;
  const int n = G4 * (FF + HH);
  for (; i < n; i += st){
    int j = i / 1536, k = i - j * 1536;
    u16 v = f2bf(w1[i]);
    if (k < HH) w1c[j * HH + k] = v;
    else        w1o[j * FF + (k - HH)] = v;
  }
}
__global__ void k_addb(const float* __restrict__ a, const float* __restrict__ b,
                       float* __restrict__ o, int n){
  int i = blockIdx.x * blockDim.x + threadIdx.x;
  int st = gridDim.x * blockDim.x;
  for (; i < n; i += st) o[i] = a[i] + b[i];
}
__global__ void k_demo_t(const float* __restrict__ d, u16* __restrict__ o){
  const int n = LL * BB * FF;
  int i = blockIdx.x * blockDim.x + threadIdx.x;
  int st = gridDim.x * blockDim.x;
  for (; i < n; i += st){
    int f = i & 511;
    int row = i >> 9;
    int l = row >> 5, b = row & 31;
    o[i] = f2bf(d[(size_t)b * (LL * FF) + l * FF + f]);
  }
}

// ---------- generic GEMM (unchanged, proven) ----------
template<int RELU>
__global__ void __launch_bounds__(256) k_gemm_bt(const u16* __restrict__ A, const u16* __restrict__ B,
        const float* __restrict__ bias, u16* __restrict__ C, int M, int N, int K)
{
  __shared__ u16 As[128 * 64];
  __shared__ u16 Bs[128 * 64];
  const int tid = threadIdx.x;
  const int lane = tid & 63, wave = tid >> 6;
  const int m0 = blockIdx.x * 128, n0 = blockIdx.y * 128;
  const int wm = wave >> 1, wn = wave & 1;
  const int lr = lane & 15, lk = (lane >> 4) * 8;
  f4v acc[4][4];
  #pragma unroll
  for (int i = 0; i < 4; i++)
    #pragma unroll
    for (int j = 0; j < 4; j++) acc[i][j] = f4v{0.f, 0.f, 0.f, 0.f};

  for (int kt = 0; kt < K; kt += 64){
    #pragma unroll
    for (int i = 0; i < 4; i++){
      int c = tid + i * 256;
      int row = c >> 3, cc = (c & 7) * 8;
      glds16(A + (size_t)(m0 + row) * K + kt + cc, &As[c * 8]);
      glds16(B + (size_t)(n0 + row) * K + kt + cc, &Bs[c * 8]);
    }
    __syncthreads();
    #pragma unroll
    for (int ks = 0; ks < 2; ++ks){
      int ko = ks * 32 + lk;
      s8v av[4], bv[4];
      #pragma unroll
      for (int m = 0; m < 4; m++) av[m] = *(const s8v*)&As[(wm * 64 + m * 16 + lr) * 64 + ko];
      #pragma unroll
      for (int n = 0; n < 4; n++) bv[n] = *(const s8v*)&Bs[(wn * 64 + n * 16 + lr) * 64 + ko];
      #pragma unroll
      for (int m = 0; m < 4; m++)
        #pragma unroll
        for (int n = 0; n < 4; n++) mfma16(acc[m][n], av[m], bv[n]);
    }
    __syncthreads();
  }
  const int r0 = (lane >> 4) * 4;
  #pragma unroll
  for (int m = 0; m < 4; m++){
    #pragma unroll
    for (int n = 0; n < 4; n++){
      int col = n0 + wn * 64 + n * 16 + lr;
      float bc = bias[col];
      #pragma unroll
      for (int r = 0; r < 4; r++){
        int row = m0 + wm * 64 + m * 16 + r0 + r;
        float v = acc[m][n][r] + bc;
        if (RELU) v = fmaxf(v, 0.f);
        C[(size_t)row * N + col] = f2bf(v);
      }
    }
  }
}

// ---------- encoder: round-11 verbatim (passed) ----------
union SMemE { u16 stage[32768]; float gx[16][32][17]; };

__global__ void __launch_bounds__(1024, 4) k_encoder(const u16* __restrict__ Whh, const u16* __restrict__ Xih,
      u16* __restrict__ zslot, u16* __restrict__ denc, u32* bar)
{
  __shared__ SMemE sm;
  const int nb = blockIdx.x, tid = threadIdx.x;
  const int lane = tid & 63, w = tid >> 6;
  const int jc = nb * 16;
  const int lr = lane & 15, lk = (lane >> 4) * 8;
  const int eb = tid >> 4, ejj = tid & 15;
  const int rb = (lane >> 4) * 4;

  if (tid < 512) stcc_u16(&zslot[eb * HH + jc + ejj], 0);
  float cr = 0.f;
  u32 epoch = 0;
  gbar(bar, 64, epoch);

  const int kh = (w & 3) * 256;
  const u16* Wb = Whh + (size_t)((w >> 2) * HH + jc + lr) * HH + kh + lk;
  for (int l = 0; l < LL; ++l){
    const u16* hb = (l == 0) ? zslot : (denc + (size_t)(l - 1) * (BB * HH));
    s8v ht[4];
    stg_issue(hb, ht, HH);
    float xi = 0, xf = 0, xg = 0, xo = 0;
    if (tid < 512){
      const u16* xr = Xih + ((size_t)(l * BB + eb)) * G4 + jc + ejj;
      xi = bf2f(xr[0]); xf = bf2f(xr[1024]); xg = bf2f(xr[2048]); xo = bf2f(xr[3072]);
    }
    stg_commit(ht, sm.stage);
    __syncthreads();
    f4v a0 = {0.f,0.f,0.f,0.f}, a1 = {0.f,0.f,0.f,0.f};
    #pragma unroll
    for (int ks = 0; ks < 8; ++ks){
      int cb = (kh + lk + ks * 32) * 2;
      s8v va0 = ldsA(sm.stage, lr,      cb);
      s8v va1 = ldsA(sm.stage, lr + 16, cb);
      s8v vb  = *(const s8v*)(Wb + ks * 32);
      mfma16(a0, va0, vb);
      mfma16(a1, va1, vb);
    }
    __syncthreads();
    #pragma unroll
    for (int r = 0; r < 4; r++){ sm.gx[w][rb + r][lr] = a0[r]; sm.gx[w][16 + rb + r][lr] = a1[r]; }
    __syncthreads();
    if (tid < 512){
      float gi = sm.gx[0][eb][ejj] + sm.gx[1][eb][ejj] + sm.gx[2][eb][ejj] + sm.gx[3][eb][ejj] + xi;
      float gf = sm.gx[4][eb][ejj] + sm.gx[5][eb][ejj] + sm.gx[6][eb][ejj] + sm.gx[7][eb][ejj] + xf;
      float gg = sm.gx[8][eb][ejj] + sm.gx[9][eb][ejj] + sm.gx[10][eb][ejj] + sm.gx[11][eb][ejj] + xg;
      float go = sm.gx[12][eb][ejj] + sm.gx[13][eb][ejj] + sm.gx[14][eb][ejj] + sm.gx[15][eb][ejj] + xo;
      cr = sigf(gf) * cr + sigf(gi) * tanhf(gg);
      float h = sigf(go) * tanhf(cr);
      stcc_u16(&denc[(size_t)l * (BB * HH) + eb * HH + jc + ejj], f2bf(h));
    }
    gbar(bar, 64, epoch);
  }
}

// ---------- decoder: 128 blocks x 512 threads; round-13 + XCD pair-swizzle ----------
union SMemD {
  u16 stage[32768];
  float gx[8][32][17];
  struct { float swt[128]; } a;
  char pad[98304];                 // 96KB LDS -> 1 block/CU -> 128 CUs busy
};

__global__ void __launch_bounds__(512, 1) k_decoder(
    const u16* __restrict__ aproj, const u16* __restrict__ denc, const u16* __restrict__ obsp,
    const u16* __restrict__ W1c, const u16* __restrict__ W2w, const u16* __restrict__ WihL,
    const u16* __restrict__ WhhL, const float* __restrict__ blstm, const float* __restrict__ b2,
    const float* __restrict__ h0, const float* __restrict__ c0, const int* __restrict__ lens,
    float* __restrict__ hfR, u16* __restrict__ hbR, u16* __restrict__ ctxR,
    u16* __restrict__ mbR, u16* __restrict__ xbR, float* __restrict__ scX,
    float* __restrict__ out, u32* bar)
{
  __shared__ SMemD sm;
  // XCD pair-swizzle: default dispatch puts consecutive blocks on different
  // XCDs (xcd = blockIdx % 8). Remap so logical pairs (2pb, 2pb+1) -- which
  // share W2/WihL/WhhL column slices -- land on the SAME XCD: per-XCD weight
  // footprint drops ~7MB -> ~4MB, making weights L2-resident across t.
  // Bijective on [0,128): p&7 in [0,8), p>>3 in [0,16).
  const int p = blockIdx.x;
  const int nb = (p & 7) * 16 + (p >> 3);
  const int tid = threadIdx.x;
  const int lane = tid & 63, w = tid >> 6;         // 8 waves
  const int lr = lane & 15, lk = (lane >> 4) * 8;
  const int rb = (lane >> 4) * 4;
  const int eb = tid >> 4, ejj = tid & 15;         // 32-batch elementwise map (B)
  const int ab = nb & 31, aq = nb >> 5;            // A: batch, l/ctx quarter
  const int pb = nb >> 1, bh = nb & 1;             // C/D: 16-col group, batch half
  const int jc = pb * 16;

  float cr = 0.f;
  if (tid < 256){
    int b = bh * 16 + (tid >> 4), col = jc + (tid & 15);
    float hv = h0[b * HH + col];
    stcc_f32(&hfR[b * HH + col], hv);
    stcc_u16(&hbR[b * HH + col], f2bf(hv));
    cr = c0[b * HH + col];
  }
  u32 epoch = 0;
  gbar(bar, 128, epoch);

  for (int t = 0; t < TT; ++t){
    const u16* ctxS = ctxR + (size_t)t * (BB * HH);
    const u16* mbS  = mbR  + (size_t)t * (BB * G4);
    const u16* xbS  = xbR  + (size_t)t * (BB * HH);
    const u16* hbS  = hbR  + (size_t)t * (BB * HH);
    const float* hfS= hfR  + (size_t)t * (BB * HH);
    float* scT = scX + (size_t)t * (BB * 128) + ab * 128;

    // ---- A1: scores for batch ab, l-quarter aq (8 waves x 4 l) ----
    {
      const int len = lens[ab];
      float hr[16];
      const float* hp = hfS + ab * HH + lane * 16;
      #pragma unroll
      for (int i = 0; i < 16; i++) hr[i] = hp[i];
      #pragma unroll
      for (int i = 0; i < 4; ++i){
        int l = aq * 32 + w * 4 + i;
        const u16* ap = aproj + ((size_t)(l * BB + ab)) * HH + lane * 16;
        s8v v0 = *(const s8v*)ap;
        s8v v1 = *(const s8v*)(ap + 8);
        float s = 0.f;
        #pragma unroll
        for (int k = 0; k < 8; k++) s += bf2f((u16)v0[k]) * hr[k];
        #pragma unroll
        for (int k = 0; k < 8; k++) s += bf2f((u16)v1[k]) * hr[8 + k];
        #pragma unroll
        for (int off = 32; off > 0; off >>= 1) s += __shfl_down(s, off);
        if (lane == 0){
          s *= SCALE_;
          if (l >= len && l != 0) s = -__builtin_inff();
          stcc_f32(&scT[l], s);
        }
      }
    }
    gbar(bar, 128, epoch);

    // ---- A2: softmax (replicated in quad) + ctx quarter ----
    {
      if (w == 0){
        float x0 = scT[lane], x1 = scT[lane + 64];   // plain: virgin rotated slot
        float mx = fmaxf(x0, x1);
        #pragma unroll
        for (int off = 32; off > 0; off >>= 1) mx = fmaxf(mx, __shfl_xor(mx, off));
        float e0 = __expf(x0 - mx), e1 = __expf(x1 - mx);
        float smv = e0 + e1;
        #pragma unroll
        for (int off = 32; off > 0; off >>= 1) smv += __shfl_xor(smv, off);
        float inv = 1.f / smv;
        sm.a.swt[lane] = e0 * inv;
        sm.a.swt[lane + 64] = e1 * inv;
      }
      __syncthreads();
      if (tid < 256){
        int col = aq * 256 + tid;
        const u16* dp = denc + (size_t)ab * HH + col;
        float acc = 0.f;
        #pragma unroll 4
        for (int l = 0; l < LL; ++l)
          acc += sm.a.swt[l] * bf2f(dp[(size_t)l * (BB * HH)]);
        stcc_u16((u16*)&ctxS[ab * HH + col], f2bf(acc));
      }
    }
    gbar(bar, 128, epoch);

    // ---- B: m[:, nb*32 .. +31] = relu(ctx @ W1c^T + obsp[t]); 8 waves = 2 cg x 4 kq ----
    {
      s8v ct[8];
      st5_issue(ctxS, ct, HH);
      st5_commit(ct, sm.stage);
      __syncthreads();
      const int col0 = nb * 32 + (w >> 2) * 16;
      const int kh = (w & 3) * 256;
      f4v a0 = {0.f,0.f,0.f,0.f}, a1 = {0.f,0.f,0.f,0.f};
      const u16* Bp = W1c + (size_t)(col0 + lr) * HH + kh + lk;
      #pragma unroll
      for (int ks = 0; ks < 8; ++ks){
        int cb = (kh + lk + ks * 32) * 2;
        s8v va0 = ldsA(sm.stage, lr,      cb);
        s8v va1 = ldsA(sm.stage, lr + 16, cb);
        s8v vb  = *(const s8v*)(Bp + ks * 32);
        mfma16(a0, va0, vb);
        mfma16(a1, va1, vb);
      }
      __syncthreads();            // stage dead -> gx overlay
      #pragma unroll
      for (int r = 0; r < 4; r++){ sm.gx[w][rb + r][lr] = a0[r]; sm.gx[w][16 + rb + r][lr] = a1[r]; }
      __syncthreads();
      #pragma unroll
      for (int cg = 0; cg < 2; ++cg){
        int col = nb * 32 + cg * 16 + ejj;
        float v = sm.gx[4 * cg][eb][ejj] + sm.gx[4 * cg + 1][eb][ejj]
                + sm.gx[4 * cg + 2][eb][ejj] + sm.gx[4 * cg + 3][eb][ejj]
                + bf2f(obsp[((size_t)(t * BB + eb)) * G4 + col]);
        stcc_u16((u16*)&mbS[eb * G4 + col], f2bf(fmaxf(v, 0.f)));
      }
    }
    gbar(bar, 128, epoch);

    // ---- C: x[bh*16..+15, jc..+15] = relu(m @ W2^T + b2); FULL K per block ----
    {
      f4v a0 = {0.f,0.f,0.f,0.f};
      for (int q = 0; q < 4; ++q){
        s8v ct[4];
        st16_issue(mbS + (size_t)(bh * 16) * G4 + q * 1024, ct, G4);
        st16_commit(ct, sm.stage);
        __syncthreads();
        const u16* Bp = W2w + (size_t)(jc + lr) * G4 + q * 1024 + w * 128 + lk;
        #pragma unroll
        for (int ks = 0; ks < 4; ++ks){
          int cb = (w * 128 + lk + ks * 32) * 2;
          s8v va0 = ldsA(sm.stage, lr, cb);
          s8v vb  = *(const s8v*)(Bp + ks * 32);
          mfma16(a0, va0, vb);
        }
        __syncthreads();
      }
      #pragma unroll
      for (int r = 0; r < 4; r++) sm.gx[w][rb + r][lr] = a0[r];
      __syncthreads();
      if (tid < 256){
        int bb = tid >> 4, cc = tid & 15;
        float v = b2[jc + cc];
        #pragma unroll
        for (int g = 0; g < 8; ++g) v += sm.gx[g][bb][cc];
        stcc_u16((u16*)&xbS[(bh * 16 + bb) * HH + jc + cc], f2bf(fmaxf(v, 0.f)));
      }
    }
    gbar(bar, 128, epoch);

    // ---- D: gates[bh-half, jc..+15] = x@WihL^T + h@WhhL^T; 8 waves = 4 gates x 2 K-halves ----
    {
      s8v xt[4], ht[4];
      st16_issue(xbS + (size_t)(bh * 16) * HH, xt, HH);
      st16_issue(hbS + (size_t)(bh * 16) * HH, ht, HH);
      st16_commit(xt, sm.stage);              // x: LDS rows 0..15 (bytes 0..32767)
      st16_commit(ht, sm.stage + 16384);      // h: bytes 32768..65535
      __syncthreads();
      const int gate = w >> 1, kh = (w & 1) * 512;
      f4v a0 = {0.f,0.f,0.f,0.f};
      const u16* Bx = WihL + (size_t)(gate * HH + jc + lr) * HH + kh + lk;
      #pragma unroll
      for (int ks = 0; ks < 16; ++ks){
        int cb = (kh + lk + ks * 32) * 2;
        mfma16(a0, ldsA(sm.stage, lr, cb), *(const s8v*)(Bx + ks * 32));
      }
      const u16* Bh = WhhL + (size_t)(gate * HH + jc + lr) * HH + kh + lk;
      #pragma unroll
      for (int ks = 0; ks < 16; ++ks){
        int cb = (kh + lk + ks * 32) * 2;
        mfma16(a0, ldsA(sm.stage + 16384, lr, cb), *(const s8v*)(Bh + ks * 32));
      }
      __syncthreads();
      #pragma unroll
      for (int r = 0; r < 4; r++) sm.gx[w][rb + r][lr] = a0[r];
      __syncthreads();
      if (tid < 256){
        int bb = tid >> 4, cc = tid & 15;
        int b = bh * 16 + bb, col = jc + cc;
        float gi = sm.gx[0][bb][cc] + sm.gx[1][bb][cc] + blstm[col];
        float gf = sm.gx[2][bb][cc] + sm.gx[3][bb][cc] + blstm[1024 + col];
        float gg = sm.gx[4][bb][cc] + sm.gx[5][bb][cc] + blstm[2048 + col];
        float go = sm.gx[6][bb][cc] + sm.gx[7][bb][cc] + blstm[3072 + col];
        cr = sigf(gf) * cr + sigf(gi) * tanhf(gg);
        float h = sigf(go) * tanhf(cr);
        stcc_f32(&out[(size_t)t * (BB * HH) + b * HH + col], h);
        stcc_f32(&hfR[(size_t)(t + 1) * (BB * HH) + b * HH + col], h);
        stcc_u16(&hbR[(size_t)(t + 1) * (BB * HH) + b * HH + col], f2bf(h));
        if (t == TT - 1){
          stcc_f32(&out[1048576 + b * HH + col], h);
          stcc_f32(&out[1081344 + b * HH + col], cr);
        }
      }
    }
    gbar(bar, 128, epoch);
  }
}

// ---------- workspace layout (round-13 proven, no aliases) ----------
static constexpr size_t oWihE = 0;
static constexpr size_t oWhhE = oWihE + 4194304;
static constexpr size_t oAttnW= oWhhE + 8388608;
static constexpr size_t oW1C  = oAttnW+ 2097152;
static constexpr size_t oW1O  = oW1C  + 8388608;
static constexpr size_t oW2   = oW1O  + 4194304;
static constexpr size_t oWihL = oW2   + 8388608;
static constexpr size_t oWhhL = oWihL + 8388608;
static constexpr size_t oBEnc = oWhhL + 8388608;
static constexpr size_t oBL   = oBEnc + 16384;
static constexpr size_t oDemoT= oBL   + 16384;
static constexpr size_t oObsB = oDemoT+ 4194304;
static constexpr size_t oXih  = oObsB + 1048576;
static constexpr size_t oObsP = oXih  + 33554432;
static constexpr size_t oDEnc = oObsP + 8388608;
static constexpr size_t oAPrj = oDEnc + 8388608;
static constexpr size_t oZE   = oAPrj + 8388608;
static constexpr size_t oHFR  = oZE   + 65536;
static constexpr size_t oHBR  = oHFR  + 4325376;
static constexpr size_t oCtxR = oHBR  + 2162688;
static constexpr size_t oMBR  = oCtxR + 2097152;
static constexpr size_t oXBR  = oMBR  + 8388608;
static constexpr size_t oScX  = oXBR  + 2097152;
static constexpr size_t oBar  = oScX  + 524288;

extern "C" void kernel_launch(void* const* d_in, const int* in_sizes, int n_in,
                              void* d_out, int out_size, void* d_ws, size_t ws_size,
                              hipStream_t stream)
{
  const float* demo = (const float*)d_in[0];
  const int*   lens = (const int*)  d_in[1];
  const float* obs  = (const float*)d_in[2];
  const float* h0   = (const float*)d_in[3];
  const float* c0   = (const float*)d_in[4];
  const float* eWih = (const float*)d_in[5];
  const float* eWhh = (const float*)d_in[6];
  const float* eBih = (const float*)d_in[7];
  const float* eBhh = (const float*)d_in[8];
  const float* aW   = (const float*)d_in[9];
  const float* aB   = (const float*)d_in[10];
  const float* W1   = (const float*)d_in[11];
  const float* B1   = (const float*)d_in[12];
  const float* W2   = (const float*)d_in[13];
  const float* B2   = (const float*)d_in[14];
  const float* lWih = (const float*)d_in[15];
  const float* lWhh = (const float*)d_in[16];
  const float* lBih = (const float*)d_in[17];
  const float* lBhh = (const float*)d_in[18];

  char* ws = (char*)d_ws;
  u16*  WihE = (u16*)(ws + oWihE);
  u16*  WhhE = (u16*)(ws + oWhhE);
  u16*  AttnW= (u16*)(ws + oAttnW);
  u16*  W1C  = (u16*)(ws + oW1C);
  u16*  W1O  = (u16*)(ws + oW1O);
  u16*  W2w  = (u16*)(ws + oW2);
  u16*  WihL = (u16*)(ws + oWihL);
  u16*  WhhL = (u16*)(ws + oWhhL);
  float* BEnc= (float*)(ws + oBEnc);
  float* BL  = (float*)(ws + oBL);
  u16*  DemoT= (u16*)(ws + oDemoT);
  u16*  ObsB = (u16*)(ws + oObsB);
  u16*  Xih  = (u16*)(ws + oXih);
  u16*  ObsP = (u16*)(ws + oObsP);
  u16*  DEnc = (u16*)(ws + oDEnc);
  u16*  APrj = (u16*)(ws + oAPrj);
  u16*  ZE   = (u16*)(ws + oZE);
  float* HFR = (float*)(ws + oHFR);
  u16*  HBR  = (u16*)(ws + oHBR);
  u16*  CtxR = (u16*)(ws + oCtxR);
  u16*  MBR  = (u16*)(ws + oMBR);
  u16*  XBR  = (u16*)(ws + oXBR);
  float* ScX = (float*)(ws + oScX);
  u32*  Bar  = (u32*)(ws + oBar);

  k_convert<<<1024, 256, 0, stream>>>(eWih, WihE, G4 * FF);
  k_convert<<<1024, 256, 0, stream>>>(eWhh, WhhE, G4 * HH);
  k_convert<<<512,  256, 0, stream>>>(aW,   AttnW, HH * HH);
  k_split_w1<<<1024, 256, 0, stream>>>(W1, W1C, W1O);
  k_convert<<<1024, 256, 0, stream>>>(W2,   W2w,  HH * G4);
  k_convert<<<1024, 256, 0, stream>>>(lWih, WihL, G4 * HH);
  k_convert<<<1024, 256, 0, stream>>>(lWhh, WhhL, G4 * HH);
  k_addb<<<16, 256, 0, stream>>>(eBih, eBhh, BEnc, G4);
  k_addb<<<16, 256, 0, stream>>>(lBih, lBhh, BL, G4);
  k_demo_t<<<1024, 256, 0, stream>>>(demo, DemoT);
  k_convert<<<512, 256, 0, stream>>>(obs, ObsB, TT * BB * FF);
  hipMemsetAsync(Bar, 0, 256, stream);

  {
    dim3 g(LL * BB / 128, G4 / 128);
    k_gemm_bt<0><<<g, 256, 0, stream>>>(DemoT, WihE, BEnc, Xih, LL * BB, G4, FF);
  }
  {
    dim3 g(TT * BB / 128, G4 / 128);
    k_gemm_bt<0><<<g, 256, 0, stream>>>(ObsB, W1O, B1, ObsP, TT * BB, G4, FF);
  }

  k_encoder<<<64, 1024, 0, stream>>>(WhhE, Xih, ZE, DEnc, Bar);

  {
    dim3 g(LL * BB / 128, HH / 128);
    k_gemm_bt<0><<<g, 256, 0, stream>>>(DEnc, AttnW, aB, APrj, LL * BB, HH, HH);
  }

  k_decoder<<<128, 512, 0, stream>>>(APrj, DEnc, ObsP, W1C, W2w, WihL, WhhL,
                                     BL, B2, h0, c0, lens,
                                     HFR, HBR, CtxR, MBR, XBR, ScX,
                                     (float*)d_out, Bar + 16);
}

// Round 15
// 2536.480 us; speedup vs baseline: 1.5098x; 1.0055x over previous
//
#include <hip/hip_runtime.h>

typedef unsigned short u16;
typedef unsigned int   u32;
typedef short s8v __attribute__((ext_vector_type(8)));
typedef float f4v __attribute__((ext_vector_type(4)));

// Problem constants
#define TT 32
#define BB 32
#define LL 128
#define FF 512
#define HH 1024
#define G4 4096
#define SCALE_ 0.08838834764831845f   // 1/sqrt(128)

// ---------- helpers ----------
__device__ __forceinline__ u16 f2bf(float f){
  u32 u = __float_as_uint(f);
  u32 r = u + 0x7fffu + ((u >> 16) & 1u);   // RNE
  return (u16)(r >> 16);
}
__device__ __forceinline__ float bf2f(u16 s){ return __uint_as_float(((u32)s) << 16); }
__device__ __forceinline__ float sigf(float x){ return 1.f / (1.f + __expf(-x)); }

__device__ __forceinline__ void mfma16(f4v& d, s8v a, s8v b){
  asm("v_mfma_f32_16x16x32_bf16 %0, %1, %2, %0" : "+v"(d) : "v"(a), "v"(b));
}

typedef __attribute__((address_space(3))) u32 as3u32;
typedef __attribute__((address_space(1))) u32 as1u32;
__device__ __forceinline__ void glds16(const u16* g, u16* l){
  __builtin_amdgcn_global_load_lds((const as1u32*)g, (as3u32*)l, 16, 0, 0);
}

// ---- producer stores: write-through to LLC (coherent point) ----
__device__ __forceinline__ void stcc_u16(u16* p, u16 v){
  u32 vv = v;
  asm volatile("global_store_short %0, %1, off sc0 sc1" :: "v"(p), "v"(vv) : "memory");
}
__device__ __forceinline__ void stcc_u32(void* p, u32 v){
  asm volatile("global_store_dword %0, %1, off sc0 sc1" :: "v"(p), "v"(v) : "memory");
}
__device__ __forceinline__ void stcc_f32(float* p, float v){
  asm volatile("global_store_dword %0, %1, off sc0 sc1" :: "v"(p), "v"(v) : "memory");
}
__device__ __forceinline__ u32 poll_ld(const u32* p){
  u32 v;
  asm volatile("global_load_dword %0, %1, off sc0 sc1\n\ts_waitcnt vmcnt(0)"
               : "=v"(v) : "v"(p) : "memory");
  return v;
}

// grid barrier. DISCIPLINE (rounds 6/7/12): every cross-block buffer must be
// (a) rotated per step, (b) written exactly once before first read, (c) never
// aliased onto memory touched earlier in the launch.
__device__ __forceinline__ void gbar(u32* cnt, u32 nblk, u32& epoch){
  asm volatile("s_waitcnt vmcnt(0)" ::: "memory");
  __syncthreads();
  ++epoch;
  if (threadIdx.x == 0){
    atomicAdd(cnt, 1u);
    u32 target = epoch * nblk;
    while (poll_ld(cnt) < target) __builtin_amdgcn_s_sleep(1);
  }
  __syncthreads();
}

// ---------- 1024-thread staging (encoder): [32][1024] u16 -> LDS, XOR swizzle ----------
__device__ __forceinline__ void stg_issue(const u16* __restrict__ src, s8v* tmp, int rstride){
  const int tid = threadIdx.x;
  const int row = tid >> 5, s0 = tid & 31;
  const u16* p = src + (size_t)row * rstride + s0 * 8;
  #pragma unroll
  for (int i = 0; i < 4; i++) tmp[i] = *(const s8v*)(p + i * 256);
}
__device__ __forceinline__ void stg_commit(const s8v* tmp, u16* lds){
  const int tid = threadIdx.x;
  const int row = tid >> 5, s0 = tid & 31;
  char* base = (char*)lds + (row << 11);
  u32 x = (u32)(row & 15) << 4;
  #pragma unroll
  for (int i = 0; i < 4; i++){
    u32 cb = (u32)(s0 + 32 * i) << 4;
    *(s8v*)(base + (cb ^ x)) = tmp[i];
  }
}
// ---------- 512-thread staging, 32 rows: [32][1024] ----------
__device__ __forceinline__ void st5_issue(const u16* __restrict__ src, s8v* tmp, int rstride){
  const int tid = threadIdx.x;
  const int row = tid >> 4, s0 = tid & 15;
  const u16* p = src + (size_t)row * rstride + s0 * 8;
  #pragma unroll
  for (int i = 0; i < 8; i++) tmp[i] = *(const s8v*)(p + i * 128);
}
__device__ __forceinline__ void st5_commit(const s8v* tmp, u16* lds){
  const int tid = threadIdx.x;
  const int row = tid >> 4, s0 = tid & 15;
  char* base = (char*)lds + (row << 11);
  u32 x = (u32)(row & 15) << 4;
  #pragma unroll
  for (int i = 0; i < 8; i++){
    u32 cb = (u32)(s0 + 16 * i) << 4;
    *(s8v*)(base + (cb ^ x)) = tmp[i];
  }
}
// ---------- 512-thread staging, 16 rows: [16][1024] ----------
__device__ __forceinline__ void st16_issue(const u16* __restrict__ src, s8v* tmp, int rstride){
  const int tid = threadIdx.x;
  const int row = tid >> 5, s0 = tid & 31;   // row 0..15
  const u16* p = src + (size_t)row * rstride + s0 * 8;
  #pragma unroll
  for (int i = 0; i < 4; i++) tmp[i] = *(const s8v*)(p + i * 256);
}
__device__ __forceinline__ void st16_commit(const s8v* tmp, u16* lds){
  const int tid = threadIdx.x;
  const int row = tid >> 5, s0 = tid & 31;
  char* base = (char*)lds + (row << 11);
  u32 x = (u32)(row & 15) << 4;
  #pragma unroll
  for (int i = 0; i < 4; i++){
    u32 cb = (u32)(s0 + 32 * i) << 4;
    *(s8v*)(base + (cb ^ x)) = tmp[i];
  }
}
__device__ __forceinline__ s8v ldsA(const u16* lds, int row, int cb){
  return *(const s8v*)((const char*)lds + (row << 11) + (cb ^ ((row & 15) << 4)));
}

// ---------- prep kernels ----------
__global__ void k_convert(const float* __restrict__ src, u16* __restrict__ dst, int n){
  int i = blockIdx.x * blockDim.x + threadIdx.x;
  int st = gridDim.x * blockDim.x;
  for (; i < n; i += st) dst[i] = f2bf(src[i]);
}
__global__ void k_split_w1(const float* __restrict__ w1, u16* __restrict__ w1c, u16* __restrict__ w1o){
  int i = blockIdx.x * blockDim.x + threadIdx.x;
  int st = gridDim.x * blockDim.x;
  const int n = G4 * (FF + HH);
  for (; i < n; i += st){
    int j = i / 1536, k = i - j * 1536;
    u16 v = f2bf(w1[i]);
    if (k < HH) w1c[j * HH + k] = v;
    else        w1o[j * FF + (k - HH)] = v;
  }
}
__global__ void k_addb(const float* __restrict__ a, const float* __restrict__ b,
                       float* __restrict__ o, int n){
  int i = blockIdx.x * blockDim.x + threadIdx.x;
  int st = gridDim.x * blockDim.x;
  for (; i < n; i += st) o[i] = a[i] + b[i];
}
__global__ void k_demo_t(const float* __restrict__ d, u16* __restrict__ o){
  const int n = LL * BB * FF;
  int i = blockIdx.x * blockDim.x + threadIdx.x;
  int st = gridDim.x * blockDim.x;
  for (; i < n; i += st){
    int f = i & 511;
    int row = i >> 9;
    int l = row >> 5, b = row & 31;
    o[i] = f2bf(d[(size_t)b * (LL * FF) + l * FF + f]);
  }
}

// ---------- generic GEMM (unchanged, proven) ----------
template<int RELU>
__global__ void __launch_bounds__(256) k_gemm_bt(const u16* __restrict__ A, const u16* __restrict__ B,
        const float* __restrict__ bias, u16* __restrict__ C, int M, int N, int K)
{
  __shared__ u16 As[128 * 64];
  __shared__ u16 Bs[128 * 64];
  const int tid = threadIdx.x;
  const int lane = tid & 63, wave = tid >> 6;
  const int m0 = blockIdx.x * 128, n0 = blockIdx.y * 128;
  const int wm = wave >> 1, wn = wave & 1;
  const int lr = lane & 15, lk = (lane >> 4) * 8;
  f4v acc[4][4];
  #pragma unroll
  for (int i = 0; i < 4; i++)
    #pragma unroll
    for (int j = 0; j < 4; j++) acc[i][j] = f4v{0.f, 0.f, 0.f, 0.f};

  for (int kt = 0; kt < K; kt += 64){
    #pragma unroll
    for (int i = 0; i < 4; i++){
      int c = tid + i * 256;
      int row = c >> 3, cc = (c & 7) * 8;
      glds16(A + (size_t)(m0 + row) * K + kt + cc, &As[c * 8]);
      glds16(B + (size_t)(n0 + row) * K + kt + cc, &Bs[c * 8]);
    }
    __syncthreads();
    #pragma unroll
    for (int ks = 0; ks < 2; ++ks){
      int ko = ks * 32 + lk;
      s8v av[4], bv[4];
      #pragma unroll
      for (int m = 0; m < 4; m++) av[m] = *(const s8v*)&As[(wm * 64 + m * 16 + lr) * 64 + ko];
      #pragma unroll
      for (int n = 0; n < 4; n++) bv[n] = *(const s8v*)&Bs[(wn * 64 + n * 16 + lr) * 64 + ko];
      #pragma unroll
      for (int m = 0; m < 4; m++)
        #pragma unroll
        for (int n = 0; n < 4; n++) mfma16(acc[m][n], av[m], bv[n]);
    }
    __syncthreads();
  }
  const int r0 = (lane >> 4) * 4;
  #pragma unroll
  for (int m = 0; m < 4; m++){
    #pragma unroll
    for (int n = 0; n < 4; n++){
      int col = n0 + wn * 64 + n * 16 + lr;
      float bc = bias[col];
      #pragma unroll
      for (int r = 0; r < 4; r++){
        int row = m0 + wm * 64 + m * 16 + r0 + r;
        float v = acc[m][n][r] + bc;
        if (RELU) v = fmaxf(v, 0.f);
        C[(size_t)row * N + col] = f2bf(v);
      }
    }
  }
}

// ---------- encoder: round-11 verbatim (passed) ----------
union SMemE { u16 stage[32768]; float gx[16][32][17]; };

__global__ void __launch_bounds__(1024, 4) k_encoder(const u16* __restrict__ Whh, const u16* __restrict__ Xih,
      u16* __restrict__ zslot, u16* __restrict__ denc, u32* bar)
{
  __shared__ SMemE sm;
  const int nb = blockIdx.x, tid = threadIdx.x;
  const int lane = tid & 63, w = tid >> 6;
  const int jc = nb * 16;
  const int lr = lane & 15, lk = (lane >> 4) * 8;
  const int eb = tid >> 4, ejj = tid & 15;
  const int rb = (lane >> 4) * 4;

  if (tid < 512) stcc_u16(&zslot[eb * HH + jc + ejj], 0);
  float cr = 0.f;
  u32 epoch = 0;
  gbar(bar, 64, epoch);

  const int kh = (w & 3) * 256;
  const u16* Wb = Whh + (size_t)((w >> 2) * HH + jc + lr) * HH + kh + lk;
  for (int l = 0; l < LL; ++l){
    const u16* hb = (l == 0) ? zslot : (denc + (size_t)(l - 1) * (BB * HH));
    s8v ht[4];
    stg_issue(hb, ht, HH);
    float xi = 0, xf = 0, xg = 0, xo = 0;
    if (tid < 512){
      const u16* xr = Xih + ((size_t)(l * BB + eb)) * G4 + jc + ejj;
      xi = bf2f(xr[0]); xf = bf2f(xr[1024]); xg = bf2f(xr[2048]); xo = bf2f(xr[3072]);
    }
    stg_commit(ht, sm.stage);
    __syncthreads();
    f4v a0 = {0.f,0.f,0.f,0.f}, a1 = {0.f,0.f,0.f,0.f};
    #pragma unroll
    for (int ks = 0; ks < 8; ++ks){
      int cb = (kh + lk + ks * 32) * 2;
      s8v va0 = ldsA(sm.stage, lr,      cb);
      s8v va1 = ldsA(sm.stage, lr + 16, cb);
      s8v vb  = *(const s8v*)(Wb + ks * 32);
      mfma16(a0, va0, vb);
      mfma16(a1, va1, vb);
    }
    __syncthreads();
    #pragma unroll
    for (int r = 0; r < 4; r++){ sm.gx[w][rb + r][lr] = a0[r]; sm.gx[w][16 + rb + r][lr] = a1[r]; }
    __syncthreads();
    if (tid < 512){
      float gi = sm.gx[0][eb][ejj] + sm.gx[1][eb][ejj] + sm.gx[2][eb][ejj] + sm.gx[3][eb][ejj] + xi;
      float gf = sm.gx[4][eb][ejj] + sm.gx[5][eb][ejj] + sm.gx[6][eb][ejj] + sm.gx[7][eb][ejj] + xf;
      float gg = sm.gx[8][eb][ejj] + sm.gx[9][eb][ejj] + sm.gx[10][eb][ejj] + sm.gx[11][eb][ejj] + xg;
      float go = sm.gx[12][eb][ejj] + sm.gx[13][eb][ejj] + sm.gx[14][eb][ejj] + sm.gx[15][eb][ejj] + xo;
      cr = sigf(gf) * cr + sigf(gi) * tanhf(gg);
      float h = sigf(go) * tanhf(cr);
      stcc_u16(&denc[(size_t)l * (BB * HH) + eb * HH + jc + ejj], f2bf(h));
    }
    gbar(bar, 64, epoch);
  }
}

// ---------- decoder: 128 blocks x 512 threads; 4 barriers/t ----------
// Phase1: blocks 0..31 (physical) = fused attention (scores+softmax+ctx, one batch each);
//         blocks 32..95 = pGh[t] = h(t) @ WhhL^T (64 gate-rows each), concurrent.
// B, C: round-14 proven. D: x@WihL + pGh + bias (no h staging).
union SMemD {
  u16 stage[32768];
  float gx[8][32][17];
  struct { float ssc[128]; float swt[128]; } a;
  char pad[98304];                 // 96KB LDS -> 1 block/CU -> 128 CUs busy
};

__global__ void __launch_bounds__(512, 1) k_decoder(
    const u16* __restrict__ aproj, const u16* __restrict__ denc, const u16* __restrict__ obsp,
    const u16* __restrict__ W1c, const u16* __restrict__ W2w, const u16* __restrict__ WihL,
    const u16* __restrict__ WhhL, const float* __restrict__ blstm, const float* __restrict__ b2,
    const float* __restrict__ h0, const float* __restrict__ c0, const int* __restrict__ lens,
    float* __restrict__ hfR, u16* __restrict__ hbR, u16* __restrict__ ctxR,
    u16* __restrict__ mbR, u16* __restrict__ xbR, u16* __restrict__ pGh,
    float* __restrict__ out, u32* bar)
{
  __shared__ SMemD sm;
  const int p = blockIdx.x;
  // logical nb for B/C/D: pair-swizzle keeps (2pb,2pb+1) on one XCD (round-14 win)
  const int nb = (p & 7) * 16 + (p >> 3);
  const int tid = threadIdx.x;
  const int lane = tid & 63, w = tid >> 6;         // 8 waves
  const int lr = lane & 15, lk = (lane >> 4) * 8;
  const int rb = (lane >> 4) * 4;
  const int eb = tid >> 4, ejj = tid & 15;         // 32-batch elementwise map (B)
  const int pb = nb >> 1, bh = nb & 1;             // C/D: 16-col group, batch half
  const int jc = pb * 16;

  float cr = 0.f;
  if (tid < 256){
    int b = bh * 16 + (tid >> 4), col = jc + (tid & 15);
    float hv = h0[b * HH + col];
    stcc_f32(&hfR[b * HH + col], hv);
    stcc_u16(&hbR[b * HH + col], f2bf(hv));
    cr = c0[b * HH + col];
  }
  u32 epoch = 0;
  gbar(bar, 128, epoch);

  for (int t = 0; t < TT; ++t){
    const u16* ctxS = ctxR + (size_t)t * (BB * HH);
    const u16* mbS  = mbR  + (size_t)t * (BB * G4);
    const u16* xbS  = xbR  + (size_t)t * (BB * HH);
    const u16* hbS  = hbR  + (size_t)t * (BB * HH);
    const float* hfS= hfR  + (size_t)t * (BB * HH);
    u16* pGhT = pGh + (size_t)t * (BB * G4);

    // ---- Phase 1: fused attention (p<32) || Whh gate partials (32<=p<96) ----
    if (p < 32){
      const int ab = p;
      const int len = lens[ab];
      float hr[16];
      const float* hp = hfS + ab * HH + lane * 16;
      #pragma unroll
      for (int i = 0; i < 16; i++) hr[i] = hp[i];
      for (int i = 0; i < 16; ++i){
        int l = w * 16 + i;
        const u16* ap = aproj + ((size_t)(l * BB + ab)) * HH + lane * 16;
        s8v v0 = *(const s8v*)ap;
        s8v v1 = *(const s8v*)(ap + 8);
        float s = 0.f;
        #pragma unroll
        for (int k = 0; k < 8; k++) s += bf2f((u16)v0[k]) * hr[k];
        #pragma unroll
        for (int k = 0; k < 8; k++) s += bf2f((u16)v1[k]) * hr[8 + k];
        #pragma unroll
        for (int off = 32; off > 0; off >>= 1) s += __shfl_down(s, off);
        if (lane == 0){
          s *= SCALE_;
          if (l >= len && l != 0) s = -__builtin_inff();
          sm.a.ssc[l] = s;
        }
      }
      __syncthreads();
      if (w == 0){
        float x0 = sm.a.ssc[lane], x1 = sm.a.ssc[lane + 64];
        float mx = fmaxf(x0, x1);
        #pragma unroll
        for (int off = 32; off > 0; off >>= 1) mx = fmaxf(mx, __shfl_xor(mx, off));
        float e0 = __expf(x0 - mx), e1 = __expf(x1 - mx);
        float smv = e0 + e1;
        #pragma unroll
        for (int off = 32; off > 0; off >>= 1) smv += __shfl_xor(smv, off);
        float inv = 1.f / smv;
        sm.a.swt[lane] = e0 * inv;
        sm.a.swt[lane + 64] = e1 * inv;
      }
      __syncthreads();
      {
        int col = tid * 2;
        const u16* dp = denc + (size_t)ab * HH + col;
        float a0 = 0.f, a1 = 0.f;
        #pragma unroll 4
        for (int l = 0; l < LL; ++l){
          u32 dv = *(const u32*)(dp + (size_t)l * (BB * HH));
          a0 += sm.a.swt[l] * bf2f((u16)(dv & 0xffff));
          a1 += sm.a.swt[l] * bf2f((u16)(dv >> 16));
        }
        u32 pk = ((u32)f2bf(a1) << 16) | f2bf(a0);
        stcc_u32((void*)(ctxS + ab * HH + col), pk);
      }
    } else if (p < 96){
      const int gr = p - 32;               // 64 gate-row groups of 64 rows
      const int rows0 = gr * 64;
      s8v ht[8];
      st5_issue(hbS, ht, HH);
      st5_commit(ht, sm.stage);
      __syncthreads();
      const int tile = w & 3, kh2 = (w >> 2) * 512;
      f4v a0 = {0.f,0.f,0.f,0.f}, a1 = {0.f,0.f,0.f,0.f};
      const u16* Bh = WhhL + (size_t)(rows0 + tile * 16 + lr) * HH + kh2 + lk;
      #pragma unroll
      for (int ks = 0; ks < 16; ++ks){
        int cb = (kh2 + lk + ks * 32) * 2;
        s8v va0 = ldsA(sm.stage, lr,      cb);
        s8v va1 = ldsA(sm.stage, lr + 16, cb);
        s8v vb  = *(const s8v*)(Bh + ks * 32);
        mfma16(a0, va0, vb);
        mfma16(a1, va1, vb);
      }
      __syncthreads();            // stage dead -> gx overlay
      #pragma unroll
      for (int r = 0; r < 4; r++){ sm.gx[w][rb + r][lr] = a0[r]; sm.gx[w][16 + rb + r][lr] = a1[r]; }
      __syncthreads();
      {
        int b = tid >> 4, rl = tid & 15;
        #pragma unroll
        for (int t2 = 0; t2 < 4; ++t2){
          float v = sm.gx[t2][b][rl] + sm.gx[t2 + 4][b][rl];
          stcc_u16(&pGhT[(size_t)b * G4 + rows0 + t2 * 16 + rl], f2bf(v));
        }
      }
    }
    gbar(bar, 128, epoch);

    // ---- B: m[:, nb*32 .. +31] = relu(ctx @ W1c^T + obsp[t]); 8 waves = 2 cg x 4 kq ----
    {
      s8v ct[8];
      st5_issue(ctxS, ct, HH);
      st5_commit(ct, sm.stage);
      __syncthreads();
      const int col0 = nb * 32 + (w >> 2) * 16;
      const int kh = (w & 3) * 256;
      f4v a0 = {0.f,0.f,0.f,0.f}, a1 = {0.f,0.f,0.f,0.f};
      const u16* Bp = W1c + (size_t)(col0 + lr) * HH + kh + lk;
      #pragma unroll
      for (int ks = 0; ks < 8; ++ks){
        int cb = (kh + lk + ks * 32) * 2;
        s8v va0 = ldsA(sm.stage, lr,      cb);
        s8v va1 = ldsA(sm.stage, lr + 16, cb);
        s8v vb  = *(const s8v*)(Bp + ks * 32);
        mfma16(a0, va0, vb);
        mfma16(a1, va1, vb);
      }
      __syncthreads();            // stage dead -> gx overlay
      #pragma unroll
      for (int r = 0; r < 4; r++){ sm.gx[w][rb + r][lr] = a0[r]; sm.gx[w][16 + rb + r][lr] = a1[r]; }
      __syncthreads();
      #pragma unroll
      for (int cg = 0; cg < 2; ++cg){
        int col = nb * 32 + cg * 16 + ejj;
        float v = sm.gx[4 * cg][eb][ejj] + sm.gx[4 * cg + 1][eb][ejj]
                + sm.gx[4 * cg + 2][eb][ejj] + sm.gx[4 * cg + 3][eb][ejj]
                + bf2f(obsp[((size_t)(t * BB + eb)) * G4 + col]);
        stcc_u16((u16*)&mbS[eb * G4 + col], f2bf(fmaxf(v, 0.f)));
      }
    }
    gbar(bar, 128, epoch);

    // ---- C: x[bh*16..+15, jc..+15] = relu(m @ W2^T + b2); FULL K per block ----
    {
      f4v a0 = {0.f,0.f,0.f,0.f};
      for (int q = 0; q < 4; ++q){
        s8v ct[4];
        st16_issue(mbS + (size_t)(bh * 16) * G4 + q * 1024, ct, G4);
        st16_commit(ct, sm.stage);
        __syncthreads();
        const u16* Bp = W2w + (size_t)(jc + lr) * G4 + q * 1024 + w * 128 + lk;
        #pragma unroll
        for (int ks = 0; ks < 4; ++ks){
          int cb = (w * 128 + lk + ks * 32) * 2;
          s8v va0 = ldsA(sm.stage, lr, cb);
          s8v vb  = *(const s8v*)(Bp + ks * 32);
          mfma16(a0, va0, vb);
        }
        __syncthreads();
      }
      #pragma unroll
      for (int r = 0; r < 4; r++) sm.gx[w][rb + r][lr] = a0[r];
      __syncthreads();
      if (tid < 256){
        int bb = tid >> 4, cc = tid & 15;
        float v = b2[jc + cc];
        #pragma unroll
        for (int g = 0; g < 8; ++g) v += sm.gx[g][bb][cc];
        stcc_u16((u16*)&xbS[(bh * 16 + bb) * HH + jc + cc], f2bf(fmaxf(v, 0.f)));
      }
    }
    gbar(bar, 128, epoch);

    // ---- D: gates = x@WihL^T + pGh + bias; 8 waves = 4 gates x 2 K-halves ----
    {
      s8v xt[4];
      st16_issue(xbS + (size_t)(bh * 16) * HH, xt, HH);
      st16_commit(xt, sm.stage);
      __syncthreads();
      const int gate = w >> 1, kh = (w & 1) * 512;
      f4v a0 = {0.f,0.f,0.f,0.f};
      const u16* Bx = WihL + (size_t)(gate * HH + jc + lr) * HH + kh + lk;
      #pragma unroll
      for (int ks = 0; ks < 16; ++ks){
        int cb = (kh + lk + ks * 32) * 2;
        mfma16(a0, ldsA(sm.stage, lr, cb), *(const s8v*)(Bx + ks * 32));
      }
      __syncthreads();
      #pragma unroll
      for (int r = 0; r < 4; r++) sm.gx[w][rb + r][lr] = a0[r];
      __syncthreads();
      if (tid < 256){
        int bb = tid >> 4, cc = tid & 15;
        int b = bh * 16 + bb, col = jc + cc;
        const u16* pg = pGhT + (size_t)b * G4 + col;
        float gi = sm.gx[0][bb][cc] + sm.gx[1][bb][cc] + bf2f(pg[0])    + blstm[col];
        float gf = sm.gx[2][bb][cc] + sm.gx[3][bb][cc] + bf2f(pg[1024]) + blstm[1024 + col];
        float gg = sm.gx[4][bb][cc] + sm.gx[5][bb][cc] + bf2f(pg[2048]) + blstm[2048 + col];
        float go = sm.gx[6][bb][cc] + sm.gx[7][bb][cc] + bf2f(pg[3072]) + blstm[3072 + col];
        cr = sigf(gf) * cr + sigf(gi) * tanhf(gg);
        float h = sigf(go) * tanhf(cr);
        stcc_f32(&out[(size_t)t * (BB * HH) + b * HH + col], h);
        stcc_f32(&hfR[(size_t)(t + 1) * (BB * HH) + b * HH + col], h);
        stcc_u16(&hbR[(size_t)(t + 1) * (BB * HH) + b * HH + col], f2bf(h));
        if (t == TT - 1){
          stcc_f32(&out[1048576 + b * HH + col], h);
          stcc_f32(&out[1081344 + b * HH + col], cr);
        }
      }
    }
    gbar(bar, 128, epoch);
  }
}

// ---------- workspace layout (no aliases; pGh fresh region) ----------
static constexpr size_t oWihE = 0;
static constexpr size_t oWhhE = oWihE + 4194304;
static constexpr size_t oAttnW= oWhhE + 8388608;
static constexpr size_t oW1C  = oAttnW+ 2097152;
static constexpr size_t oW1O  = oW1C  + 8388608;
static constexpr size_t oW2   = oW1O  + 4194304;
static constexpr size_t oWihL = oW2   + 8388608;
static constexpr size_t oWhhL = oWihL + 8388608;
static constexpr size_t oBEnc = oWhhL + 8388608;
static constexpr size_t oBL   = oBEnc + 16384;
static constexpr size_t oDemoT= oBL   + 16384;
static constexpr size_t oObsB = oDemoT+ 4194304;
static constexpr size_t oXih  = oObsB + 1048576;
static constexpr size_t oObsP = oXih  + 33554432;
static constexpr size_t oDEnc = oObsP + 8388608;
static constexpr size_t oAPrj = oDEnc + 8388608;
static constexpr size_t oZE   = oAPrj + 8388608;
static constexpr size_t oHFR  = oZE   + 65536;
static constexpr size_t oHBR  = oHFR  + 4325376;
static constexpr size_t oCtxR = oHBR  + 2162688;
static constexpr size_t oMBR  = oCtxR + 2097152;
static constexpr size_t oXBR  = oMBR  + 8388608;
static constexpr size_t oPGh  = oXBR  + 2097152;   // 32 x 32 x 4096 x 2B = 8 MB (rotated, virgin)
static constexpr size_t oBar  = oPGh  + 8388608;

extern "C" void kernel_launch(void* const* d_in, const int* in_sizes, int n_in,
                              void* d_out, int out_size, void* d_ws, size_t ws_size,
                              hipStream_t stream)
{
  const float* demo = (const float*)d_in[0];
  const int*   lens = (const int*)  d_in[1];
  const float* obs  = (const float*)d_in[2];
  const float* h0   = (const float*)d_in[3];
  const float* c0   = (const float*)d_in[4];
  const float* eWih = (const float*)d_in[5];
  const float* eWhh = (const float*)d_in[6];
  const float* eBih = (const float*)d_in[7];
  const float* eBhh = (const float*)d_in[8];
  const float* aW   = (const float*)d_in[9];
  const float* aB   = (const float*)d_in[10];
  const float* W1   = (const float*)d_in[11];
  const float* B1   = (const float*)d_in[12];
  const float* W2   = (const float*)d_in[13];
  const float* B2   = (const float*)d_in[14];
  const float* lWih = (const float*)d_in[15];
  const float* lWhh = (const float*)d_in[16];
  const float* lBih = (const float*)d_in[17];
  const float* lBhh = (const float*)d_in[18];

  char* ws = (char*)d_ws;
  u16*  WihE = (u16*)(ws + oWihE);
  u16*  WhhE = (u16*)(ws + oWhhE);
  u16*  AttnW= (u16*)(ws + oAttnW);
  u16*  W1C  = (u16*)(ws + oW1C);
  u16*  W1O  = (u16*)(ws + oW1O);
  u16*  W2w  = (u16*)(ws + oW2);
  u16*  WihL = (u16*)(ws + oWihL);
  u16*  WhhL = (u16*)(ws + oWhhL);
  float* BEnc= (float*)(ws + oBEnc);
  float* BL  = (float*)(ws + oBL);
  u16*  DemoT= (u16*)(ws + oDemoT);
  u16*  ObsB = (u16*)(ws + oObsB);
  u16*  Xih  = (u16*)(ws + oXih);
  u16*  ObsP = (u16*)(ws + oObsP);
  u16*  DEnc = (u16*)(ws + oDEnc);
  u16*  APrj = (u16*)(ws + oAPrj);
  u16*  ZE   = (u16*)(ws + oZE);
  float* HFR = (float*)(ws + oHFR);
  u16*  HBR  = (u16*)(ws + oHBR);
  u16*  CtxR = (u16*)(ws + oCtxR);
  u16*  MBR  = (u16*)(ws + oMBR);
  u16*  XBR  = (u16*)(ws + oXBR);
  u16*  PGh  = (u16*)(ws + oPGh);
  u32*  Bar  = (u32*)(ws + oBar);

  k_convert<<<1024, 256, 0, stream>>>(eWih, WihE, G4 * FF);
  k_convert<<<1024, 256, 0, stream>>>(eWhh, WhhE, G4 * HH);
  k_convert<<<512,  256, 0, stream>>>(aW,   AttnW, HH * HH);
  k_split_w1<<<1024, 256, 0, stream>>>(W1, W1C, W1O);
  k_convert<<<1024, 256, 0, stream>>>(W2,   W2w,  HH * G4);
  k_convert<<<1024, 256, 0, stream>>>(lWih, WihL, G4 * HH);
  k_convert<<<1024, 256, 0, stream>>>(lWhh, WhhL, G4 * HH);
  k_addb<<<16, 256, 0, stream>>>(eBih, eBhh, BEnc, G4);
  k_addb<<<16, 256, 0, stream>>>(lBih, lBhh, BL, G4);
  k_demo_t<<<1024, 256, 0, stream>>>(demo, DemoT);
  k_convert<<<512, 256, 0, stream>>>(obs, ObsB, TT * BB * FF);
  hipMemsetAsync(Bar, 0, 256, stream);

  {
    dim3 g(LL * BB / 128, G4 / 128);
    k_gemm_bt<0><<<g, 256, 0, stream>>>(DemoT, WihE, BEnc, Xih, LL * BB, G4, FF);
  }
  {
    dim3 g(TT * BB / 128, G4 / 128);
    k_gemm_bt<0><<<g, 256, 0, stream>>>(ObsB, W1O, B1, ObsP, TT * BB, G4, FF);
  }

  k_encoder<<<64, 1024, 0, stream>>>(WhhE, Xih, ZE, DEnc, Bar);

  {
    dim3 g(LL * BB / 128, HH / 128);
    k_gemm_bt<0><<<g, 256, 0, stream>>>(DEnc, AttnW, aB, APrj, LL * BB, HH, HH);
  }

  k_decoder<<<128, 512, 0, stream>>>(APrj, DEnc, ObsP, W1C, W2w, WihL, WhhL,
                                     BL, B2, h0, c0, lens,
                                     HFR, HBR, CtxR, MBR, XBR, PGh,
                                     (float*)d_out, Bar + 16);
}